// Round 4
// baseline (1063.778 us; speedup 1.0000x reference)
//
#include <hip/hip_runtime.h>

// GNN: N=50000 nodes, E=800000 edges, H=64, L=2.
// R9: BARRIER-FREE restructure. Each wave owns 16 rows (edges/nodes) x all 64
// features (loop fo over output-feature tiles). All phase-to-phase data flow
// is wave-private (LDS plane round-trip within the wave's 16 rows; DS ops are
// in-order per wave) -> zero __syncthreads in edge/node kernels.
// Inputs (eattr/epk/x/x_h/agg) load directly into register fragments; epk
// output packs directly from acc. LDS = one plane pair (18.7 KB).
// R10: resubmit of R9 unchanged — GPU acquisition timed out (no counters).
// Pipeline: conv_w | CSR | encode | edge_l0(+agg) | node_l0 | memset |
//           edge_l1(+agg) | node_l1+dec.

#define NN 50000
#define EE 800000
#define HH 64
#define LDK 72   // bf16 plane leading dim (144 B row)
#define EPB 64   // rows (edges or nodes) per block

typedef short short8 __attribute__((ext_vector_type(8)));
typedef short short4v __attribute__((ext_vector_type(4)));
typedef float f32x4 __attribute__((ext_vector_type(4)));

#define MFMA __builtin_amdgcn_mfma_f32_16x16x32_bf16

// wt slots (each 8192 ushorts: 4096 hi + 4096 lo, layout [f][k])
#define S_WE2   0
#define S_W1E0  1
#define S_W2E0  2
#define S_W1E1  3
#define S_W2E1  4
#define S_WN2   5
#define S_W1S0  6
#define S_W1D0  7
#define S_W1S1  8
#define S_W1D1  9
#define S_W1NX0 10
#define S_W1NA0 11
#define S_W2N0  12
#define S_W1NX1 13
#define S_W1NA1 14
#define S_W2N1  15
#define S_DW1   16
#define OFF_WE1 (17*8192)          // [f][32], K=4 padded
#define OFF_WN1 (17*8192+4096)     // [f][32], K=8 padded
#define WT_USHORTS (17*8192+8192)

// ---------------- bf16 helpers ----------------

__device__ __forceinline__ void split2(float x, unsigned short& h, unsigned short& l) {
    union { float f; unsigned u; } a, hf, b;
    a.f = x;
    const unsigned hb = (a.u + 0x7FFFu + ((a.u >> 16) & 1u)) >> 16;  // RNE hi
    hf.u = hb << 16;
    b.f = x - hf.f;                  // exact
    h = (unsigned short)hb;
    l = (unsigned short)(b.u >> 16); // truncated lo: err <= 2^-16 |x|
}

__device__ __forceinline__ float bf2f(unsigned short s) {
    union { unsigned u; float f; } a; a.u = ((unsigned)s) << 16; return a.f;
}

__device__ __forceinline__ float uph(unsigned u) {
    union { unsigned x; float f; } a; a.x = u & 0xFFFF0000u; return a.f;
}
__device__ __forceinline__ float upl(unsigned u) {
    union { unsigned x; float f; } a; a.x = u << 16; return a.f;
}

__device__ __forceinline__ short8 zero8() {
    short8 z;
#pragma unroll
    for (int i = 0; i < 8; ++i) z[i] = 0;
    return z;
}

// split 8 floats -> hi/lo bf16 fragments
__device__ __forceinline__ void split8(const float* v, short8& h, short8& l) {
    union { unsigned short u[8]; short8 s; } H, L;
#pragma unroll
    for (int i = 0; i < 8; ++i) split2(v[i], H.u[i], L.u[i]);
    h = H.s; l = L.s;
}

// A-frags for one 16-outfeat slice of a 64x64 weight: [chunk][plane]
__device__ __forceinline__ void load_wf(const unsigned short* __restrict__ wm,
                                        int fo, int l15, int quad, short8 (&w)[2][2]) {
#pragma unroll
    for (int c = 0; c < 2; ++c) {
        const int el = (fo * 16 + l15) * 64 + c * 32 + quad * 8;
        w[c][0] = *(const short8*)(wm + el);
        w[c][1] = *(const short8*)(wm + 4096 + el);
    }
}

// D += Ah*Bh + Al*Bh + Ah*Bl over K=64 (2 chunks)
__device__ __forceinline__ f32x4 chain6(const short8 (&w)[2][2],
                                        short8 bh0, short8 bh1,
                                        short8 bl0, short8 bl1, f32x4 a) {
    a = MFMA(w[0][0], bh0, a, 0, 0, 0);
    a = MFMA(w[1][0], bh1, a, 0, 0, 0);
    a = MFMA(w[0][1], bh0, a, 0, 0, 0);
    a = MFMA(w[1][1], bh1, a, 0, 0, 0);
    a = MFMA(w[0][0], bl0, a, 0, 0, 0);
    a = MFMA(w[1][0], bl1, a, 0, 0, 0);
    return a;
}

// acc[fo] += W[fo] @ B (K=64), B-frags shared across fo
__device__ __forceinline__ void gemm_fo(const unsigned short* __restrict__ wm,
                                        int l15, int quad,
                                        short8 bh0, short8 bh1, short8 bl0, short8 bl1,
                                        f32x4 (&acc)[4]) {
#pragma unroll
    for (int fo = 0; fo < 4; ++fo) {
        short8 w[2][2];
        load_wf(wm, fo, l15, quad, w);
        acc[fo] = chain6(w, bh0, bh1, bl0, bl1, acc[fo]);
    }
}

// B-frags for this lane's row r from planes (both chunks, hi+lo)
__device__ __forceinline__ void load_bf(const unsigned short* pHi, const unsigned short* pLo,
                                        int r, int quad,
                                        short8& bh0, short8& bh1, short8& bl0, short8& bl1) {
    bh0 = *(const short8*)(pHi + r * LDK + quad * 8);
    bh1 = *(const short8*)(pHi + r * LDK + 32 + quad * 8);
    bl0 = *(const short8*)(pLo + r * LDK + quad * 8);
    bl1 = *(const short8*)(pLo + r * LDK + 32 + quad * 8);
}

__device__ __forceinline__ void set_bias_fo(f32x4 (&acc)[4], const float* __restrict__ b, int q4) {
#pragma unroll
    for (int fo = 0; fo < 4; ++fo) {
        const float4 b4 = *(const float4*)(b + fo * 16 + q4);
        acc[fo][0] = b4.x; acc[fo][1] = b4.y; acc[fo][2] = b4.z; acc[fo][3] = b4.w;
    }
}

__device__ __forceinline__ void set_zero(f32x4 (&acc)[4]) {
#pragma unroll
    for (int fo = 0; fo < 4; ++fo)
#pragma unroll
        for (int i = 0; i < 4; ++i) acc[fo][i] = 0.f;
}

__device__ __forceinline__ void relu4(f32x4 (&acc)[4]) {
#pragma unroll
    for (int fo = 0; fo < 4; ++fo)
#pragma unroll
        for (int i = 0; i < 4; ++i) acc[fo][i] = fmaxf(acc[fo][i], 0.f);
}

// store this lane's C tiles (row r, feats fo*16+q4..+4) to planes (wave-private)
__device__ __forceinline__ void store_row_planes(unsigned short* pHi, unsigned short* pLo,
                                                 const f32x4 (&acc)[4], int r, int q4) {
#pragma unroll
    for (int fo = 0; fo < 4; ++fo) {
        union { unsigned short u[4]; short4v v; } h, l;
#pragma unroll
        for (int i = 0; i < 4; ++i) split2(acc[fo][i], h.u[i], l.u[i]);
        *(short4v*)(pHi + r * LDK + fo * 16 + q4) = h.v;
        *(short4v*)(pLo + r * LDK + fo * 16 + q4) = l.v;
    }
}

// in-LDS segment sum over dst-sorted rows + atomic scatter to agg.
// wave wv sums its own rows [wv*16, wv*16+16); lane = feature.
__device__ __forceinline__ void segsum_atomic(const unsigned short* pHi, const unsigned short* pLo,
                                              const int* sDst, int t,
                                              float* __restrict__ agg) {
    const int f = t & 63, c0 = (t >> 6) * 16;
    float s = 0.f;
    int d = sDst[c0];
#pragma unroll
    for (int i = 0; i < 16; ++i) {
        const int r = c0 + i;
        s += bf2f(pHi[r * LDK + f]) + bf2f(pLo[r * LDK + f]);
        const int dn = (i == 15) ? -1 : sDst[r + 1];
        if (dn != d) {
            atomicAdd(&agg[(size_t)d * HH + f], s);
            s = 0.f; d = dn;
        }
    }
}

// load f32 row [64] from global as B-frags (2 chunks, hi/lo); zero if !valid
__device__ __forceinline__ void load_f32row_bf(const float* __restrict__ g, long rowOff,
                                               int quad, bool valid,
                                               short8& h0, short8& h1, short8& l0, short8& l1) {
    float v0[8], v1[8];
#pragma unroll
    for (int i = 0; i < 8; ++i) { v0[i] = 0.f; v1[i] = 0.f; }
    if (valid) {
        const float4 a0 = *(const float4*)(g + rowOff + quad * 8);
        const float4 a1 = *(const float4*)(g + rowOff + quad * 8 + 4);
        const float4 b0 = *(const float4*)(g + rowOff + 32 + quad * 8);
        const float4 b1 = *(const float4*)(g + rowOff + 32 + quad * 8 + 4);
        v0[0] = a0.x; v0[1] = a0.y; v0[2] = a0.z; v0[3] = a0.w;
        v0[4] = a1.x; v0[5] = a1.y; v0[6] = a1.z; v0[7] = a1.w;
        v1[0] = b0.x; v1[1] = b0.y; v1[2] = b0.z; v1[3] = b0.w;
        v1[4] = b1.x; v1[5] = b1.y; v1[6] = b1.z; v1[7] = b1.w;
    }
    split8(v0, h0, l0);
    split8(v1, h1, l1);
}

// ---------------- setup: split all weights, transposed [f][k] ----------------

__global__ void k_conv_w(const float* __restrict__ enc_n_w1, const float* __restrict__ enc_n_w2,
                         const float* __restrict__ enc_e_w1, const float* __restrict__ enc_e_w2,
                         const float* __restrict__ pe_w1, const float* __restrict__ pe_w2,
                         const float* __restrict__ pn_w1, const float* __restrict__ pn_w2,
                         const float* __restrict__ dw1, unsigned short* __restrict__ wt)
{
    const int i = blockIdx.x * 256 + threadIdx.x;
    if (i < 17 * 4096) {
        const int m = i >> 12, r = i & 4095;
        const int f = r & 63, k = r >> 6;
        const float* W;
        switch (m) {
            case S_WE2:   W = enc_e_w2; break;
            case S_W1E0:  W = pe_w1; break;
            case S_W2E0:  W = pe_w2; break;
            case S_W1E1:  W = pe_w1 + 192 * 64; break;
            case S_W2E1:  W = pe_w2 + 64 * 64; break;
            case S_WN2:   W = enc_n_w2; break;
            case S_W1S0:  W = pe_w1 + 64 * 64; break;
            case S_W1D0:  W = pe_w1 + 128 * 64; break;
            case S_W1S1:  W = pe_w1 + 192 * 64 + 64 * 64; break;
            case S_W1D1:  W = pe_w1 + 192 * 64 + 128 * 64; break;
            case S_W1NX0: W = pn_w1; break;
            case S_W1NA0: W = pn_w1 + 64 * 64; break;
            case S_W2N0:  W = pn_w2; break;
            case S_W1NX1: W = pn_w1 + 128 * 64; break;
            case S_W1NA1: W = pn_w1 + 128 * 64 + 64 * 64; break;
            case S_W2N1:  W = pn_w2 + 64 * 64; break;
            default:      W = dw1; break;
        }
        unsigned short h, l; split2(W[r], h, l);    // W[k*64+f]
        wt[m * 8192 + f * 64 + k] = h;
        wt[m * 8192 + 4096 + f * 64 + k] = l;
    } else if (i < 17 * 4096 + 2048) {
        const int r = i - 17 * 4096, f = r >> 5, k = r & 31;
        const float v = (k < 4) ? enc_e_w1[k * 64 + f] : 0.f;
        unsigned short h, l; split2(v, h, l);
        wt[OFF_WE1 + f * 32 + k] = h;
        wt[OFF_WE1 + 2048 + f * 32 + k] = l;
    } else if (i < 17 * 4096 + 4096) {
        const int r = i - 17 * 4096 - 2048, f = r >> 5, k = r & 31;
        const float v = (k < 8) ? enc_n_w1[k * 64 + f] : 0.f;
        unsigned short h, l; split2(v, h, l);
        wt[OFF_WN1 + f * 32 + k] = h;
        wt[OFF_WN1 + 2048 + f * 32 + k] = l;
    }
}

// ---------------- CSR build ----------------

__global__ void k_deg(const int* __restrict__ eidx, unsigned* __restrict__ deg) {
    const int e = blockIdx.x * 256 + threadIdx.x;
    if (e < EE) atomicAdd(&deg[eidx[EE + e]], 1u);
}

__global__ __launch_bounds__(1024) void k_scan(unsigned* deg, unsigned* __restrict__ off) {
    __shared__ unsigned part[1024];
    const int t = threadIdx.x;
    const int CH = (NN + 1023) / 1024;
    const int s = t * CH, e = s + CH < NN ? s + CH : NN;
    unsigned sum = 0;
    for (int i = s; i < e; ++i) sum += deg[i];
    part[t] = sum;
    __syncthreads();
    for (int d = 1; d < 1024; d <<= 1) {
        unsigned v = (t >= d) ? part[t - d] : 0u;
        __syncthreads();
        if (t >= d) part[t] += v;
        __syncthreads();
    }
    unsigned base = (t > 0) ? part[t - 1] : 0u;
    for (int i = s; i < e; ++i) {
        const unsigned d = deg[i];
        off[i] = base;
        deg[i] = base;          // reuse as fill cursor
        base += d;
    }
    if (t == 1023) off[NN] = part[1023];
}

__global__ void k_fill(const int* __restrict__ eidx, unsigned* __restrict__ cur,
                       int* __restrict__ csr, int* __restrict__ srcs_s,
                       int* __restrict__ dsts_s) {
    const int e = blockIdx.x * 256 + threadIdx.x;
    if (e < EE) {
        const int d = eidx[EE + e];
        const unsigned p = atomicAdd(&cur[d], 1u);
        csr[p] = e;
        srcs_s[p] = eidx[e];
        dsts_s[p] = d;
    }
}

// ---------------- K2: edge encoder + layer-0 edge MLP + fused agg ----------------

__global__ __launch_bounds__(256, 4) void k_edge_l0(
    const float* __restrict__ eattr, const int* __restrict__ csr,
    const int* __restrict__ srcs_s, const int* __restrict__ dsts_s,
    const float* __restrict__ Ps, const float* __restrict__ Pd,
    const float* __restrict__ be1, const float* __restrict__ be2,
    const unsigned short* __restrict__ wt,
    const float* __restrict__ pb1, const float* __restrict__ pb2,
    unsigned* __restrict__ epk, float* __restrict__ agg)
{
    __shared__ unsigned short pHi[EPB * LDK], pLo[EPB * LDK];
    __shared__ int sDst[EPB];

    const int t = threadIdx.x;
    const int lane = t & 63, wv = t >> 6;
    const int quad = lane >> 4, l15 = lane & 15, q4 = quad * 4;
    const long eBase = (long)blockIdx.x * EPB;
    const int r = wv * 16 + l15;            // wave-private LDS row
    const long e = eBase + r;               // this lane's (sorted) edge

    if (lane < 16) sDst[wv * 16 + lane] = dsts_s[eBase + wv * 16 + lane];

    const int src = srcs_s[e];
    const int dst = dsts_s[e];

    // eattr B-frag (K=32: feats 0..3 data, rest zero); only quad-0 lanes carry data
    short8 ah0 = zero8(), al0 = zero8();
    if (quad == 0) {
        const int eid = csr[e];
        const float4 ea = *(const float4*)(eattr + (size_t)eid * 4);
        float v[8] = {ea.x, ea.y, ea.z, ea.w, 0.f, 0.f, 0.f, 0.f};
        split8(v, ah0, al0);
    }

    // prefetch Ps/Pd (consumed in phase3)
    float4 ps[4], pd[4];
#pragma unroll
    for (int fo = 0; fo < 4; ++fo) {
        ps[fo] = *(const float4*)(Ps + (size_t)src * HH + fo * 16 + q4);
        pd[fo] = *(const float4*)(Pd + (size_t)dst * HH + fo * 16 + q4);
    }

    f32x4 acc[4];

    // phase1: h0 = relu(eattr @ We1 + be1) -> planes
    set_bias_fo(acc, be1, q4);
#pragma unroll
    for (int fo = 0; fo < 4; ++fo) {
        const int el = (fo * 16 + l15) * 32 + quad * 8;
        const short8 wa0 = *(const short8*)(wt + OFF_WE1 + el);
        const short8 wa1 = *(const short8*)(wt + OFF_WE1 + 2048 + el);
        f32x4 a = acc[fo];
        a = MFMA(wa0, ah0, a, 0, 0, 0);
        a = MFMA(wa1, ah0, a, 0, 0, 0);
        a = MFMA(wa0, al0, a, 0, 0, 0);
        acc[fo] = a;
    }
    relu4(acc);
    store_row_planes(pHi, pLo, acc, r, q4);

    short8 bh0, bh1, bl0, bl1;

    // phase2: e0 = h0 @ We2 + be2
    load_bf(pHi, pLo, r, quad, bh0, bh1, bl0, bl1);
    set_bias_fo(acc, be2, q4);
    gemm_fo(wt + S_WE2 * 8192, l15, quad, bh0, bh1, bl0, bl1, acc);
    f32x4 e0s[4];
#pragma unroll
    for (int fo = 0; fo < 4; ++fo) e0s[fo] = acc[fo];
    store_row_planes(pHi, pLo, acc, r, q4);

    // phase3: t1 = relu(e0 @ W1e + Ps[src] + Pd[dst] + pb1)
    load_bf(pHi, pLo, r, quad, bh0, bh1, bl0, bl1);
    set_zero(acc);
    gemm_fo(wt + S_W1E0 * 8192, l15, quad, bh0, bh1, bl0, bl1, acc);
#pragma unroll
    for (int fo = 0; fo < 4; ++fo) {
        const float4 b4 = *(const float4*)(pb1 + fo * 16 + q4);
        acc[fo][0] = fmaxf(acc[fo][0] + ps[fo].x + pd[fo].x + b4.x, 0.f);
        acc[fo][1] = fmaxf(acc[fo][1] + ps[fo].y + pd[fo].y + b4.y, 0.f);
        acc[fo][2] = fmaxf(acc[fo][2] + ps[fo].z + pd[fo].z + b4.z, 0.f);
        acc[fo][3] = fmaxf(acc[fo][3] + ps[fo].w + pd[fo].w + b4.w, 0.f);
    }
    store_row_planes(pHi, pLo, acc, r, q4);

    // phase4: e1 = e0(regs) + t1 @ W2e + pb2 -> planes (for segsum) + epk direct
    load_bf(pHi, pLo, r, quad, bh0, bh1, bl0, bl1);
    set_zero(acc);
    gemm_fo(wt + S_W2E0 * 8192, l15, quad, bh0, bh1, bl0, bl1, acc);
#pragma unroll
    for (int fo = 0; fo < 4; ++fo) {
        const float4 b4 = *(const float4*)(pb2 + fo * 16 + q4);
        acc[fo][0] += e0s[fo][0] + b4.x;
        acc[fo][1] += e0s[fo][1] + b4.y;
        acc[fo][2] += e0s[fo][2] + b4.z;
        acc[fo][3] += e0s[fo][3] + b4.w;
        union { unsigned short u[4]; short4v v; } h, l;
        union { unsigned u[4]; uint4 v; } o;
#pragma unroll
        for (int i = 0; i < 4; ++i) {
            split2(acc[fo][i], h.u[i], l.u[i]);
            o.u[i] = ((unsigned)h.u[i] << 16) | l.u[i];
        }
        *(short4v*)(pHi + r * LDK + fo * 16 + q4) = h.v;
        *(short4v*)(pLo + r * LDK + fo * 16 + q4) = l.v;
        *(uint4*)(epk + (size_t)e * HH + fo * 16 + q4) = o.v;
    }

    // fused aggregation (wave-private rows): agg[dst] += e1
    segsum_atomic(pHi, pLo, sDst, t, agg);
}

// ---------------- K4: layer-1 edge MLP + fused agg ----------------

__global__ __launch_bounds__(256, 4) void k_edge_l1(
    const int* __restrict__ srcs_s, const int* __restrict__ dsts_s,
    const float* __restrict__ Ps, const float* __restrict__ Pd,
    const unsigned short* __restrict__ wt,
    const float* __restrict__ pb1, const float* __restrict__ pb2,
    const unsigned* __restrict__ epk, float* __restrict__ agg)
{
    __shared__ unsigned short pHi[EPB * LDK], pLo[EPB * LDK];
    __shared__ int sDst[EPB];

    const int t = threadIdx.x;
    const int lane = t & 63, wv = t >> 6;
    const int quad = lane >> 4, l15 = lane & 15, q4 = quad * 4;
    const long eBase = (long)blockIdx.x * EPB;
    const int r = wv * 16 + l15;
    const long e = eBase + r;

    if (lane < 16) sDst[wv * 16 + lane] = dsts_s[eBase + wv * 16 + lane];

    const int src = srcs_s[e];
    const int dst = dsts_s[e];

    // B-frags direct from epk (deinterleave hi/lo in regs)
    short8 bh0, bh1, bl0, bl1;
    {
        union { unsigned u[8]; uint4 v[2]; } c0, c1;
        c0.v[0] = *(const uint4*)(epk + (size_t)e * HH + quad * 8);
        c0.v[1] = *(const uint4*)(epk + (size_t)e * HH + quad * 8 + 4);
        c1.v[0] = *(const uint4*)(epk + (size_t)e * HH + 32 + quad * 8);
        c1.v[1] = *(const uint4*)(epk + (size_t)e * HH + 32 + quad * 8 + 4);
        union { unsigned short u[8]; short8 s; } H0, L0, H1, L1;
#pragma unroll
        for (int i = 0; i < 8; ++i) {
            H0.u[i] = (unsigned short)(c0.u[i] >> 16);
            L0.u[i] = (unsigned short)(c0.u[i] & 0xFFFFu);
            H1.u[i] = (unsigned short)(c1.u[i] >> 16);
            L1.u[i] = (unsigned short)(c1.u[i] & 0xFFFFu);
        }
        bh0 = H0.s; bl0 = L0.s; bh1 = H1.s; bl1 = L1.s;
    }
    // residual e1 at this lane's C-positions (L1/L2-hot reload)
    uint4 rs[4];
#pragma unroll
    for (int fo = 0; fo < 4; ++fo)
        rs[fo] = *(const uint4*)(epk + (size_t)e * HH + fo * 16 + q4);

    // Ps/Pd prefetch
    float4 ps[4], pd[4];
#pragma unroll
    for (int fo = 0; fo < 4; ++fo) {
        ps[fo] = *(const float4*)(Ps + (size_t)src * HH + fo * 16 + q4);
        pd[fo] = *(const float4*)(Pd + (size_t)dst * HH + fo * 16 + q4);
    }

    f32x4 acc[4];

    // t1 = relu(e1 @ W1e + Ps[src] + Pd[dst] + pb1)
    set_zero(acc);
    gemm_fo(wt + S_W1E1 * 8192, l15, quad, bh0, bh1, bl0, bl1, acc);
#pragma unroll
    for (int fo = 0; fo < 4; ++fo) {
        const float4 b4 = *(const float4*)(pb1 + fo * 16 + q4);
        acc[fo][0] = fmaxf(acc[fo][0] + ps[fo].x + pd[fo].x + b4.x, 0.f);
        acc[fo][1] = fmaxf(acc[fo][1] + ps[fo].y + pd[fo].y + b4.y, 0.f);
        acc[fo][2] = fmaxf(acc[fo][2] + ps[fo].z + pd[fo].z + b4.z, 0.f);
        acc[fo][3] = fmaxf(acc[fo][3] + ps[fo].w + pd[fo].w + b4.w, 0.f);
    }
    store_row_planes(pHi, pLo, acc, r, q4);

    // e2 = e1 + t1 @ W2e + pb2 -> planes (segsum only)
    load_bf(pHi, pLo, r, quad, bh0, bh1, bl0, bl1);
    set_zero(acc);
    gemm_fo(wt + S_W2E1 * 8192, l15, quad, bh0, bh1, bl0, bl1, acc);
#pragma unroll
    for (int fo = 0; fo < 4; ++fo) {
        const float4 b4 = *(const float4*)(pb2 + fo * 16 + q4);
        acc[fo][0] += uph(rs[fo].x) + upl(rs[fo].x) + b4.x;
        acc[fo][1] += uph(rs[fo].y) + upl(rs[fo].y) + b4.y;
        acc[fo][2] += uph(rs[fo].z) + upl(rs[fo].z) + b4.z;
        acc[fo][3] += uph(rs[fo].w) + upl(rs[fo].w) + b4.w;
    }
    store_row_planes(pHi, pLo, acc, r, q4);

    // fused aggregation: agg[dst] += e2
    segsum_atomic(pHi, pLo, sDst, t, agg);
}

// ---------------- K1: node encoder + layer-0 projections ----------------

__global__ __launch_bounds__(256, 4) void k_encode_nodes(
    const float* __restrict__ x, const unsigned short* __restrict__ wt,
    const float* __restrict__ bn1, const float* __restrict__ bn2,
    float* __restrict__ x_h, float* __restrict__ Ps, float* __restrict__ Pd)
{
    __shared__ unsigned short pHi[EPB * LDK], pLo[EPB * LDK];

    const int t = threadIdx.x;
    const int lane = t & 63, wv = t >> 6;
    const int quad = lane >> 4, l15 = lane & 15, q4 = quad * 4;
    const int nodeBase = blockIdx.x * 64;
    const int r = wv * 16 + l15;
    const int n = nodeBase + r;
    const bool valid = n < NN;

    // x B-frag (K=32: 8 feats, rest zero); only quad-0 lanes carry data
    short8 ah0 = zero8(), al0 = zero8();
    if (quad == 0 && valid) {
        const float4 a0 = *(const float4*)(x + (size_t)n * 8);
        const float4 a1 = *(const float4*)(x + (size_t)n * 8 + 4);
        float v[8] = {a0.x, a0.y, a0.z, a0.w, a1.x, a1.y, a1.z, a1.w};
        split8(v, ah0, al0);
    }

    f32x4 acc[4];

    // phase1: h1 = relu(x @ wn1 + bn1)
    set_bias_fo(acc, bn1, q4);
#pragma unroll
    for (int fo = 0; fo < 4; ++fo) {
        const int el = (fo * 16 + l15) * 32 + quad * 8;
        const short8 wa0 = *(const short8*)(wt + OFF_WN1 + el);
        const short8 wa1 = *(const short8*)(wt + OFF_WN1 + 2048 + el);
        f32x4 a = acc[fo];
        a = MFMA(wa0, ah0, a, 0, 0, 0);
        a = MFMA(wa1, ah0, a, 0, 0, 0);
        a = MFMA(wa0, al0, a, 0, 0, 0);
        acc[fo] = a;
    }
    relu4(acc);
    store_row_planes(pHi, pLo, acc, r, q4);

    short8 bh0, bh1, bl0, bl1;

    // phase2: x_h = h1 @ wn2 + bn2 -> global + planes
    load_bf(pHi, pLo, r, quad, bh0, bh1, bl0, bl1);
    set_bias_fo(acc, bn2, q4);
    gemm_fo(wt + S_WN2 * 8192, l15, quad, bh0, bh1, bl0, bl1, acc);
    if (valid) {
#pragma unroll
        for (int fo = 0; fo < 4; ++fo)
            *(float4*)(x_h + (size_t)n * HH + fo * 16 + q4) =
                make_float4(acc[fo][0], acc[fo][1], acc[fo][2], acc[fo][3]);
    }
    store_row_planes(pHi, pLo, acc, r, q4);

    // phases 3/4 share x_h B-frags
    load_bf(pHi, pLo, r, quad, bh0, bh1, bl0, bl1);
    set_zero(acc);
    gemm_fo(wt + S_W1S0 * 8192, l15, quad, bh0, bh1, bl0, bl1, acc);
    if (valid) {
#pragma unroll
        for (int fo = 0; fo < 4; ++fo)
            *(float4*)(Ps + (size_t)n * HH + fo * 16 + q4) =
                make_float4(acc[fo][0], acc[fo][1], acc[fo][2], acc[fo][3]);
    }
    set_zero(acc);
    gemm_fo(wt + S_W1D0 * 8192, l15, quad, bh0, bh1, bl0, bl1, acc);
    if (valid) {
#pragma unroll
        for (int fo = 0; fo < 4; ++fo)
            *(float4*)(Pd + (size_t)n * HH + fo * 16 + q4) =
                make_float4(acc[fo][0], acc[fo][1], acc[fo][2], acc[fo][3]);
    }
}

// ---------------- K3: node update l0 + layer-1 projections ----------------

__global__ __launch_bounds__(256, 4) void k_node_l0(
    float* x_h, const float* agg, const unsigned short* __restrict__ wt,
    const float* __restrict__ nb1, const float* __restrict__ nb2,
    float* Ps, float* __restrict__ Pd)
{
    __shared__ unsigned short pHi[EPB * LDK], pLo[EPB * LDK];

    const int t = threadIdx.x;
    const int lane = t & 63, wv = t >> 6;
    const int quad = lane >> 4, l15 = lane & 15, q4 = quad * 4;
    const int nodeBase = blockIdx.x * 64;
    const int r = wv * 16 + l15;
    const int n = nodeBase + r;
    const bool valid = n < NN;

    // B-frags direct from x_h and agg
    short8 xh0, xh1, xl0, xl1, gh0, gh1, gl0, gl1;
    load_f32row_bf(x_h, (long)n * HH, quad, valid, xh0, xh1, xl0, xl1);
    load_f32row_bf(agg, (long)n * HH, quad, valid, gh0, gh1, gl0, gl1);

    f32x4 acc[4];

    // t1 = relu(x_h @ W1x + agg @ W1a + nb1)
    set_bias_fo(acc, nb1, q4);
    gemm_fo(wt + S_W1NX0 * 8192, l15, quad, xh0, xh1, xl0, xl1, acc);
    gemm_fo(wt + S_W1NA0 * 8192, l15, quad, gh0, gh1, gl0, gl1, acc);
    relu4(acc);
    store_row_planes(pHi, pLo, acc, r, q4);

    short8 bh0, bh1, bl0, bl1;

    // x_h1 = x_h + t1 @ W2n + nb2 -> global + planes
    load_bf(pHi, pLo, r, quad, bh0, bh1, bl0, bl1);
    set_bias_fo(acc, nb2, q4);
    gemm_fo(wt + S_W2N0 * 8192, l15, quad, bh0, bh1, bl0, bl1, acc);
    if (valid) {
#pragma unroll
        for (int fo = 0; fo < 4; ++fo) {
            const size_t gi = (size_t)n * HH + fo * 16 + q4;
            const float4 xr = *(const float4*)(x_h + gi);
            acc[fo][0] += xr.x; acc[fo][1] += xr.y;
            acc[fo][2] += xr.z; acc[fo][3] += xr.w;
            *(float4*)(x_h + gi) = make_float4(acc[fo][0], acc[fo][1], acc[fo][2], acc[fo][3]);
        }
    }
    store_row_planes(pHi, pLo, acc, r, q4);

    // Ps1/Pd1 share x_h1 B-frags
    load_bf(pHi, pLo, r, quad, bh0, bh1, bl0, bl1);
    set_zero(acc);
    gemm_fo(wt + S_W1S1 * 8192, l15, quad, bh0, bh1, bl0, bl1, acc);
    if (valid) {
#pragma unroll
        for (int fo = 0; fo < 4; ++fo)
            *(float4*)(Ps + (size_t)n * HH + fo * 16 + q4) =
                make_float4(acc[fo][0], acc[fo][1], acc[fo][2], acc[fo][3]);
    }
    set_zero(acc);
    gemm_fo(wt + S_W1D1 * 8192, l15, quad, bh0, bh1, bl0, bl1, acc);
    if (valid) {
#pragma unroll
        for (int fo = 0; fo < 4; ++fo)
            *(float4*)(Pd + (size_t)n * HH + fo * 16 + q4) =
                make_float4(acc[fo][0], acc[fo][1], acc[fo][2], acc[fo][3]);
    }
}

// ---------------- K5: node update l1 + decoder ----------------

__global__ __launch_bounds__(256, 4) void k_node_l1_dec(
    const float* x_h, const float* agg, const unsigned short* __restrict__ wt,
    const float* __restrict__ nb1, const float* __restrict__ nb2,
    const float* __restrict__ db1, const float* __restrict__ dw2,
    const float* __restrict__ db2, float* __restrict__ out)
{
    __shared__ unsigned short pHi[EPB * LDK], pLo[EPB * LDK];

    const int t = threadIdx.x;
    const int lane = t & 63, wv = t >> 6;
    const int quad = lane >> 4, l15 = lane & 15, q4 = quad * 4;
    const int nodeBase = blockIdx.x * 64;
    const int r = wv * 16 + l15;
    const int n = nodeBase + r;
    const bool valid = n < NN;

    short8 xh0, xh1, xl0, xl1, gh0, gh1, gl0, gl1;
    load_f32row_bf(x_h, (long)n * HH, quad, valid, xh0, xh1, xl0, xl1);
    load_f32row_bf(agg, (long)n * HH, quad, valid, gh0, gh1, gl0, gl1);

    f32x4 acc[4];

    // t1 = relu(x_h @ W1x + agg @ W1a + nb1)
    set_bias_fo(acc, nb1, q4);
    gemm_fo(wt + S_W1NX1 * 8192, l15, quad, xh0, xh1, xl0, xl1, acc);
    gemm_fo(wt + S_W1NA1 * 8192, l15, quad, gh0, gh1, gl0, gl1, acc);
    relu4(acc);
    store_row_planes(pHi, pLo, acc, r, q4);

    short8 bh0, bh1, bl0, bl1;

    // x_h2 = x_h + t1 @ W2n + nb2 (regs/planes only)
    load_bf(pHi, pLo, r, quad, bh0, bh1, bl0, bl1);
    set_bias_fo(acc, nb2, q4);
    gemm_fo(wt + S_W2N1 * 8192, l15, quad, bh0, bh1, bl0, bl1, acc);
    if (valid) {
#pragma unroll
        for (int fo = 0; fo < 4; ++fo) {
            const float4 xr = *(const float4*)(x_h + (size_t)n * HH + fo * 16 + q4);
            acc[fo][0] += xr.x; acc[fo][1] += xr.y;
            acc[fo][2] += xr.z; acc[fo][3] += xr.w;
        }
    }
    store_row_planes(pHi, pLo, acc, r, q4);

    // d1 = relu(x_h2 @ dec_w1 + db1) -> planes
    load_bf(pHi, pLo, r, quad, bh0, bh1, bl0, bl1);
    set_bias_fo(acc, db1, q4);
    gemm_fo(wt + S_DW1 * 8192, l15, quad, bh0, bh1, bl0, bl1, acc);
    relu4(acc);
    store_row_planes(pHi, pLo, acc, r, q4);

    // out = d1 @ dec_w2 + db2  (wave-private: lanes 0..15 handle own 16 nodes)
    if (lane < 16) {
        const int nn = nodeBase + wv * 16 + lane;
        if (nn < NN) {
            const int rr = wv * 16 + lane;
            float o[6];
#pragma unroll
            for (int c = 0; c < 6; ++c) o[c] = db2[c];
#pragma unroll 8
            for (int k = 0; k < 64; ++k) {
                const float a = bf2f(pHi[rr * LDK + k]) + bf2f(pLo[rr * LDK + k]);
#pragma unroll
                for (int c = 0; c < 6; ++c) o[c] = fmaf(a, dw2[k * 6 + c], o[c]);
            }
            float* op = out + (size_t)nn * 6;
#pragma unroll
            for (int c = 0; c < 6; ++c) op[c] = o[c];
        }
    }
}

// ---------------- launcher ----------------

extern "C" void kernel_launch(void* const* d_in, const int* in_sizes, int n_in,
                              void* d_out, int out_size, void* d_ws, size_t ws_size,
                              hipStream_t stream) {
    const float* x        = (const float*)d_in[0];
    const float* eattr    = (const float*)d_in[1];
    const int*   eidx     = (const int*)d_in[2];
    const float* enc_n_w1 = (const float*)d_in[3];
    const float* enc_n_b1 = (const float*)d_in[4];
    const float* enc_n_w2 = (const float*)d_in[5];
    const float* enc_n_b2 = (const float*)d_in[6];
    const float* enc_e_w1 = (const float*)d_in[7];
    const float* enc_e_b1 = (const float*)d_in[8];
    const float* enc_e_w2 = (const float*)d_in[9];
    const float* enc_e_b2 = (const float*)d_in[10];
    const float* pe_w1    = (const float*)d_in[11];  // [2,192,64]
    const float* pe_b1    = (const float*)d_in[12];  // [2,64]
    const float* pe_w2    = (const float*)d_in[13];  // [2,64,64]
    const float* pe_b2    = (const float*)d_in[14];  // [2,64]
    const float* pn_w1    = (const float*)d_in[15];  // [2,128,64]
    const float* pn_b1    = (const float*)d_in[16];
    const float* pn_w2    = (const float*)d_in[17];  // [2,64,64]
    const float* pn_b2    = (const float*)d_in[18];
    const float* dw1      = (const float*)d_in[19];
    const float* db1      = (const float*)d_in[20];
    const float* dw2      = (const float*)d_in[21];
    const float* db2      = (const float*)d_in[22];
    float* out = (float*)d_out;

    // ws: x_h | Ps | Pd | agg | epk | off | deg | csr | srcs_s | dsts_s | wt
    const size_t NNHH = (size_t)NN * HH;
    float* ws  = (float*)d_ws;
    float* x_h = ws;
    float* Ps  = ws + NNHH;
    float* Pd  = ws + 2 * NNHH;
    float* agg = ws + 3 * NNHH;
    unsigned* epk = (unsigned*)(ws + 4 * NNHH);           // EE*HH uints
    unsigned* off = epk + (size_t)EE * HH;                // NN+1
    unsigned* deg = off + (NN + 1);                       // NN, reused as cursor
    int* csr    = (int*)(deg + NN);                       // EE
    int* srcs_s = csr + EE;                               // EE
    int* dsts_s = srcs_s + EE;                            // EE
    unsigned short* wt = (unsigned short*)(dsts_s + EE);  // WT_USHORTS

    const int nodeBlocks = (NN + 63) / 64;   // 782
    const int edgeBlocks = EE / EPB;         // 12500
    const int eScal      = (EE + 255) / 256; // 3125

    hipMemsetAsync(deg, 0, (size_t)NN * sizeof(unsigned), stream);
    hipMemsetAsync(agg, 0, NNHH * sizeof(float), stream);

    k_conv_w<<<288, 256, 0, stream>>>(
        enc_n_w1, enc_n_w2, enc_e_w1, enc_e_w2,
        pe_w1, pe_w2, pn_w1, pn_w2, dw1, wt);

    k_deg<<<eScal, 256, 0, stream>>>(eidx, deg);
    k_scan<<<1, 1024, 0, stream>>>(deg, off);
    k_fill<<<eScal, 256, 0, stream>>>(eidx, deg, csr, srcs_s, dsts_s);

    k_encode_nodes<<<nodeBlocks, 256, 0, stream>>>(
        x, wt, enc_n_b1, enc_n_b2, x_h, Ps, Pd);

    k_edge_l0<<<edgeBlocks, 256, 0, stream>>>(
        eattr, csr, srcs_s, dsts_s, Ps, Pd,
        enc_e_b1, enc_e_b2, wt, pe_b1, pe_b2, epk, agg);

    k_node_l0<<<nodeBlocks, 256, 0, stream>>>(
        x_h, agg, wt, pn_b1, pn_b2, Ps, Pd);

    hipMemsetAsync(agg, 0, NNHH * sizeof(float), stream);

    k_edge_l1<<<edgeBlocks, 256, 0, stream>>>(
        srcs_s, dsts_s, Ps, Pd, wt, pe_b1 + 64, pe_b2 + 64, epk, agg);

    k_node_l1_dec<<<nodeBlocks, 256, 0, stream>>>(
        x_h, agg, wt, pn_b1 + 64, pn_b2 + 64,
        db1, dw2, db2, out);
}

// Round 5
// 759.238 us; speedup vs baseline: 1.4011x; 1.4011x over previous
//
#include <hip/hip_runtime.h>

// GNN: N=50000 nodes, E=800000 edges, H=64, L=2.
// R11: revert to R8 barriered structure (measured 667us; R9 barrier-free was
// 2.1x WORSE - serial intra-wave chains). Changes vs R8:
//  (1) edge kernels: 512 threads / 8 waves, 2 row-tiles per wave (same 64-edge
//      block, same LDS) -> up to 32 waves/CU (was 16) for latency hiding.
//  (2) v_cvt_pk_bf16_f32-based split (identical numerics, ~40% less split VALU)
//      in edge kernels.
// Node kernels / CSR / conv_w kept verbatim from R8.
// Pipeline: conv_w | CSR | encode | edge_l0(+agg) | node_l0 | memset |
//           edge_l1(+agg) | node_l1+dec.

#define NN 50000
#define EE 800000
#define HH 64
#define LDK 72   // bf16 plane leading dim (144 B row)
#define EPB 64   // rows (edges or nodes) per block

typedef short short8 __attribute__((ext_vector_type(8)));
typedef short short4v __attribute__((ext_vector_type(4)));
typedef float f32x4 __attribute__((ext_vector_type(4)));

#define MFMA __builtin_amdgcn_mfma_f32_16x16x32_bf16

// wt slots (each 8192 ushorts: 4096 hi + 4096 lo, layout [f][k])
#define S_WE2   0
#define S_W1E0  1
#define S_W2E0  2
#define S_W1E1  3
#define S_W2E1  4
#define S_WN2   5
#define S_W1S0  6
#define S_W1D0  7
#define S_W1S1  8
#define S_W1D1  9
#define S_W1NX0 10
#define S_W1NA0 11
#define S_W2N0  12
#define S_W1NX1 13
#define S_W1NA1 14
#define S_W2N1  15
#define S_DW1   16
#define OFF_WE1 (17*8192)          // [f][32], K=4 padded
#define OFF_WN1 (17*8192+4096)     // [f][32], K=8 padded
#define WT_USHORTS (17*8192+8192)

// ---------------- bf16 helpers ----------------

__device__ __forceinline__ void split2(float x, unsigned short& h, unsigned short& l) {
    union { float f; unsigned u; } a, hf, b;
    a.f = x;
    const unsigned hb = (a.u + 0x7FFFu + ((a.u >> 16) & 1u)) >> 16;  // RNE hi
    hf.u = hb << 16;
    b.f = x - hf.f;                  // exact
    h = (unsigned short)hb;
    l = (unsigned short)(b.u >> 16); // truncated lo: err <= 2^-16 |x|
}

__device__ __forceinline__ float bf2f(unsigned short s) {
    union { unsigned u; float f; } a; a.u = ((unsigned)s) << 16; return a.f;
}

__device__ __forceinline__ float uph(unsigned u) {
    union { unsigned x; float f; } a; a.x = u & 0xFFFF0000u; return a.f;
}
__device__ __forceinline__ float upl(unsigned u) {
    union { unsigned x; float f; } a; a.x = u << 16; return a.f;
}

// packed split: hw = {bf16(x1)<<16 | bf16(x0)}, lw = matching truncated residuals.
// hi identical to split2's RNE; lo = trunc_bf16(x - hi.f) identical.
__device__ __forceinline__ unsigned cvtpk_bf16(float a, float b) {
    unsigned r;
    asm("v_cvt_pk_bf16_f32 %0, %1, %2" : "=v"(r) : "v"(a), "v"(b));
    return r;
}
__device__ __forceinline__ void split_pair(float x0, float x1, unsigned& hw, unsigned& lw) {
    hw = cvtpk_bf16(x0, x1);
    union { unsigned u; float f; } h0, h1, r0, r1;
    h0.u = hw << 16;
    h1.u = hw & 0xFFFF0000u;
    r0.f = x0 - h0.f;
    r1.f = x1 - h1.f;
    lw = (r0.u >> 16) | (r1.u & 0xFFFF0000u);
}

// A-frags for one 16-feature slice of a 64x64 weight: [chunk][plane]
__device__ __forceinline__ void load_wf(const unsigned short* __restrict__ wm,
                                        int ft, int l15, int quad, short8 (&w)[2][2]) {
#pragma unroll
    for (int c = 0; c < 2; ++c) {
        const int el = (ft * 16 + l15) * 64 + c * 32 + quad * 8;
        w[c][0] = *(const short8*)(wm + el);
        w[c][1] = *(const short8*)(wm + 4096 + el);
    }
}

// D += Ah*Bh + Al*Bh + Ah*Bl over K=64 (2 chunks)
__device__ __forceinline__ f32x4 chain6(const short8 (&w)[2][2],
                                        short8 bh0, short8 bh1,
                                        short8 bl0, short8 bl1, f32x4 a) {
    a = MFMA(w[0][0], bh0, a, 0, 0, 0);
    a = MFMA(w[1][0], bh1, a, 0, 0, 0);
    a = MFMA(w[0][1], bh0, a, 0, 0, 0);
    a = MFMA(w[1][1], bh1, a, 0, 0, 0);
    a = MFMA(w[0][0], bl0, a, 0, 0, 0);
    a = MFMA(w[1][0], bl1, a, 0, 0, 0);
    return a;
}

// ======== 4-tile helpers (node kernels, 256 thr) — R8 verbatim ========

__device__ __forceinline__ void gemm_planes(const unsigned short* pHi, const unsigned short* pLo,
                                            const short8 (&w)[2][2], int l15, int quad,
                                            f32x4 (&acc)[4]) {
#pragma unroll
    for (int et = 0; et < 4; ++et) {
        const int e = et * 16 + l15;
        const short8 bh0 = *(const short8*)(pHi + e * LDK + quad * 8);
        const short8 bh1 = *(const short8*)(pHi + e * LDK + 32 + quad * 8);
        const short8 bl0 = *(const short8*)(pLo + e * LDK + quad * 8);
        const short8 bl1 = *(const short8*)(pLo + e * LDK + 32 + quad * 8);
        acc[et] = chain6(w, bh0, bh1, bl0, bl1, acc[et]);
    }
}

__device__ __forceinline__ void set_bias(f32x4 (&acc)[4], const float* __restrict__ b, int f0) {
    const float4 b4 = *(const float4*)(b + f0);
#pragma unroll
    for (int et = 0; et < 4; ++et) {
        acc[et][0] = b4.x; acc[et][1] = b4.y; acc[et][2] = b4.z; acc[et][3] = b4.w;
    }
}

__device__ __forceinline__ void set_zero(f32x4 (&acc)[4]) {
#pragma unroll
    for (int et = 0; et < 4; ++et)
#pragma unroll
        for (int r = 0; r < 4; ++r) acc[et][r] = 0.f;
}

__device__ __forceinline__ void relu4(f32x4 (&acc)[4]) {
#pragma unroll
    for (int et = 0; et < 4; ++et)
#pragma unroll
        for (int r = 0; r < 4; ++r) acc[et][r] = fmaxf(acc[et][r], 0.f);
}

__device__ __forceinline__ void store_split_planes(unsigned short* pHi, unsigned short* pLo,
                                                   const f32x4 (&acc)[4], int l15, int f0) {
#pragma unroll
    for (int et = 0; et < 4; ++et) {
        const int e = et * 16 + l15;
        union { unsigned short u[4]; short4v v; } h, l;
#pragma unroll
        for (int r = 0; r < 4; ++r) split2(acc[et][r], h.u[r], l.u[r]);
        *(short4v*)(pHi + e * LDK + f0) = h.v;
        *(short4v*)(pLo + e * LDK + f0) = l.v;
    }
}

// stage fp32 [64][64] tile -> split hi/lo planes; invalid rows zero
__device__ __forceinline__ void stage_split64(unsigned short* pHi, unsigned short* pLo,
                                              const float* g, long rowBase, int t, int nValid) {
    const int row = t >> 2, q = t & 3;
    const bool valid = row < nValid;
#pragma unroll
    for (int i = 0; i < 4; ++i) {
        const int col = q * 16 + i * 4;
        float4 v = make_float4(0.f, 0.f, 0.f, 0.f);
        if (valid) v = *(const float4*)(g + (size_t)(rowBase + row) * HH + col);
        union { unsigned short u[4]; short4v s; } h, l;
        split2(v.x, h.u[0], l.u[0]); split2(v.y, h.u[1], l.u[1]);
        split2(v.z, h.u[2], l.u[2]); split2(v.w, h.u[3], l.u[3]);
        *(short4v*)(pHi + row * LDK + col) = h.s;
        *(short4v*)(pLo + row * LDK + col) = l.s;
    }
}

// ======== 2-tile helpers (edge kernels, 512 thr / 8 waves) ========

__device__ __forceinline__ void gemm_planes2(const unsigned short* pHi, const unsigned short* pLo,
                                             const short8 (&w)[2][2], int rbase, int l15, int quad,
                                             f32x4 (&acc)[2]) {
#pragma unroll
    for (int et = 0; et < 2; ++et) {
        const int e = rbase + et * 16 + l15;
        const short8 bh0 = *(const short8*)(pHi + e * LDK + quad * 8);
        const short8 bh1 = *(const short8*)(pHi + e * LDK + 32 + quad * 8);
        const short8 bl0 = *(const short8*)(pLo + e * LDK + quad * 8);
        const short8 bl1 = *(const short8*)(pLo + e * LDK + 32 + quad * 8);
        acc[et] = chain6(w, bh0, bh1, bl0, bl1, acc[et]);
    }
}

__device__ __forceinline__ void set_bias2(f32x4 (&acc)[2], const float* __restrict__ b, int f0) {
    const float4 b4 = *(const float4*)(b + f0);
#pragma unroll
    for (int et = 0; et < 2; ++et) {
        acc[et][0] = b4.x; acc[et][1] = b4.y; acc[et][2] = b4.z; acc[et][3] = b4.w;
    }
}

__device__ __forceinline__ void set_zero2(f32x4 (&acc)[2]) {
#pragma unroll
    for (int et = 0; et < 2; ++et)
#pragma unroll
        for (int r = 0; r < 4; ++r) acc[et][r] = 0.f;
}

__device__ __forceinline__ void relu2(f32x4 (&acc)[2]) {
#pragma unroll
    for (int et = 0; et < 2; ++et)
#pragma unroll
        for (int r = 0; r < 4; ++r) acc[et][r] = fmaxf(acc[et][r], 0.f);
}

// store via packed cvt_pk split (numerics == split2)
__device__ __forceinline__ void store_split_planes2(unsigned short* pHi, unsigned short* pLo,
                                                    const f32x4 (&acc)[2], int rbase, int l15, int f0) {
#pragma unroll
    for (int et = 0; et < 2; ++et) {
        const int e = rbase + et * 16 + l15;
        unsigned hw0, lw0, hw1, lw1;
        split_pair(acc[et][0], acc[et][1], hw0, lw0);
        split_pair(acc[et][2], acc[et][3], hw1, lw1);
        uint2 hv; hv.x = hw0; hv.y = hw1;
        uint2 lv; lv.x = lw0; lv.y = lw1;
        *(uint2*)(pHi + e * LDK + f0) = hv;
        *(uint2*)(pLo + e * LDK + f0) = lv;
    }
}

// in-LDS segment sum (512-thread version: 8 lane-groups x 8 rows)
__device__ __forceinline__ void segsum_atomic8(const unsigned short* pHi, const unsigned short* pLo,
                                               const int* sDst, int t,
                                               float* __restrict__ agg) {
    const int f = t & 63, c0 = (t >> 6) * 8;
    float s = 0.f;
    int d = sDst[c0];
#pragma unroll
    for (int i = 0; i < 8; ++i) {
        const int r = c0 + i;
        s += bf2f(pHi[r * LDK + f]) + bf2f(pLo[r * LDK + f]);
        const int dn = (i == 7) ? -1 : sDst[r + 1];
        if (dn != d) {
            atomicAdd(&agg[(size_t)d * HH + f], s);
            s = 0.f; d = dn;
        }
    }
}

// ---------------- setup: split all weights, transposed [f][k] ----------------

__global__ void k_conv_w(const float* __restrict__ enc_n_w1, const float* __restrict__ enc_n_w2,
                         const float* __restrict__ enc_e_w1, const float* __restrict__ enc_e_w2,
                         const float* __restrict__ pe_w1, const float* __restrict__ pe_w2,
                         const float* __restrict__ pn_w1, const float* __restrict__ pn_w2,
                         const float* __restrict__ dw1, unsigned short* __restrict__ wt)
{
    const int i = blockIdx.x * 256 + threadIdx.x;
    if (i < 17 * 4096) {
        const int m = i >> 12, r = i & 4095;
        const int f = r & 63, k = r >> 6;
        const float* W;
        switch (m) {
            case S_WE2:   W = enc_e_w2; break;
            case S_W1E0:  W = pe_w1; break;
            case S_W2E0:  W = pe_w2; break;
            case S_W1E1:  W = pe_w1 + 192 * 64; break;
            case S_W2E1:  W = pe_w2 + 64 * 64; break;
            case S_WN2:   W = enc_n_w2; break;
            case S_W1S0:  W = pe_w1 + 64 * 64; break;
            case S_W1D0:  W = pe_w1 + 128 * 64; break;
            case S_W1S1:  W = pe_w1 + 192 * 64 + 64 * 64; break;
            case S_W1D1:  W = pe_w1 + 192 * 64 + 128 * 64; break;
            case S_W1NX0: W = pn_w1; break;
            case S_W1NA0: W = pn_w1 + 64 * 64; break;
            case S_W2N0:  W = pn_w2; break;
            case S_W1NX1: W = pn_w1 + 128 * 64; break;
            case S_W1NA1: W = pn_w1 + 128 * 64 + 64 * 64; break;
            case S_W2N1:  W = pn_w2 + 64 * 64; break;
            default:      W = dw1; break;
        }
        unsigned short h, l; split2(W[r], h, l);    // W[k*64+f]
        wt[m * 8192 + f * 64 + k] = h;
        wt[m * 8192 + 4096 + f * 64 + k] = l;
    } else if (i < 17 * 4096 + 2048) {
        const int r = i - 17 * 4096, f = r >> 5, k = r & 31;
        const float v = (k < 4) ? enc_e_w1[k * 64 + f] : 0.f;
        unsigned short h, l; split2(v, h, l);
        wt[OFF_WE1 + f * 32 + k] = h;
        wt[OFF_WE1 + 2048 + f * 32 + k] = l;
    } else if (i < 17 * 4096 + 4096) {
        const int r = i - 17 * 4096 - 2048, f = r >> 5, k = r & 31;
        const float v = (k < 8) ? enc_n_w1[k * 64 + f] : 0.f;
        unsigned short h, l; split2(v, h, l);
        wt[OFF_WN1 + f * 32 + k] = h;
        wt[OFF_WN1 + 2048 + f * 32 + k] = l;
    }
}

// ---------------- CSR build ----------------

__global__ void k_deg(const int* __restrict__ eidx, unsigned* __restrict__ deg) {
    const int e = blockIdx.x * 256 + threadIdx.x;
    if (e < EE) atomicAdd(&deg[eidx[EE + e]], 1u);
}

__global__ __launch_bounds__(1024) void k_scan(unsigned* deg, unsigned* __restrict__ off) {
    __shared__ unsigned part[1024];
    const int t = threadIdx.x;
    const int CH = (NN + 1023) / 1024;
    const int s = t * CH, e = s + CH < NN ? s + CH : NN;
    unsigned sum = 0;
    for (int i = s; i < e; ++i) sum += deg[i];
    part[t] = sum;
    __syncthreads();
    for (int d = 1; d < 1024; d <<= 1) {
        unsigned v = (t >= d) ? part[t - d] : 0u;
        __syncthreads();
        if (t >= d) part[t] += v;
        __syncthreads();
    }
    unsigned base = (t > 0) ? part[t - 1] : 0u;
    for (int i = s; i < e; ++i) {
        const unsigned d = deg[i];
        off[i] = base;
        deg[i] = base;          // reuse as fill cursor
        base += d;
    }
    if (t == 1023) off[NN] = part[1023];
}

__global__ void k_fill(const int* __restrict__ eidx, unsigned* __restrict__ cur,
                       int* __restrict__ csr, int* __restrict__ srcs_s,
                       int* __restrict__ dsts_s) {
    const int e = blockIdx.x * 256 + threadIdx.x;
    if (e < EE) {
        const int d = eidx[EE + e];
        const unsigned p = atomicAdd(&cur[d], 1u);
        csr[p] = e;
        srcs_s[p] = eidx[e];
        dsts_s[p] = d;
    }
}

// ---------------- K2: edge encoder + layer-0 edge MLP + fused agg (512 thr) --------

__global__ __launch_bounds__(512) void k_edge_l0(
    const float* __restrict__ eattr, const int* __restrict__ csr,
    const int* __restrict__ srcs_s, const int* __restrict__ dsts_s,
    const float* __restrict__ Ps, const float* __restrict__ Pd,
    const float* __restrict__ be1, const float* __restrict__ be2,
    const unsigned short* __restrict__ wt,
    const float* __restrict__ pb1, const float* __restrict__ pb2,
    unsigned* __restrict__ epk, float* __restrict__ agg)
{
    __shared__ unsigned short pHhi[EPB * LDK], pHlo[EPB * LDK];
    __shared__ unsigned short pEhi[EPB * LDK], pElo[EPB * LDK];
    __shared__ int sDst[EPB];

    const int t = threadIdx.x;
    const int lane = t & 63, wid = t >> 6;      // 8 waves
    const int ft = wid & 3, half = wid >> 2;    // feature tile / row half
    const int quad = lane >> 4, l15 = lane & 15;
    const int f0 = ft * 16 + quad * 4;
    const int rbase = half * 32;                // this wave's 2 tiles: rows rbase..rbase+31
    const long eBase = (long)blockIdx.x * EPB;

    // stage eattr (gathered via csr): k 0..3 data, 4..31 zero. 8 thr/row, q<4 act.
    {
        const int row = t >> 3, q = t & 7;
        if (q == 0) {
            const int eid = csr[eBase + row];
            const float4 ea = *(const float4*)(eattr + (size_t)eid * 4);
            unsigned hw0, lw0, hw1, lw1;
            split_pair(ea.x, ea.y, hw0, lw0);
            split_pair(ea.z, ea.w, hw1, lw1);
            uint4 H; H.x = hw0; H.y = hw1; H.z = 0u; H.w = 0u;
            uint4 L; L.x = lw0; L.y = lw1; L.z = 0u; L.w = 0u;
            *(uint4*)(pHhi + row * LDK) = H;
            *(uint4*)(pHlo + row * LDK) = L;
        } else if (q < 4) {
            const uint4 z = {0u, 0u, 0u, 0u};
            *(uint4*)(pHhi + row * LDK + q * 8) = z;
            *(uint4*)(pHlo + row * LDK + q * 8) = z;
        }
    }
    if (t < EPB) sDst[t] = dsts_s[eBase + t];

    int srcs[2], dsts[2];
#pragma unroll
    for (int et = 0; et < 2; ++et) {
        const long p = eBase + rbase + et * 16 + l15;
        srcs[et] = srcs_s[p];
        dsts[et] = dsts_s[p];
    }
    // prefetch Ps/Pd gathers (consumed in phase3)
    float4 ps[2], pd[2];
#pragma unroll
    for (int et = 0; et < 2; ++et) {
        ps[et] = *(const float4*)(Ps + (size_t)srcs[et] * HH + f0);
        pd[et] = *(const float4*)(Pd + (size_t)dsts[et] * HH + f0);
    }
    __syncthreads();

    f32x4 acc[2];

    // phase1: h0 = relu(eattr @ We1 + be1) -> pE
    {
        short8 wa[2];
        const int el = (ft * 16 + l15) * 32 + quad * 8;
        wa[0] = *(const short8*)(wt + OFF_WE1 + el);
        wa[1] = *(const short8*)(wt + OFF_WE1 + 2048 + el);
        set_bias2(acc, be1, f0);
#pragma unroll
        for (int et = 0; et < 2; ++et) {
            const int e = rbase + et * 16 + l15;
            const short8 bh0 = *(const short8*)(pHhi + e * LDK + quad * 8);
            const short8 bl0 = *(const short8*)(pHlo + e * LDK + quad * 8);
            f32x4 a = acc[et];
            a = MFMA(wa[0], bh0, a, 0, 0, 0);
            a = MFMA(wa[1], bh0, a, 0, 0, 0);
            a = MFMA(wa[0], bl0, a, 0, 0, 0);
            acc[et] = a;
        }
        relu2(acc);
        store_split_planes2(pEhi, pElo, acc, rbase, l15, f0);
    }
    __syncthreads();

    // phase2: e0 = h0 @ We2 + be2 (regs) -> pH
    f32x4 e0s[2];
    {
        short8 w[2][2];
        load_wf(wt + S_WE2 * 8192, ft, l15, quad, w);
        set_bias2(acc, be2, f0);
        gemm_planes2(pEhi, pElo, w, rbase, l15, quad, acc);
#pragma unroll
        for (int et = 0; et < 2; ++et) e0s[et] = acc[et];
        store_split_planes2(pHhi, pHlo, acc, rbase, l15, f0);
    }
    __syncthreads();

    // phase3: t1 = relu(e0 @ W1e + Ps[src] + Pd[dst] + pb1) -> pE
    {
        short8 w[2][2];
        load_wf(wt + S_W1E0 * 8192, ft, l15, quad, w);
        set_zero2(acc);
        gemm_planes2(pHhi, pHlo, w, rbase, l15, quad, acc);
        const float4 b4 = *(const float4*)(pb1 + f0);
#pragma unroll
        for (int et = 0; et < 2; ++et) {
            acc[et][0] = fmaxf(acc[et][0] + ps[et].x + pd[et].x + b4.x, 0.f);
            acc[et][1] = fmaxf(acc[et][1] + ps[et].y + pd[et].y + b4.y, 0.f);
            acc[et][2] = fmaxf(acc[et][2] + ps[et].z + pd[et].z + b4.z, 0.f);
            acc[et][3] = fmaxf(acc[et][3] + ps[et].w + pd[et].w + b4.w, 0.f);
        }
        store_split_planes2(pEhi, pElo, acc, rbase, l15, f0);
    }
    __syncthreads();

    // phase4: e1 = e0(regs) + t1 @ W2e + pb2 -> pH
    {
        short8 w[2][2];
        load_wf(wt + S_W2E0 * 8192, ft, l15, quad, w);
        set_zero2(acc);
        gemm_planes2(pEhi, pElo, w, rbase, l15, quad, acc);
        const float4 b4 = *(const float4*)(pb2 + f0);
#pragma unroll
        for (int et = 0; et < 2; ++et) {
            acc[et][0] += e0s[et][0] + b4.x;
            acc[et][1] += e0s[et][1] + b4.y;
            acc[et][2] += e0s[et][2] + b4.z;
            acc[et][3] += e0s[et][3] + b4.w;
        }
        store_split_planes2(pHhi, pHlo, acc, rbase, l15, f0);
    }
    __syncthreads();

    // pack pH -> epk (coalesced; 8 thr/row, 8 ushorts each)
    {
        const int row = t >> 3, q = t & 7;
        const int lo = row * LDK + q * 8;
        const long go = (eBase + row) * HH + q * 8;
        union { unsigned short u[8]; uint4 v; } H, L;
        H.v = *(const uint4*)(pHhi + lo);
        L.v = *(const uint4*)(pHlo + lo);
        union { unsigned u[8]; uint4 v[2]; } o;
#pragma unroll
        for (int i = 0; i < 8; ++i) o.u[i] = ((unsigned)H.u[i] << 16) | L.u[i];
        *(uint4*)(epk + go) = o.v[0];
        *(uint4*)(epk + go + 4) = o.v[1];
    }
    // fused aggregation: agg[dst] += e1
    segsum_atomic8(pHhi, pHlo, sDst, t, agg);
}

// ---------------- K4: layer-1 edge MLP + fused agg (512 thr) ----------------

__global__ __launch_bounds__(512) void k_edge_l1(
    const int* __restrict__ srcs_s, const int* __restrict__ dsts_s,
    const float* __restrict__ Ps, const float* __restrict__ Pd,
    const unsigned short* __restrict__ wt,
    const float* __restrict__ pb1, const float* __restrict__ pb2,
    const unsigned* __restrict__ epk, float* __restrict__ agg)
{
    __shared__ unsigned short pEhi[EPB * LDK], pElo[EPB * LDK];
    __shared__ unsigned short pHhi[EPB * LDK], pHlo[EPB * LDK];
    __shared__ int sDst[EPB];

    const int t = threadIdx.x;
    const int lane = t & 63, wid = t >> 6;
    const int ft = wid & 3, half = wid >> 2;
    const int quad = lane >> 4, l15 = lane & 15;
    const int f0 = ft * 16 + quad * 4;
    const int rbase = half * 32;
    const long eBase = (long)blockIdx.x * EPB;

    // load epk -> deinterleave -> pE (8 thr/row, 8 words each)
    {
        const int row = t >> 3, q = t & 7;
        const int lo = row * LDK + q * 8;
        const long go = (eBase + row) * HH + q * 8;
        union { unsigned u[8]; uint4 v[2]; } in;
        in.v[0] = *(const uint4*)(epk + go);
        in.v[1] = *(const uint4*)(epk + go + 4);
        union { unsigned short u[8]; uint4 v; } H, L;
#pragma unroll
        for (int i = 0; i < 8; ++i) {
            H.u[i] = (unsigned short)(in.u[i] >> 16);
            L.u[i] = (unsigned short)(in.u[i] & 0xFFFFu);
        }
        *(uint4*)(pEhi + lo) = H.v;
        *(uint4*)(pElo + lo) = L.v;
    }
    if (t < EPB) sDst[t] = dsts_s[eBase + t];

    int srcs[2], dsts[2];
#pragma unroll
    for (int et = 0; et < 2; ++et) {
        const long p = eBase + rbase + et * 16 + l15;
        srcs[et] = srcs_s[p];
        dsts[et] = dsts_s[p];
    }
    // prefetch Ps/Pd gathers (consumed in t1 phase)
    float4 ps[2], pd[2];
#pragma unroll
    for (int et = 0; et < 2; ++et) {
        ps[et] = *(const float4*)(Ps + (size_t)srcs[et] * HH + f0);
        pd[et] = *(const float4*)(Pd + (size_t)dsts[et] * HH + f0);
    }
    __syncthreads();

    f32x4 acc[2];

    // t1 = relu(e1 @ W1e + Ps[src] + Pd[dst] + pb1) -> pH
    {
        short8 w[2][2];
        load_wf(wt + S_W1E1 * 8192, ft, l15, quad, w);
        set_zero2(acc);
        gemm_planes2(pEhi, pElo, w, rbase, l15, quad, acc);
        const float4 b4 = *(const float4*)(pb1 + f0);
#pragma unroll
        for (int et = 0; et < 2; ++et) {
            acc[et][0] = fmaxf(acc[et][0] + ps[et].x + pd[et].x + b4.x, 0.f);
            acc[et][1] = fmaxf(acc[et][1] + ps[et].y + pd[et].y + b4.y, 0.f);
            acc[et][2] = fmaxf(acc[et][2] + ps[et].z + pd[et].z + b4.z, 0.f);
            acc[et][3] = fmaxf(acc[et][3] + ps[et].w + pd[et].w + b4.w, 0.f);
        }
        store_split_planes2(pHhi, pHlo, acc, rbase, l15, f0);
    }
    __syncthreads();

    // e2 = e1(pE residual, own cells) + t1 @ W2e + pb2 -> pE
    {
        short8 w[2][2];
        load_wf(wt + S_W2E1 * 8192, ft, l15, quad, w);
        set_zero2(acc);
        gemm_planes2(pHhi, pHlo, w, rbase, l15, quad, acc);
        const float4 b4 = *(const float4*)(pb2 + f0);
#pragma unroll
        for (int et = 0; et < 2; ++et) {
            const int e = rbase + et * 16 + l15;
            const short4v hv = *(const short4v*)(pEhi + e * LDK + f0);
            const short4v lv = *(const short4v*)(pElo + e * LDK + f0);
            acc[et][0] += bf2f((unsigned short)hv[0]) + bf2f((unsigned short)lv[0]) + b4.x;
            acc[et][1] += bf2f((unsigned short)hv[1]) + bf2f((unsigned short)lv[1]) + b4.y;
            acc[et][2] += bf2f((unsigned short)hv[2]) + bf2f((unsigned short)lv[2]) + b4.z;
            acc[et][3] += bf2f((unsigned short)hv[3]) + bf2f((unsigned short)lv[3]) + b4.w;
        }
        store_split_planes2(pEhi, pElo, acc, rbase, l15, f0);   // own cells, same thread
    }
    __syncthreads();

    // fused aggregation: agg[dst] += e2
    segsum_atomic8(pEhi, pElo, sDst, t, agg);
}

// ---------------- K1: node encoder + layer-0 projections (256 thr, R8) --------

__global__ __launch_bounds__(256, 4) void k_encode_nodes(
    const float* __restrict__ x, const unsigned short* __restrict__ wt,
    const float* __restrict__ bn1, const float* __restrict__ bn2,
    float* __restrict__ x_h, float* __restrict__ Ps, float* __restrict__ Pd)
{
    __shared__ unsigned short pXhi[EPB * LDK], pXlo[EPB * LDK];
    __shared__ unsigned short pHhi[EPB * LDK], pHlo[EPB * LDK];

    const int t = threadIdx.x;
    const int lane = t & 63, ft = t >> 6;
    const int quad = lane >> 4, l15 = lane & 15;
    const int f0 = ft * 16 + quad * 4;
    const int nodeBase = blockIdx.x * 64;
    const int nValid = min(64, NN - nodeBase);

    // stage x (8 cols) padded to 32
    {
        const int row = t >> 2, q = t & 3;
        if (q == 0) {
            float4 a0 = make_float4(0.f, 0.f, 0.f, 0.f), a1 = a0;
            if (row < nValid) {
                a0 = *(const float4*)(x + (size_t)(nodeBase + row) * 8);
                a1 = *(const float4*)(x + (size_t)(nodeBase + row) * 8 + 4);
            }
            union { unsigned short u[8]; uint4 v; } H, L;
            split2(a0.x, H.u[0], L.u[0]); split2(a0.y, H.u[1], L.u[1]);
            split2(a0.z, H.u[2], L.u[2]); split2(a0.w, H.u[3], L.u[3]);
            split2(a1.x, H.u[4], L.u[4]); split2(a1.y, H.u[5], L.u[5]);
            split2(a1.z, H.u[6], L.u[6]); split2(a1.w, H.u[7], L.u[7]);
            *(uint4*)(pXhi + row * LDK) = H.v;
            *(uint4*)(pXlo + row * LDK) = L.v;
        } else {
            const uint4 z = {0u, 0u, 0u, 0u};
            *(uint4*)(pXhi + row * LDK + q * 8) = z;
            *(uint4*)(pXlo + row * LDK + q * 8) = z;
        }
    }
    __syncthreads();

    f32x4 acc[4];

    // phase1: h1 = relu(x @ wn1 + bn1) -> pH
    {
        short8 wa[2];
        const int el = (ft * 16 + l15) * 32 + quad * 8;
        wa[0] = *(const short8*)(wt + OFF_WN1 + el);
        wa[1] = *(const short8*)(wt + OFF_WN1 + 2048 + el);
        set_bias(acc, bn1, f0);
#pragma unroll
        for (int et = 0; et < 4; ++et) {
            const int e = et * 16 + l15;
            const short8 bh0 = *(const short8*)(pXhi + e * LDK + quad * 8);
            const short8 bl0 = *(const short8*)(pXlo + e * LDK + quad * 8);
            f32x4 a = acc[et];
            a = MFMA(wa[0], bh0, a, 0, 0, 0);
            a = MFMA(wa[1], bh0, a, 0, 0, 0);
            a = MFMA(wa[0], bl0, a, 0, 0, 0);
            acc[et] = a;
        }
        relu4(acc);
        store_split_planes(pHhi, pHlo, acc, l15, f0);
    }
    __syncthreads();

    // phase2: x_h = h1 @ wn2 + bn2 -> global + pX
    {
        short8 w[2][2];
        load_wf(wt + S_WN2 * 8192, ft, l15, quad, w);
        set_bias(acc, bn2, f0);
        gemm_planes(pHhi, pHlo, w, l15, quad, acc);
#pragma unroll
        for (int et = 0; et < 4; ++et) {
            const int r = et * 16 + l15;
            if (r < nValid) {
                float4 v = make_float4(acc[et][0], acc[et][1], acc[et][2], acc[et][3]);
                *(float4*)(x_h + (size_t)(nodeBase + r) * HH + f0) = v;
            }
        }
        store_split_planes(pXhi, pXlo, acc, l15, f0);
    }
    __syncthreads();

    // phase3: Ps = x_h @ W1s(l0)
    {
        short8 w[2][2];
        load_wf(wt + S_W1S0 * 8192, ft, l15, quad, w);
        set_zero(acc);
        gemm_planes(pXhi, pXlo, w, l15, quad, acc);
#pragma unroll
        for (int et = 0; et < 4; ++et) {
            const int r = et * 16 + l15;
            if (r < nValid) {
                float4 v = make_float4(acc[et][0], acc[et][1], acc[et][2], acc[et][3]);
                *(float4*)(Ps + (size_t)(nodeBase + r) * HH + f0) = v;
            }
        }
    }
    // phase4: Pd = x_h @ W1d(l0)  (read-only on planes, no barrier needed)
    {
        short8 w[2][2];
        load_wf(wt + S_W1D0 * 8192, ft, l15, quad, w);
        set_zero(acc);
        gemm_planes(pXhi, pXlo, w, l15, quad, acc);
#pragma unroll
        for (int et = 0; et < 4; ++et) {
            const int r = et * 16 + l15;
            if (r < nValid) {
                float4 v = make_float4(acc[et][0], acc[et][1], acc[et][2], acc[et][3]);
                *(float4*)(Pd + (size_t)(nodeBase + r) * HH + f0) = v;
            }
        }
    }
}

// ---------------- K3: node update l0 + layer-1 projections (256 thr, R8) --------

__global__ __launch_bounds__(256, 4) void k_node_l0(
    float* x_h, const float* agg, const unsigned short* __restrict__ wt,
    const float* __restrict__ nb1, const float* __restrict__ nb2,
    float* Ps, float* __restrict__ Pd)
{
    __shared__ unsigned short pXhi[EPB * LDK], pXlo[EPB * LDK];
    __shared__ unsigned short pAhi[EPB * LDK], pAlo[EPB * LDK];

    const int t = threadIdx.x;
    const int lane = t & 63, ft = t >> 6;
    const int quad = lane >> 4, l15 = lane & 15;
    const int f0 = ft * 16 + quad * 4;
    const int nodeBase = blockIdx.x * 64;
    const int nValid = min(64, NN - nodeBase);

    stage_split64(pXhi, pXlo, x_h, nodeBase, t, nValid);
    stage_split64(pAhi, pAlo, agg, nodeBase, t, nValid);
    __syncthreads();

    f32x4 acc[4];

    // t1 = relu(x_h @ W1x + agg @ W1a + nb1)
    {
        short8 w[2][2];
        load_wf(wt + S_W1NX0 * 8192, ft, l15, quad, w);
        set_bias(acc, nb1, f0);
        gemm_planes(pXhi, pXlo, w, l15, quad, acc);
        load_wf(wt + S_W1NA0 * 8192, ft, l15, quad, w);
        gemm_planes(pAhi, pAlo, w, l15, quad, acc);
        relu4(acc);
    }
    __syncthreads();                       // pA reads complete
    store_split_planes(pAhi, pAlo, acc, l15, f0);   // t1 -> pA
    __syncthreads();

    // x_h1 = x_h + t1 @ W2n + nb2 -> global + pX
    {
        short8 w[2][2];
        load_wf(wt + S_W2N0 * 8192, ft, l15, quad, w);
        set_bias(acc, nb2, f0);
        gemm_planes(pAhi, pAlo, w, l15, quad, acc);
#pragma unroll
        for (int et = 0; et < 4; ++et) {
            const int r = et * 16 + l15;
            if (r < nValid) {
                const size_t gi = (size_t)(nodeBase + r) * HH + f0;
                const float4 xr = *(const float4*)(x_h + gi);
                acc[et][0] += xr.x; acc[et][1] += xr.y;
                acc[et][2] += xr.z; acc[et][3] += xr.w;
                float4 v = make_float4(acc[et][0], acc[et][1], acc[et][2], acc[et][3]);
                *(float4*)(x_h + gi) = v;
            }
        }
        store_split_planes(pXhi, pXlo, acc, l15, f0);
    }
    __syncthreads();

    // Ps1 = x_h1 @ W1s(l1)
    {
        short8 w[2][2];
        load_wf(wt + S_W1S1 * 8192, ft, l15, quad, w);
        set_zero(acc);
        gemm_planes(pXhi, pXlo, w, l15, quad, acc);
#pragma unroll
        for (int et = 0; et < 4; ++et) {
            const int r = et * 16 + l15;
            if (r < nValid) {
                float4 v = make_float4(acc[et][0], acc[et][1], acc[et][2], acc[et][3]);
                *(float4*)(Ps + (size_t)(nodeBase + r) * HH + f0) = v;
            }
        }
    }
    // Pd1 = x_h1 @ W1d(l1)
    {
        short8 w[2][2];
        load_wf(wt + S_W1D1 * 8192, ft, l15, quad, w);
        set_zero(acc);
        gemm_planes(pXhi, pXlo, w, l15, quad, acc);
#pragma unroll
        for (int et = 0; et < 4; ++et) {
            const int r = et * 16 + l15;
            if (r < nValid) {
                float4 v = make_float4(acc[et][0], acc[et][1], acc[et][2], acc[et][3]);
                *(float4*)(Pd + (size_t)(nodeBase + r) * HH + f0) = v;
            }
        }
    }
}

// ---------------- K5: node update l1 + decoder (256 thr, R8) ----------------

__global__ __launch_bounds__(256, 4) void k_node_l1_dec(
    const float* x_h, const float* agg, const unsigned short* __restrict__ wt,
    const float* __restrict__ nb1, const float* __restrict__ nb2,
    const float* __restrict__ db1, const float* __restrict__ dw2,
    const float* __restrict__ db2, float* __restrict__ out)
{
    __shared__ unsigned short pXhi[EPB * LDK], pXlo[EPB * LDK];
    __shared__ unsigned short pAhi[EPB * LDK], pAlo[EPB * LDK];
    __shared__ float sW2[64 * 6];

    const int t = threadIdx.x;
    const int lane = t & 63, ft = t >> 6;
    const int quad = lane >> 4, l15 = lane & 15;
    const int f0 = ft * 16 + quad * 4;
    const int nodeBase = blockIdx.x * 64;
    const int nValid = min(64, NN - nodeBase);

    stage_split64(pXhi, pXlo, x_h, nodeBase, t, nValid);
    stage_split64(pAhi, pAlo, agg, nodeBase, t, nValid);
    if (t < 192) {
        sW2[t] = dw2[t];
        sW2[t + 192] = dw2[t + 192];
    }
    __syncthreads();

    f32x4 acc[4];

    // t1 = relu(x_h @ W1x + agg @ W1a + nb1)
    {
        short8 w[2][2];
        load_wf(wt + S_W1NX1 * 8192, ft, l15, quad, w);
        set_bias(acc, nb1, f0);
        gemm_planes(pXhi, pXlo, w, l15, quad, acc);
        load_wf(wt + S_W1NA1 * 8192, ft, l15, quad, w);
        gemm_planes(pAhi, pAlo, w, l15, quad, acc);
        relu4(acc);
    }
    __syncthreads();
    store_split_planes(pAhi, pAlo, acc, l15, f0);   // t1 -> pA
    __syncthreads();

    // x_h2 = x_h + t1 @ W2n + nb2 -> pX (no global writeback needed)
    {
        short8 w[2][2];
        load_wf(wt + S_W2N1 * 8192, ft, l15, quad, w);
        set_bias(acc, nb2, f0);
        gemm_planes(pAhi, pAlo, w, l15, quad, acc);
#pragma unroll
        for (int et = 0; et < 4; ++et) {
            const int r = et * 16 + l15;
            if (r < nValid) {
                const float4 xr = *(const float4*)(x_h + (size_t)(nodeBase + r) * HH + f0);
                acc[et][0] += xr.x; acc[et][1] += xr.y;
                acc[et][2] += xr.z; acc[et][3] += xr.w;
            }
        }
        store_split_planes(pXhi, pXlo, acc, l15, f0);
    }
    __syncthreads();

    // d1 = relu(x_h2 @ dec_w1 + db1) -> pA
    {
        short8 w[2][2];
        load_wf(wt + S_DW1 * 8192, ft, l15, quad, w);
        set_bias(acc, db1, f0);
        gemm_planes(pXhi, pXlo, w, l15, quad, acc);
        relu4(acc);
        store_split_planes(pAhi, pAlo, acc, l15, f0);
    }
    __syncthreads();

    // out = d1 @ dec_w2 + db2  (64 nodes x 6)
    if (t < 64 && t < nValid) {
        float o[6];
#pragma unroll
        for (int c = 0; c < 6; ++c) o[c] = db2[c];
#pragma unroll 8
        for (int k = 0; k < 64; ++k) {
            const float a = bf2f(pAhi[t * LDK + k]) + bf2f(pAlo[t * LDK + k]);
#pragma unroll
            for (int c = 0; c < 6; ++c) o[c] = fmaf(a, sW2[k * 6 + c], o[c]);
        }
        float* op = out + (size_t)(nodeBase + t) * 6;
#pragma unroll
        for (int c = 0; c < 6; ++c) op[c] = o[c];
    }
}

// ---------------- launcher ----------------

extern "C" void kernel_launch(void* const* d_in, const int* in_sizes, int n_in,
                              void* d_out, int out_size, void* d_ws, size_t ws_size,
                              hipStream_t stream) {
    const float* x        = (const float*)d_in[0];
    const float* eattr    = (const float*)d_in[1];
    const int*   eidx     = (const int*)d_in[2];
    const float* enc_n_w1 = (const float*)d_in[3];
    const float* enc_n_b1 = (const float*)d_in[4];
    const float* enc_n_w2 = (const float*)d_in[5];
    const float* enc_n_b2 = (const float*)d_in[6];
    const float* enc_e_w1 = (const float*)d_in[7];
    const float* enc_e_b1 = (const float*)d_in[8];
    const float* enc_e_w2 = (const float*)d_in[9];
    const float* enc_e_b2 = (const float*)d_in[10];
    const float* pe_w1    = (const float*)d_in[11];  // [2,192,64]
    const float* pe_b1    = (const float*)d_in[12];  // [2,64]
    const float* pe_w2    = (const float*)d_in[13];  // [2,64,64]
    const float* pe_b2    = (const float*)d_in[14];  // [2,64]
    const float* pn_w1    = (const float*)d_in[15];  // [2,128,64]
    const float* pn_b1    = (const float*)d_in[16];
    const float* pn_w2    = (const float*)d_in[17];  // [2,64,64]
    const float* pn_b2    = (const float*)d_in[18];
    const float* dw1      = (const float*)d_in[19];
    const float* db1      = (const float*)d_in[20];
    const float* dw2      = (const float*)d_in[21];
    const float* db2      = (const float*)d_in[22];
    float* out = (float*)d_out;

    // ws: x_h | Ps | Pd | agg | epk | off | deg | csr | srcs_s | dsts_s | wt
    const size_t NNHH = (size_t)NN * HH;
    float* ws  = (float*)d_ws;
    float* x_h = ws;
    float* Ps  = ws + NNHH;
    float* Pd  = ws + 2 * NNHH;
    float* agg = ws + 3 * NNHH;
    unsigned* epk = (unsigned*)(ws + 4 * NNHH);           // EE*HH uints
    unsigned* off = epk + (size_t)EE * HH;                // NN+1
    unsigned* deg = off + (NN + 1);                       // NN, reused as cursor
    int* csr    = (int*)(deg + NN);                       // EE
    int* srcs_s = csr + EE;                               // EE
    int* dsts_s = srcs_s + EE;                            // EE
    unsigned short* wt = (unsigned short*)(dsts_s + EE);  // WT_USHORTS

    const int nodeBlocks = (NN + 63) / 64;   // 782
    const int edgeBlocks = EE / EPB;         // 12500
    const int eScal      = (EE + 255) / 256; // 3125

    hipMemsetAsync(deg, 0, (size_t)NN * sizeof(unsigned), stream);
    hipMemsetAsync(agg, 0, NNHH * sizeof(float), stream);

    k_conv_w<<<288, 256, 0, stream>>>(
        enc_n_w1, enc_n_w2, enc_e_w1, enc_e_w2,
        pe_w1, pe_w2, pn_w1, pn_w2, dw1, wt);

    k_deg<<<eScal, 256, 0, stream>>>(eidx, deg);
    k_scan<<<1, 1024, 0, stream>>>(deg, off);
    k_fill<<<eScal, 256, 0, stream>>>(eidx, deg, csr, srcs_s, dsts_s);

    k_encode_nodes<<<nodeBlocks, 256, 0, stream>>>(
        x, wt, enc_n_b1, enc_n_b2, x_h, Ps, Pd);

    k_edge_l0<<<edgeBlocks, 512, 0, stream>>>(
        eattr, csr, srcs_s, dsts_s, Ps, Pd,
        enc_e_b1, enc_e_b2, wt, pe_b1, pe_b2, epk, agg);

    k_node_l0<<<nodeBlocks, 256, 0, stream>>>(
        x_h, agg, wt, pn_b1, pn_b2, Ps, Pd);

    hipMemsetAsync(agg, 0, NNHH * sizeof(float), stream);

    k_edge_l1<<<edgeBlocks, 512, 0, stream>>>(
        srcs_s, dsts_s, Ps, Pd, wt, pe_b1 + 64, pe_b2 + 64, epk, agg);

    k_node_l1_dec<<<nodeBlocks, 256, 0, stream>>>(
        x_h, agg, wt, pn_b1 + 64, pn_b2 + 64,
        db1, dw2, db2, out);
}

// Round 6
// 722.924 us; speedup vs baseline: 1.4715x; 1.0502x over previous
//
#include <hip/hip_runtime.h>

// GNN: N=50000 nodes, E=800000 edges, H=64, L=2.
// R12: barrier-overhead attack. Evidence: R9 (0 tiles of cross-wave overlap)
// and R11 (2 tiles/wave) both lost to R8 (4 tiles/wave) with identical total
// pipe work -> edge kernels are barrier-bound. So: EPE=128 edges/block,
// 256 thr / 4 waves, 8 row-tiles per wave -> barriers per edge HALVED,
// inter-barrier ILP doubled. LDS 74KB -> 2 blocks/CU (issue-bound, ok).
// cvt_pk-based split everywhere (numerics verified identical in R11).
// Node kernels keep R8 structure (EPB=64, 256 thr).
// Pipeline: conv_w | CSR | encode | edge_l0(+agg) | node_l0 | memset |
//           edge_l1(+agg) | node_l1+dec.

#define NN 50000
#define EE 800000
#define HH 64
#define LDK 72   // bf16 plane leading dim (144 B row)
#define EPB 64   // node rows per block
#define EPE 128  // edge rows per block

typedef short short8 __attribute__((ext_vector_type(8)));
typedef short short4v __attribute__((ext_vector_type(4)));
typedef float f32x4 __attribute__((ext_vector_type(4)));

#define MFMA __builtin_amdgcn_mfma_f32_16x16x32_bf16

// wt slots (each 8192 ushorts: 4096 hi + 4096 lo, layout [f][k])
#define S_WE2   0
#define S_W1E0  1
#define S_W2E0  2
#define S_W1E1  3
#define S_W2E1  4
#define S_WN2   5
#define S_W1S0  6
#define S_W1D0  7
#define S_W1S1  8
#define S_W1D1  9
#define S_W1NX0 10
#define S_W1NA0 11
#define S_W2N0  12
#define S_W1NX1 13
#define S_W1NA1 14
#define S_W2N1  15
#define S_DW1   16
#define OFF_WE1 (17*8192)          // [f][32], K=4 padded
#define OFF_WN1 (17*8192+4096)     // [f][32], K=8 padded
#define WT_USHORTS (17*8192+8192)

// ---------------- bf16 helpers ----------------

__device__ __forceinline__ void split2(float x, unsigned short& h, unsigned short& l) {
    union { float f; unsigned u; } a, hf, b;
    a.f = x;
    const unsigned hb = (a.u + 0x7FFFu + ((a.u >> 16) & 1u)) >> 16;  // RNE hi
    hf.u = hb << 16;
    b.f = x - hf.f;                  // exact
    h = (unsigned short)hb;
    l = (unsigned short)(b.u >> 16); // truncated lo: err <= 2^-16 |x|
}

__device__ __forceinline__ float bf2f(unsigned short s) {
    union { unsigned u; float f; } a; a.u = ((unsigned)s) << 16; return a.f;
}

__device__ __forceinline__ float uph(unsigned u) {
    union { unsigned x; float f; } a; a.x = u & 0xFFFF0000u; return a.f;
}
__device__ __forceinline__ float upl(unsigned u) {
    union { unsigned x; float f; } a; a.x = u << 16; return a.f;
}

// packed split: hw = {bf16(x1)<<16 | bf16(x0)}, lw = matching truncated residuals.
// hi identical to split2's RNE (verified: R11 absmax bit-identical); lo = exact
// residual truncated to bf16.
__device__ __forceinline__ unsigned cvtpk_bf16(float a, float b) {
    unsigned r;
    asm("v_cvt_pk_bf16_f32 %0, %1, %2" : "=v"(r) : "v"(a), "v"(b));
    return r;
}
__device__ __forceinline__ void split_pair(float x0, float x1, unsigned& hw, unsigned& lw) {
    hw = cvtpk_bf16(x0, x1);
    union { unsigned u; float f; } h0, h1, r0, r1;
    h0.u = hw << 16;
    h1.u = hw & 0xFFFF0000u;
    r0.f = x0 - h0.f;
    r1.f = x1 - h1.f;
    lw = (r0.u >> 16) | (r1.u & 0xFFFF0000u);
}

// A-frags for one 16-feature slice of a 64x64 weight: [chunk][plane]
__device__ __forceinline__ void load_wf(const unsigned short* __restrict__ wm,
                                        int ft, int l15, int quad, short8 (&w)[2][2]) {
#pragma unroll
    for (int c = 0; c < 2; ++c) {
        const int el = (ft * 16 + l15) * 64 + c * 32 + quad * 8;
        w[c][0] = *(const short8*)(wm + el);
        w[c][1] = *(const short8*)(wm + 4096 + el);
    }
}

// D += Ah*Bh + Al*Bh + Ah*Bl over K=64 (2 chunks)
__device__ __forceinline__ f32x4 chain6(const short8 (&w)[2][2],
                                        short8 bh0, short8 bh1,
                                        short8 bl0, short8 bl1, f32x4 a) {
    a = MFMA(w[0][0], bh0, a, 0, 0, 0);
    a = MFMA(w[1][0], bh1, a, 0, 0, 0);
    a = MFMA(w[0][1], bh0, a, 0, 0, 0);
    a = MFMA(w[1][1], bh1, a, 0, 0, 0);
    a = MFMA(w[0][0], bl0, a, 0, 0, 0);
    a = MFMA(w[1][0], bl1, a, 0, 0, 0);
    return a;
}

// one row-tile GEMM step: acc += W @ B(row e)
__device__ __forceinline__ void gemm_tile(const unsigned short* pHi, const unsigned short* pLo,
                                          const short8 (&w)[2][2], int e, int quad, f32x4& a) {
    const short8 bh0 = *(const short8*)(pHi + e * LDK + quad * 8);
    const short8 bh1 = *(const short8*)(pHi + e * LDK + 32 + quad * 8);
    const short8 bl0 = *(const short8*)(pLo + e * LDK + quad * 8);
    const short8 bl1 = *(const short8*)(pLo + e * LDK + 32 + quad * 8);
    a = chain6(w, bh0, bh1, bl0, bl1, a);
}

// store 4 feats of row e via packed cvt split
__device__ __forceinline__ void store_row4(unsigned short* pHi, unsigned short* pLo,
                                           const f32x4& a, int e, int f0) {
    unsigned hw0, lw0, hw1, lw1;
    split_pair(a[0], a[1], hw0, lw0);
    split_pair(a[2], a[3], hw1, lw1);
    uint2 hv; hv.x = hw0; hv.y = hw1;
    uint2 lv; lv.x = lw0; lv.y = lw1;
    *(uint2*)(pHi + e * LDK + f0) = hv;
    *(uint2*)(pLo + e * LDK + f0) = lv;
}

// ======== node-kernel (4-tile, 256 thr) helpers — R8 structure ========

__device__ __forceinline__ void gemm_planes(const unsigned short* pHi, const unsigned short* pLo,
                                            const short8 (&w)[2][2], int l15, int quad,
                                            f32x4 (&acc)[4]) {
#pragma unroll
    for (int et = 0; et < 4; ++et) {
        const int e = et * 16 + l15;
        gemm_tile(pHi, pLo, w, e, quad, acc[et]);
    }
}

__device__ __forceinline__ void set_bias(f32x4 (&acc)[4], const float* __restrict__ b, int f0) {
    const float4 b4 = *(const float4*)(b + f0);
#pragma unroll
    for (int et = 0; et < 4; ++et) {
        acc[et][0] = b4.x; acc[et][1] = b4.y; acc[et][2] = b4.z; acc[et][3] = b4.w;
    }
}

__device__ __forceinline__ void set_zero(f32x4 (&acc)[4]) {
#pragma unroll
    for (int et = 0; et < 4; ++et)
#pragma unroll
        for (int r = 0; r < 4; ++r) acc[et][r] = 0.f;
}

__device__ __forceinline__ void relu4(f32x4 (&acc)[4]) {
#pragma unroll
    for (int et = 0; et < 4; ++et)
#pragma unroll
        for (int r = 0; r < 4; ++r) acc[et][r] = fmaxf(acc[et][r], 0.f);
}

__device__ __forceinline__ void store_split_planes(unsigned short* pHi, unsigned short* pLo,
                                                   const f32x4 (&acc)[4], int l15, int f0) {
#pragma unroll
    for (int et = 0; et < 4; ++et) store_row4(pHi, pLo, acc[et], et * 16 + l15, f0);
}

// stage fp32 [64][64] tile -> split hi/lo planes; invalid rows zero
__device__ __forceinline__ void stage_split64(unsigned short* pHi, unsigned short* pLo,
                                              const float* g, long rowBase, int t, int nValid) {
    const int row = t >> 2, q = t & 3;
    const bool valid = row < nValid;
#pragma unroll
    for (int i = 0; i < 4; ++i) {
        const int col = q * 16 + i * 4;
        float4 v = make_float4(0.f, 0.f, 0.f, 0.f);
        if (valid) v = *(const float4*)(g + (size_t)(rowBase + row) * HH + col);
        unsigned hw0, lw0, hw1, lw1;
        split_pair(v.x, v.y, hw0, lw0);
        split_pair(v.z, v.w, hw1, lw1);
        uint2 hv; hv.x = hw0; hv.y = hw1;
        uint2 lv; lv.x = lw0; lv.y = lw1;
        *(uint2*)(pHi + row * LDK + col) = hv;
        *(uint2*)(pLo + row * LDK + col) = lv;
    }
}

// in-LDS segment sum over dst-sorted rows + atomic scatter (EPE rows, 4 waves)
__device__ __forceinline__ void segsum_atomicE(const unsigned short* pHi, const unsigned short* pLo,
                                               const int* sDst, int t,
                                               float* __restrict__ agg) {
    const int f = t & 63, c0 = (t >> 6) * 32;
    float s = 0.f;
    int d = sDst[c0];
#pragma unroll 8
    for (int i = 0; i < 32; ++i) {
        const int r = c0 + i;
        s += bf2f(pHi[r * LDK + f]) + bf2f(pLo[r * LDK + f]);
        const int dn = (i == 31) ? -1 : sDst[r + 1];
        if (dn != d) {
            atomicAdd(&agg[(size_t)d * HH + f], s);
            s = 0.f; d = dn;
        }
    }
}

// ---------------- setup: split all weights, transposed [f][k] ----------------

__global__ void k_conv_w(const float* __restrict__ enc_n_w1, const float* __restrict__ enc_n_w2,
                         const float* __restrict__ enc_e_w1, const float* __restrict__ enc_e_w2,
                         const float* __restrict__ pe_w1, const float* __restrict__ pe_w2,
                         const float* __restrict__ pn_w1, const float* __restrict__ pn_w2,
                         const float* __restrict__ dw1, unsigned short* __restrict__ wt)
{
    const int i = blockIdx.x * 256 + threadIdx.x;
    if (i < 17 * 4096) {
        const int m = i >> 12, r = i & 4095;
        const int f = r & 63, k = r >> 6;
        const float* W;
        switch (m) {
            case S_WE2:   W = enc_e_w2; break;
            case S_W1E0:  W = pe_w1; break;
            case S_W2E0:  W = pe_w2; break;
            case S_W1E1:  W = pe_w1 + 192 * 64; break;
            case S_W2E1:  W = pe_w2 + 64 * 64; break;
            case S_WN2:   W = enc_n_w2; break;
            case S_W1S0:  W = pe_w1 + 64 * 64; break;
            case S_W1D0:  W = pe_w1 + 128 * 64; break;
            case S_W1S1:  W = pe_w1 + 192 * 64 + 64 * 64; break;
            case S_W1D1:  W = pe_w1 + 192 * 64 + 128 * 64; break;
            case S_W1NX0: W = pn_w1; break;
            case S_W1NA0: W = pn_w1 + 64 * 64; break;
            case S_W2N0:  W = pn_w2; break;
            case S_W1NX1: W = pn_w1 + 128 * 64; break;
            case S_W1NA1: W = pn_w1 + 128 * 64 + 64 * 64; break;
            case S_W2N1:  W = pn_w2 + 64 * 64; break;
            default:      W = dw1; break;
        }
        unsigned short h, l; split2(W[r], h, l);    // W[k*64+f]
        wt[m * 8192 + f * 64 + k] = h;
        wt[m * 8192 + 4096 + f * 64 + k] = l;
    } else if (i < 17 * 4096 + 2048) {
        const int r = i - 17 * 4096, f = r >> 5, k = r & 31;
        const float v = (k < 4) ? enc_e_w1[k * 64 + f] : 0.f;
        unsigned short h, l; split2(v, h, l);
        wt[OFF_WE1 + f * 32 + k] = h;
        wt[OFF_WE1 + 2048 + f * 32 + k] = l;
    } else if (i < 17 * 4096 + 4096) {
        const int r = i - 17 * 4096 - 2048, f = r >> 5, k = r & 31;
        const float v = (k < 8) ? enc_n_w1[k * 64 + f] : 0.f;
        unsigned short h, l; split2(v, h, l);
        wt[OFF_WN1 + f * 32 + k] = h;
        wt[OFF_WN1 + 2048 + f * 32 + k] = l;
    }
}

// ---------------- CSR build ----------------

__global__ void k_deg(const int* __restrict__ eidx, unsigned* __restrict__ deg) {
    const int e = blockIdx.x * 256 + threadIdx.x;
    if (e < EE) atomicAdd(&deg[eidx[EE + e]], 1u);
}

__global__ __launch_bounds__(1024) void k_scan(unsigned* deg, unsigned* __restrict__ off) {
    __shared__ unsigned part[1024];
    const int t = threadIdx.x;
    const int CH = (NN + 1023) / 1024;
    const int s = t * CH, e = s + CH < NN ? s + CH : NN;
    unsigned sum = 0;
    for (int i = s; i < e; ++i) sum += deg[i];
    part[t] = sum;
    __syncthreads();
    for (int d = 1; d < 1024; d <<= 1) {
        unsigned v = (t >= d) ? part[t - d] : 0u;
        __syncthreads();
        if (t >= d) part[t] += v;
        __syncthreads();
    }
    unsigned base = (t > 0) ? part[t - 1] : 0u;
    for (int i = s; i < e; ++i) {
        const unsigned d = deg[i];
        off[i] = base;
        deg[i] = base;          // reuse as fill cursor
        base += d;
    }
    if (t == 1023) off[NN] = part[1023];
}

__global__ void k_fill(const int* __restrict__ eidx, unsigned* __restrict__ cur,
                       int* __restrict__ csr, int* __restrict__ srcs_s,
                       int* __restrict__ dsts_s) {
    const int e = blockIdx.x * 256 + threadIdx.x;
    if (e < EE) {
        const int d = eidx[EE + e];
        const unsigned p = atomicAdd(&cur[d], 1u);
        csr[p] = e;
        srcs_s[p] = eidx[e];
        dsts_s[p] = d;
    }
}

// ---------------- K2: edge encoder + layer-0 edge MLP + fused agg ----------------
// 256 thr / 4 waves; wave ft owns feature tile, 8 row-tiles (128 edges/block).

__global__ __launch_bounds__(256, 2) void k_edge_l0(
    const float* __restrict__ eattr, const int* __restrict__ csr,
    const int* __restrict__ srcs_s, const int* __restrict__ dsts_s,
    const float* __restrict__ Ps, const float* __restrict__ Pd,
    const float* __restrict__ be1, const float* __restrict__ be2,
    const unsigned short* __restrict__ wt,
    const float* __restrict__ pb1, const float* __restrict__ pb2,
    unsigned* __restrict__ epk, float* __restrict__ agg)
{
    __shared__ unsigned short pHhi[EPE * LDK], pHlo[EPE * LDK];
    __shared__ unsigned short pEhi[EPE * LDK], pElo[EPE * LDK];
    __shared__ int sDst[EPE];

    const int t = threadIdx.x;
    const int lane = t & 63, ft = t >> 6;
    const int quad = lane >> 4, l15 = lane & 15;
    const int f0 = ft * 16 + quad * 4;
    const long eBase = (long)blockIdx.x * EPE;

    // stage eattr (gathered via csr): k 0..3 data, 4..31 zero. 2 thr/row.
    {
        const int row = t >> 1, q = t & 1;
        const uint4 z = {0u, 0u, 0u, 0u};
        if (q == 0) {
            const int eid = csr[eBase + row];
            const float4 ea = *(const float4*)(eattr + (size_t)eid * 4);
            unsigned hw0, lw0, hw1, lw1;
            split_pair(ea.x, ea.y, hw0, lw0);
            split_pair(ea.z, ea.w, hw1, lw1);
            uint4 H; H.x = hw0; H.y = hw1; H.z = 0u; H.w = 0u;
            uint4 L; L.x = lw0; L.y = lw1; L.z = 0u; L.w = 0u;
            *(uint4*)(pHhi + row * LDK) = H;
            *(uint4*)(pHlo + row * LDK) = L;
            *(uint4*)(pHhi + row * LDK + 8) = z;
            *(uint4*)(pHlo + row * LDK + 8) = z;
        } else {
            *(uint4*)(pHhi + row * LDK + 16) = z;
            *(uint4*)(pHlo + row * LDK + 16) = z;
            *(uint4*)(pHhi + row * LDK + 24) = z;
            *(uint4*)(pHlo + row * LDK + 24) = z;
        }
    }
    if (t < EPE) sDst[t] = dsts_s[eBase + t];

    int srcs[8], dsts[8];
#pragma unroll
    for (int et = 0; et < 8; ++et) {
        const long p = eBase + et * 16 + l15;
        srcs[et] = srcs_s[p];
        dsts[et] = dsts_s[p];
    }
    // prefetch Ps/Pd gathers (consumed in phase3)
    float4 ps[8], pd[8];
#pragma unroll
    for (int et = 0; et < 8; ++et) {
        ps[et] = *(const float4*)(Ps + (size_t)srcs[et] * HH + f0);
        pd[et] = *(const float4*)(Pd + (size_t)dsts[et] * HH + f0);
    }
    __syncthreads();

    // phase1: h0 = relu(eattr @ We1 + be1) -> pE
    {
        short8 wa0, wa1;
        const int el = (ft * 16 + l15) * 32 + quad * 8;
        wa0 = *(const short8*)(wt + OFF_WE1 + el);
        wa1 = *(const short8*)(wt + OFF_WE1 + 2048 + el);
        const float4 b4 = *(const float4*)(be1 + f0);
#pragma unroll
        for (int et = 0; et < 8; ++et) {
            const int e = et * 16 + l15;
            const short8 bh0 = *(const short8*)(pHhi + e * LDK + quad * 8);
            const short8 bl0 = *(const short8*)(pHlo + e * LDK + quad * 8);
            f32x4 a; a[0] = b4.x; a[1] = b4.y; a[2] = b4.z; a[3] = b4.w;
            a = MFMA(wa0, bh0, a, 0, 0, 0);
            a = MFMA(wa1, bh0, a, 0, 0, 0);
            a = MFMA(wa0, bl0, a, 0, 0, 0);
#pragma unroll
            for (int r = 0; r < 4; ++r) a[r] = fmaxf(a[r], 0.f);
            store_row4(pEhi, pElo, a, e, f0);
        }
    }
    __syncthreads();

    // phase2: e0 = h0 @ We2 + be2 -> pH (+ regs)
    f32x4 e0s[8];
    {
        short8 w[2][2];
        load_wf(wt + S_WE2 * 8192, ft, l15, quad, w);
        const float4 b4 = *(const float4*)(be2 + f0);
#pragma unroll
        for (int et = 0; et < 8; ++et) {
            const int e = et * 16 + l15;
            f32x4 a; a[0] = b4.x; a[1] = b4.y; a[2] = b4.z; a[3] = b4.w;
            gemm_tile(pEhi, pElo, w, e, quad, a);
            e0s[et] = a;
            store_row4(pHhi, pHlo, a, e, f0);
        }
    }
    __syncthreads();

    // phase3: t1 = relu(e0 @ W1e + Ps[src] + Pd[dst] + pb1) -> pE
    {
        short8 w[2][2];
        load_wf(wt + S_W1E0 * 8192, ft, l15, quad, w);
        const float4 b4 = *(const float4*)(pb1 + f0);
#pragma unroll
        for (int et = 0; et < 8; ++et) {
            const int e = et * 16 + l15;
            f32x4 a = {0.f, 0.f, 0.f, 0.f};
            gemm_tile(pHhi, pHlo, w, e, quad, a);
            a[0] = fmaxf(a[0] + ps[et].x + pd[et].x + b4.x, 0.f);
            a[1] = fmaxf(a[1] + ps[et].y + pd[et].y + b4.y, 0.f);
            a[2] = fmaxf(a[2] + ps[et].z + pd[et].z + b4.z, 0.f);
            a[3] = fmaxf(a[3] + ps[et].w + pd[et].w + b4.w, 0.f);
            store_row4(pEhi, pElo, a, e, f0);
        }
    }
    __syncthreads();

    // phase4: e1 = e0(regs) + t1 @ W2e + pb2 -> pH
    {
        short8 w[2][2];
        load_wf(wt + S_W2E0 * 8192, ft, l15, quad, w);
        const float4 b4 = *(const float4*)(pb2 + f0);
#pragma unroll
        for (int et = 0; et < 8; ++et) {
            const int e = et * 16 + l15;
            f32x4 a = {0.f, 0.f, 0.f, 0.f};
            gemm_tile(pEhi, pElo, w, e, quad, a);
            a[0] += e0s[et][0] + b4.x;
            a[1] += e0s[et][1] + b4.y;
            a[2] += e0s[et][2] + b4.z;
            a[3] += e0s[et][3] + b4.w;
            store_row4(pHhi, pHlo, a, e, f0);
        }
    }
    __syncthreads();

    // pack pH -> epk (2 thr/row, 32 ushorts each)
    {
        const int row = t >> 1, q = t & 1;
#pragma unroll
        for (int i = 0; i < 4; ++i) {
            const int lo = row * LDK + q * 32 + i * 8;
            const long go = (eBase + row) * HH + q * 32 + i * 8;
            union { unsigned short u[8]; uint4 v; } H, L;
            H.v = *(const uint4*)(pHhi + lo);
            L.v = *(const uint4*)(pHlo + lo);
            union { unsigned u[8]; uint4 v[2]; } o;
#pragma unroll
            for (int j = 0; j < 8; ++j) o.u[j] = ((unsigned)H.u[j] << 16) | L.u[j];
            *(uint4*)(epk + go) = o.v[0];
            *(uint4*)(epk + go + 4) = o.v[1];
        }
    }
    // fused aggregation: agg[dst] += e1
    segsum_atomicE(pHhi, pHlo, sDst, t, agg);
}

// ---------------- K4: layer-1 edge MLP + fused agg ----------------

__global__ __launch_bounds__(256, 2) void k_edge_l1(
    const int* __restrict__ srcs_s, const int* __restrict__ dsts_s,
    const float* __restrict__ Ps, const float* __restrict__ Pd,
    const unsigned short* __restrict__ wt,
    const float* __restrict__ pb1, const float* __restrict__ pb2,
    const unsigned* __restrict__ epk, float* __restrict__ agg)
{
    __shared__ unsigned short pEhi[EPE * LDK], pElo[EPE * LDK];
    __shared__ unsigned short pHhi[EPE * LDK], pHlo[EPE * LDK];
    __shared__ int sDst[EPE];

    const int t = threadIdx.x;
    const int lane = t & 63, ft = t >> 6;
    const int quad = lane >> 4, l15 = lane & 15;
    const int f0 = ft * 16 + quad * 4;
    const long eBase = (long)blockIdx.x * EPE;

    // load epk -> deinterleave -> pE (2 thr/row, 32 words each)
    {
        const int row = t >> 1, q = t & 1;
#pragma unroll
        for (int i = 0; i < 4; ++i) {
            const int lo = row * LDK + q * 32 + i * 8;
            const long go = (eBase + row) * HH + q * 32 + i * 8;
            union { unsigned u[8]; uint4 v[2]; } in;
            in.v[0] = *(const uint4*)(epk + go);
            in.v[1] = *(const uint4*)(epk + go + 4);
            union { unsigned short u[8]; uint4 v; } H, L;
#pragma unroll
            for (int j = 0; j < 8; ++j) {
                H.u[j] = (unsigned short)(in.u[j] >> 16);
                L.u[j] = (unsigned short)(in.u[j] & 0xFFFFu);
            }
            *(uint4*)(pEhi + lo) = H.v;
            *(uint4*)(pElo + lo) = L.v;
        }
    }
    if (t < EPE) sDst[t] = dsts_s[eBase + t];

    int srcs[8], dsts[8];
#pragma unroll
    for (int et = 0; et < 8; ++et) {
        const long p = eBase + et * 16 + l15;
        srcs[et] = srcs_s[p];
        dsts[et] = dsts_s[p];
    }
    // prefetch Ps/Pd gathers (consumed in t1 phase)
    float4 ps[8], pd[8];
#pragma unroll
    for (int et = 0; et < 8; ++et) {
        ps[et] = *(const float4*)(Ps + (size_t)srcs[et] * HH + f0);
        pd[et] = *(const float4*)(Pd + (size_t)dsts[et] * HH + f0);
    }
    __syncthreads();

    // t1 = relu(e1 @ W1e + Ps[src] + Pd[dst] + pb1) -> pH
    {
        short8 w[2][2];
        load_wf(wt + S_W1E1 * 8192, ft, l15, quad, w);
        const float4 b4 = *(const float4*)(pb1 + f0);
#pragma unroll
        for (int et = 0; et < 8; ++et) {
            const int e = et * 16 + l15;
            f32x4 a = {0.f, 0.f, 0.f, 0.f};
            gemm_tile(pEhi, pElo, w, e, quad, a);
            a[0] = fmaxf(a[0] + ps[et].x + pd[et].x + b4.x, 0.f);
            a[1] = fmaxf(a[1] + ps[et].y + pd[et].y + b4.y, 0.f);
            a[2] = fmaxf(a[2] + ps[et].z + pd[et].z + b4.z, 0.f);
            a[3] = fmaxf(a[3] + ps[et].w + pd[et].w + b4.w, 0.f);
            store_row4(pHhi, pHlo, a, e, f0);
        }
    }
    __syncthreads();

    // e2 = e1(pE residual, own cells) + t1 @ W2e + pb2 -> pE
    {
        short8 w[2][2];
        load_wf(wt + S_W2E1 * 8192, ft, l15, quad, w);
        const float4 b4 = *(const float4*)(pb2 + f0);
#pragma unroll
        for (int et = 0; et < 8; ++et) {
            const int e = et * 16 + l15;
            f32x4 a = {0.f, 0.f, 0.f, 0.f};
            gemm_tile(pHhi, pHlo, w, e, quad, a);
            const short4v hv = *(const short4v*)(pEhi + e * LDK + f0);
            const short4v lv = *(const short4v*)(pElo + e * LDK + f0);
            a[0] += bf2f((unsigned short)hv[0]) + bf2f((unsigned short)lv[0]) + b4.x;
            a[1] += bf2f((unsigned short)hv[1]) + bf2f((unsigned short)lv[1]) + b4.y;
            a[2] += bf2f((unsigned short)hv[2]) + bf2f((unsigned short)lv[2]) + b4.z;
            a[3] += bf2f((unsigned short)hv[3]) + bf2f((unsigned short)lv[3]) + b4.w;
            store_row4(pEhi, pElo, a, e, f0);   // own cells, same thread
        }
    }
    __syncthreads();

    // fused aggregation: agg[dst] += e2
    segsum_atomicE(pEhi, pElo, sDst, t, agg);
}

// ---------------- K1: node encoder + layer-0 projections (256 thr, R8) --------

__global__ __launch_bounds__(256, 4) void k_encode_nodes(
    const float* __restrict__ x, const unsigned short* __restrict__ wt,
    const float* __restrict__ bn1, const float* __restrict__ bn2,
    float* __restrict__ x_h, float* __restrict__ Ps, float* __restrict__ Pd)
{
    __shared__ unsigned short pXhi[EPB * LDK], pXlo[EPB * LDK];
    __shared__ unsigned short pHhi[EPB * LDK], pHlo[EPB * LDK];

    const int t = threadIdx.x;
    const int lane = t & 63, ft = t >> 6;
    const int quad = lane >> 4, l15 = lane & 15;
    const int f0 = ft * 16 + quad * 4;
    const int nodeBase = blockIdx.x * 64;
    const int nValid = min(64, NN - nodeBase);

    // stage x (8 cols) padded to 32
    {
        const int row = t >> 2, q = t & 3;
        if (q == 0) {
            float4 a0 = make_float4(0.f, 0.f, 0.f, 0.f), a1 = a0;
            if (row < nValid) {
                a0 = *(const float4*)(x + (size_t)(nodeBase + row) * 8);
                a1 = *(const float4*)(x + (size_t)(nodeBase + row) * 8 + 4);
            }
            unsigned hw0, lw0, hw1, lw1, hw2, lw2, hw3, lw3;
            split_pair(a0.x, a0.y, hw0, lw0);
            split_pair(a0.z, a0.w, hw1, lw1);
            split_pair(a1.x, a1.y, hw2, lw2);
            split_pair(a1.z, a1.w, hw3, lw3);
            uint4 H; H.x = hw0; H.y = hw1; H.z = hw2; H.w = hw3;
            uint4 L; L.x = lw0; L.y = lw1; L.z = lw2; L.w = lw3;
            *(uint4*)(pXhi + row * LDK) = H;
            *(uint4*)(pXlo + row * LDK) = L;
        } else {
            const uint4 z = {0u, 0u, 0u, 0u};
            *(uint4*)(pXhi + row * LDK + q * 8) = z;
            *(uint4*)(pXlo + row * LDK + q * 8) = z;
        }
    }
    __syncthreads();

    f32x4 acc[4];

    // phase1: h1 = relu(x @ wn1 + bn1) -> pH
    {
        short8 wa[2];
        const int el = (ft * 16 + l15) * 32 + quad * 8;
        wa[0] = *(const short8*)(wt + OFF_WN1 + el);
        wa[1] = *(const short8*)(wt + OFF_WN1 + 2048 + el);
        set_bias(acc, bn1, f0);
#pragma unroll
        for (int et = 0; et < 4; ++et) {
            const int e = et * 16 + l15;
            const short8 bh0 = *(const short8*)(pXhi + e * LDK + quad * 8);
            const short8 bl0 = *(const short8*)(pXlo + e * LDK + quad * 8);
            f32x4 a = acc[et];
            a = MFMA(wa[0], bh0, a, 0, 0, 0);
            a = MFMA(wa[1], bh0, a, 0, 0, 0);
            a = MFMA(wa[0], bl0, a, 0, 0, 0);
            acc[et] = a;
        }
        relu4(acc);
        store_split_planes(pHhi, pHlo, acc, l15, f0);
    }
    __syncthreads();

    // phase2: x_h = h1 @ wn2 + bn2 -> global + pX
    {
        short8 w[2][2];
        load_wf(wt + S_WN2 * 8192, ft, l15, quad, w);
        set_bias(acc, bn2, f0);
        gemm_planes(pHhi, pHlo, w, l15, quad, acc);
#pragma unroll
        for (int et = 0; et < 4; ++et) {
            const int r = et * 16 + l15;
            if (r < nValid) {
                float4 v = make_float4(acc[et][0], acc[et][1], acc[et][2], acc[et][3]);
                *(float4*)(x_h + (size_t)(nodeBase + r) * HH + f0) = v;
            }
        }
        store_split_planes(pXhi, pXlo, acc, l15, f0);
    }
    __syncthreads();

    // phase3: Ps = x_h @ W1s(l0)
    {
        short8 w[2][2];
        load_wf(wt + S_W1S0 * 8192, ft, l15, quad, w);
        set_zero(acc);
        gemm_planes(pXhi, pXlo, w, l15, quad, acc);
#pragma unroll
        for (int et = 0; et < 4; ++et) {
            const int r = et * 16 + l15;
            if (r < nValid) {
                float4 v = make_float4(acc[et][0], acc[et][1], acc[et][2], acc[et][3]);
                *(float4*)(Ps + (size_t)(nodeBase + r) * HH + f0) = v;
            }
        }
    }
    // phase4: Pd = x_h @ W1d(l0)  (read-only on planes, no barrier needed)
    {
        short8 w[2][2];
        load_wf(wt + S_W1D0 * 8192, ft, l15, quad, w);
        set_zero(acc);
        gemm_planes(pXhi, pXlo, w, l15, quad, acc);
#pragma unroll
        for (int et = 0; et < 4; ++et) {
            const int r = et * 16 + l15;
            if (r < nValid) {
                float4 v = make_float4(acc[et][0], acc[et][1], acc[et][2], acc[et][3]);
                *(float4*)(Pd + (size_t)(nodeBase + r) * HH + f0) = v;
            }
        }
    }
}

// ---------------- K3: node update l0 + layer-1 projections (256 thr, R8) --------

__global__ __launch_bounds__(256, 4) void k_node_l0(
    float* x_h, const float* agg, const unsigned short* __restrict__ wt,
    const float* __restrict__ nb1, const float* __restrict__ nb2,
    float* Ps, float* __restrict__ Pd)
{
    __shared__ unsigned short pXhi[EPB * LDK], pXlo[EPB * LDK];
    __shared__ unsigned short pAhi[EPB * LDK], pAlo[EPB * LDK];

    const int t = threadIdx.x;
    const int lane = t & 63, ft = t >> 6;
    const int quad = lane >> 4, l15 = lane & 15;
    const int f0 = ft * 16 + quad * 4;
    const int nodeBase = blockIdx.x * 64;
    const int nValid = min(64, NN - nodeBase);

    stage_split64(pXhi, pXlo, x_h, nodeBase, t, nValid);
    stage_split64(pAhi, pAlo, agg, nodeBase, t, nValid);
    __syncthreads();

    f32x4 acc[4];

    // t1 = relu(x_h @ W1x + agg @ W1a + nb1)
    {
        short8 w[2][2];
        load_wf(wt + S_W1NX0 * 8192, ft, l15, quad, w);
        set_bias(acc, nb1, f0);
        gemm_planes(pXhi, pXlo, w, l15, quad, acc);
        load_wf(wt + S_W1NA0 * 8192, ft, l15, quad, w);
        gemm_planes(pAhi, pAlo, w, l15, quad, acc);
        relu4(acc);
    }
    __syncthreads();                       // pA reads complete
    store_split_planes(pAhi, pAlo, acc, l15, f0);   // t1 -> pA
    __syncthreads();

    // x_h1 = x_h + t1 @ W2n + nb2 -> global + pX
    {
        short8 w[2][2];
        load_wf(wt + S_W2N0 * 8192, ft, l15, quad, w);
        set_bias(acc, nb2, f0);
        gemm_planes(pAhi, pAlo, w, l15, quad, acc);
#pragma unroll
        for (int et = 0; et < 4; ++et) {
            const int r = et * 16 + l15;
            if (r < nValid) {
                const size_t gi = (size_t)(nodeBase + r) * HH + f0;
                const float4 xr = *(const float4*)(x_h + gi);
                acc[et][0] += xr.x; acc[et][1] += xr.y;
                acc[et][2] += xr.z; acc[et][3] += xr.w;
                float4 v = make_float4(acc[et][0], acc[et][1], acc[et][2], acc[et][3]);
                *(float4*)(x_h + gi) = v;
            }
        }
        store_split_planes(pXhi, pXlo, acc, l15, f0);
    }
    __syncthreads();

    // Ps1 = x_h1 @ W1s(l1)
    {
        short8 w[2][2];
        load_wf(wt + S_W1S1 * 8192, ft, l15, quad, w);
        set_zero(acc);
        gemm_planes(pXhi, pXlo, w, l15, quad, acc);
#pragma unroll
        for (int et = 0; et < 4; ++et) {
            const int r = et * 16 + l15;
            if (r < nValid) {
                float4 v = make_float4(acc[et][0], acc[et][1], acc[et][2], acc[et][3]);
                *(float4*)(Ps + (size_t)(nodeBase + r) * HH + f0) = v;
            }
        }
    }
    // Pd1 = x_h1 @ W1d(l1)
    {
        short8 w[2][2];
        load_wf(wt + S_W1D1 * 8192, ft, l15, quad, w);
        set_zero(acc);
        gemm_planes(pXhi, pXlo, w, l15, quad, acc);
#pragma unroll
        for (int et = 0; et < 4; ++et) {
            const int r = et * 16 + l15;
            if (r < nValid) {
                float4 v = make_float4(acc[et][0], acc[et][1], acc[et][2], acc[et][3]);
                *(float4*)(Pd + (size_t)(nodeBase + r) * HH + f0) = v;
            }
        }
    }
}

// ---------------- K5: node update l1 + decoder (256 thr, R8) ----------------

__global__ __launch_bounds__(256, 4) void k_node_l1_dec(
    const float* x_h, const float* agg, const unsigned short* __restrict__ wt,
    const float* __restrict__ nb1, const float* __restrict__ nb2,
    const float* __restrict__ db1, const float* __restrict__ dw2,
    const float* __restrict__ db2, float* __restrict__ out)
{
    __shared__ unsigned short pXhi[EPB * LDK], pXlo[EPB * LDK];
    __shared__ unsigned short pAhi[EPB * LDK], pAlo[EPB * LDK];
    __shared__ float sW2[64 * 6];

    const int t = threadIdx.x;
    const int lane = t & 63, ft = t >> 6;
    const int quad = lane >> 4, l15 = lane & 15;
    const int f0 = ft * 16 + quad * 4;
    const int nodeBase = blockIdx.x * 64;
    const int nValid = min(64, NN - nodeBase);

    stage_split64(pXhi, pXlo, x_h, nodeBase, t, nValid);
    stage_split64(pAhi, pAlo, agg, nodeBase, t, nValid);
    if (t < 192) {
        sW2[t] = dw2[t];
        sW2[t + 192] = dw2[t + 192];
    }
    __syncthreads();

    f32x4 acc[4];

    // t1 = relu(x_h @ W1x + agg @ W1a + nb1)
    {
        short8 w[2][2];
        load_wf(wt + S_W1NX1 * 8192, ft, l15, quad, w);
        set_bias(acc, nb1, f0);
        gemm_planes(pXhi, pXlo, w, l15, quad, acc);
        load_wf(wt + S_W1NA1 * 8192, ft, l15, quad, w);
        gemm_planes(pAhi, pAlo, w, l15, quad, acc);
        relu4(acc);
    }
    __syncthreads();
    store_split_planes(pAhi, pAlo, acc, l15, f0);   // t1 -> pA
    __syncthreads();

    // x_h2 = x_h + t1 @ W2n + nb2 -> pX (no global writeback needed)
    {
        short8 w[2][2];
        load_wf(wt + S_W2N1 * 8192, ft, l15, quad, w);
        set_bias(acc, nb2, f0);
        gemm_planes(pAhi, pAlo, w, l15, quad, acc);
#pragma unroll
        for (int et = 0; et < 4; ++et) {
            const int r = et * 16 + l15;
            if (r < nValid) {
                const float4 xr = *(const float4*)(x_h + (size_t)(nodeBase + r) * HH + f0);
                acc[et][0] += xr.x; acc[et][1] += xr.y;
                acc[et][2] += xr.z; acc[et][3] += xr.w;
            }
        }
        store_split_planes(pXhi, pXlo, acc, l15, f0);
    }
    __syncthreads();

    // d1 = relu(x_h2 @ dec_w1 + db1) -> pA
    {
        short8 w[2][2];
        load_wf(wt + S_DW1 * 8192, ft, l15, quad, w);
        set_bias(acc, db1, f0);
        gemm_planes(pXhi, pXlo, w, l15, quad, acc);
        relu4(acc);
        store_split_planes(pAhi, pAlo, acc, l15, f0);
    }
    __syncthreads();

    // out = d1 @ dec_w2 + db2  (64 nodes x 6)
    if (t < 64 && t < nValid) {
        float o[6];
#pragma unroll
        for (int c = 0; c < 6; ++c) o[c] = db2[c];
#pragma unroll 8
        for (int k = 0; k < 64; ++k) {
            const float a = bf2f(pAhi[t * LDK + k]) + bf2f(pAlo[t * LDK + k]);
#pragma unroll
            for (int c = 0; c < 6; ++c) o[c] = fmaf(a, sW2[k * 6 + c], o[c]);
        }
        float* op = out + (size_t)(nodeBase + t) * 6;
#pragma unroll
        for (int c = 0; c < 6; ++c) op[c] = o[c];
    }
}

// ---------------- launcher ----------------

extern "C" void kernel_launch(void* const* d_in, const int* in_sizes, int n_in,
                              void* d_out, int out_size, void* d_ws, size_t ws_size,
                              hipStream_t stream) {
    const float* x        = (const float*)d_in[0];
    const float* eattr    = (const float*)d_in[1];
    const int*   eidx     = (const int*)d_in[2];
    const float* enc_n_w1 = (const float*)d_in[3];
    const float* enc_n_b1 = (const float*)d_in[4];
    const float* enc_n_w2 = (const float*)d_in[5];
    const float* enc_n_b2 = (const float*)d_in[6];
    const float* enc_e_w1 = (const float*)d_in[7];
    const float* enc_e_b1 = (const float*)d_in[8];
    const float* enc_e_w2 = (const float*)d_in[9];
    const float* enc_e_b2 = (const float*)d_in[10];
    const float* pe_w1    = (const float*)d_in[11];  // [2,192,64]
    const float* pe_b1    = (const float*)d_in[12];  // [2,64]
    const float* pe_w2    = (const float*)d_in[13];  // [2,64,64]
    const float* pe_b2    = (const float*)d_in[14];  // [2,64]
    const float* pn_w1    = (const float*)d_in[15];  // [2,128,64]
    const float* pn_b1    = (const float*)d_in[16];
    const float* pn_w2    = (const float*)d_in[17];  // [2,64,64]
    const float* pn_b2    = (const float*)d_in[18];
    const float* dw1      = (const float*)d_in[19];
    const float* db1      = (const float*)d_in[20];
    const float* dw2      = (const float*)d_in[21];
    const float* db2      = (const float*)d_in[22];
    float* out = (float*)d_out;

    // ws: x_h | Ps | Pd | agg | epk | off | deg | csr | srcs_s | dsts_s | wt
    const size_t NNHH = (size_t)NN * HH;
    float* ws  = (float*)d_ws;
    float* x_h = ws;
    float* Ps  = ws + NNHH;
    float* Pd  = ws + 2 * NNHH;
    float* agg = ws + 3 * NNHH;
    unsigned* epk = (unsigned*)(ws + 4 * NNHH);           // EE*HH uints
    unsigned* off = epk + (size_t)EE * HH;                // NN+1
    unsigned* deg = off + (NN + 1);                       // NN, reused as cursor
    int* csr    = (int*)(deg + NN);                       // EE
    int* srcs_s = csr + EE;                               // EE
    int* dsts_s = srcs_s + EE;                            // EE
    unsigned short* wt = (unsigned short*)(dsts_s + EE);  // WT_USHORTS

    const int nodeBlocks = (NN + 63) / 64;   // 782
    const int edgeBlocks = EE / EPE;         // 6250
    const int eScal      = (EE + 255) / 256; // 3125

    hipMemsetAsync(deg, 0, (size_t)NN * sizeof(unsigned), stream);
    hipMemsetAsync(agg, 0, NNHH * sizeof(float), stream);

    k_conv_w<<<288, 256, 0, stream>>>(
        enc_n_w1, enc_n_w2, enc_e_w1, enc_e_w2,
        pe_w1, pe_w2, pn_w1, pn_w2, dw1, wt);

    k_deg<<<eScal, 256, 0, stream>>>(eidx, deg);
    k_scan<<<1, 1024, 0, stream>>>(deg, off);
    k_fill<<<eScal, 256, 0, stream>>>(eidx, deg, csr, srcs_s, dsts_s);

    k_encode_nodes<<<nodeBlocks, 256, 0, stream>>>(
        x, wt, enc_n_b1, enc_n_b2, x_h, Ps, Pd);

    k_edge_l0<<<edgeBlocks, 256, 0, stream>>>(
        eattr, csr, srcs_s, dsts_s, Ps, Pd,
        enc_e_b1, enc_e_b2, wt, pe_b1, pe_b2, epk, agg);

    k_node_l0<<<nodeBlocks, 256, 0, stream>>>(
        x_h, agg, wt, pn_b1, pn_b2, Ps, Pd);

    hipMemsetAsync(agg, 0, NNHH * sizeof(float), stream);

    k_edge_l1<<<edgeBlocks, 256, 0, stream>>>(
        srcs_s, dsts_s, Ps, Pd, wt, pe_b1 + 64, pe_b2 + 64, epk, agg);

    k_node_l1_dec<<<nodeBlocks, 256, 0, stream>>>(
        x_h, agg, wt, pn_b1 + 64, pn_b2 + 64,
        db1, dw2, db2, out);
}

// Round 7
// 668.987 us; speedup vs baseline: 1.5901x; 1.0806x over previous
//
#include <hip/hip_runtime.h>

// GNN: N=50000 nodes, E=800000 edges, H=64, L=2.
// R13: R8 geometry (best measured: EPB=64, 256thr/4 waves, 4 tiles/wave) +
// algebraic phase fusion:
//  - edge_l0: e0 is LINEAR in h0 -> t1 = relu(h0@(We2*W1e) + be2*W1e + pb1 +
//    Ps+Pd). Phase2' computes e0 (regs-only residual) and t1 from the same
//    h0 B-frags: one barrier + one LDS round-trip removed, same MFMA count.
//  - encode: x_h LINEAR in h1 -> Ps = h1@(wn2*W1s0)+bn2*W1s0 (same for Pd).
//    All three output GEMMs read h1 planes read-only: 4 barriers -> 2.
//  - fused products (WE21/WNS0/WND0 + biases) computed fp32 in k_fuse_w.
//  - cvt_pk splits everywhere (absmax-identical, validated R11/R12).
// Node l0/l1 kernels: R8 structure + cvt_pk (R12 versions).
// Pipeline: conv_w|fuse_w | CSR | encode | edge_l0(+agg) | node_l0 | memset |
//           edge_l1(+agg) | node_l1+dec.

#define NN 50000
#define EE 800000
#define HH 64
#define LDK 72   // bf16 plane leading dim (144 B row)
#define EPB 64   // rows per block

typedef short short8 __attribute__((ext_vector_type(8)));
typedef short short4v __attribute__((ext_vector_type(4)));
typedef float f32x4 __attribute__((ext_vector_type(4)));

#define MFMA __builtin_amdgcn_mfma_f32_16x16x32_bf16

// wt slots (each 8192 ushorts: 4096 hi + 4096 lo, layout [f][k])
#define S_WE2   0
#define S_W1E0  1   // (unused after fusion, kept for layout stability)
#define S_W2E0  2
#define S_W1E1  3
#define S_W2E1  4
#define S_WN2   5
#define S_W1S0  6   // (unused after fusion)
#define S_W1D0  7   // (unused after fusion)
#define S_W1S1  8
#define S_W1D1  9
#define S_W1NX0 10
#define S_W1NA0 11
#define S_W2N0  12
#define S_W1NX1 13
#define S_W1NA1 14
#define S_W2N1  15
#define S_DW1   16
#define S_WE21  17  // We2(l0e) @ W1e(l0)
#define S_WNS0  18  // wn2 @ W1s(l0)
#define S_WND0  19  // wn2 @ W1d(l0)
#define OFF_WE1 (20*8192)          // [f][32], K=4 padded
#define OFF_WN1 (20*8192+4096)     // [f][32], K=8 padded
#define FB_OFF  (20*8192+8192)     // ushort offset of float fused biases
// fb floats: [0..63]=be2@W1e, [64..127]=bn2@W1s0, [128..191]=bn2@W1d0
#define WT_USHORTS (20*8192+8192+384)

// ---------------- bf16 helpers ----------------

__device__ __forceinline__ void split2(float x, unsigned short& h, unsigned short& l) {
    union { float f; unsigned u; } a, hf, b;
    a.f = x;
    const unsigned hb = (a.u + 0x7FFFu + ((a.u >> 16) & 1u)) >> 16;  // RNE hi
    hf.u = hb << 16;
    b.f = x - hf.f;                  // exact
    h = (unsigned short)hb;
    l = (unsigned short)(b.u >> 16); // truncated lo: err <= 2^-16 |x|
}

__device__ __forceinline__ float bf2f(unsigned short s) {
    union { unsigned u; float f; } a; a.u = ((unsigned)s) << 16; return a.f;
}

__device__ __forceinline__ float uph(unsigned u) {
    union { unsigned x; float f; } a; a.x = u & 0xFFFF0000u; return a.f;
}
__device__ __forceinline__ float upl(unsigned u) {
    union { unsigned x; float f; } a; a.x = u << 16; return a.f;
}

// packed split (numerics == split2, verified R11/R12 absmax-identical)
__device__ __forceinline__ unsigned cvtpk_bf16(float a, float b) {
    unsigned r;
    asm("v_cvt_pk_bf16_f32 %0, %1, %2" : "=v"(r) : "v"(a), "v"(b));
    return r;
}
__device__ __forceinline__ void split_pair(float x0, float x1, unsigned& hw, unsigned& lw) {
    hw = cvtpk_bf16(x0, x1);
    union { unsigned u; float f; } h0, h1, r0, r1;
    h0.u = hw << 16;
    h1.u = hw & 0xFFFF0000u;
    r0.f = x0 - h0.f;
    r1.f = x1 - h1.f;
    lw = (r0.u >> 16) | (r1.u & 0xFFFF0000u);
}

// A-frags for one 16-feature slice of a 64x64 weight: [chunk][plane]
__device__ __forceinline__ void load_wf(const unsigned short* __restrict__ wm,
                                        int ft, int l15, int quad, short8 (&w)[2][2]) {
#pragma unroll
    for (int c = 0; c < 2; ++c) {
        const int el = (ft * 16 + l15) * 64 + c * 32 + quad * 8;
        w[c][0] = *(const short8*)(wm + el);
        w[c][1] = *(const short8*)(wm + 4096 + el);
    }
}

// D += Ah*Bh + Al*Bh + Ah*Bl over K=64 (2 chunks)
__device__ __forceinline__ f32x4 chain6(const short8 (&w)[2][2],
                                        short8 bh0, short8 bh1,
                                        short8 bl0, short8 bl1, f32x4 a) {
    a = MFMA(w[0][0], bh0, a, 0, 0, 0);
    a = MFMA(w[1][0], bh1, a, 0, 0, 0);
    a = MFMA(w[0][1], bh0, a, 0, 0, 0);
    a = MFMA(w[1][1], bh1, a, 0, 0, 0);
    a = MFMA(w[0][0], bl0, a, 0, 0, 0);
    a = MFMA(w[1][0], bl1, a, 0, 0, 0);
    return a;
}

// one row-tile GEMM step: acc += W @ B(row e)
__device__ __forceinline__ void gemm_tile(const unsigned short* pHi, const unsigned short* pLo,
                                          const short8 (&w)[2][2], int e, int quad, f32x4& a) {
    const short8 bh0 = *(const short8*)(pHi + e * LDK + quad * 8);
    const short8 bh1 = *(const short8*)(pHi + e * LDK + 32 + quad * 8);
    const short8 bl0 = *(const short8*)(pLo + e * LDK + quad * 8);
    const short8 bl1 = *(const short8*)(pLo + e * LDK + 32 + quad * 8);
    a = chain6(w, bh0, bh1, bl0, bl1, a);
}

// store 4 feats of row e via packed cvt split
__device__ __forceinline__ void store_row4(unsigned short* pHi, unsigned short* pLo,
                                           const f32x4& a, int e, int f0) {
    unsigned hw0, lw0, hw1, lw1;
    split_pair(a[0], a[1], hw0, lw0);
    split_pair(a[2], a[3], hw1, lw1);
    uint2 hv; hv.x = hw0; hv.y = hw1;
    uint2 lv; lv.x = lw0; lv.y = lw1;
    *(uint2*)(pHi + e * LDK + f0) = hv;
    *(uint2*)(pLo + e * LDK + f0) = lv;
}

// ======== 4-tile helpers (256 thr) ========

__device__ __forceinline__ void gemm_planes(const unsigned short* pHi, const unsigned short* pLo,
                                            const short8 (&w)[2][2], int l15, int quad,
                                            f32x4 (&acc)[4]) {
#pragma unroll
    for (int et = 0; et < 4; ++et) {
        const int e = et * 16 + l15;
        gemm_tile(pHi, pLo, w, e, quad, acc[et]);
    }
}

__device__ __forceinline__ void set_bias(f32x4 (&acc)[4], const float* __restrict__ b, int f0) {
    const float4 b4 = *(const float4*)(b + f0);
#pragma unroll
    for (int et = 0; et < 4; ++et) {
        acc[et][0] = b4.x; acc[et][1] = b4.y; acc[et][2] = b4.z; acc[et][3] = b4.w;
    }
}

__device__ __forceinline__ void set_zero(f32x4 (&acc)[4]) {
#pragma unroll
    for (int et = 0; et < 4; ++et)
#pragma unroll
        for (int r = 0; r < 4; ++r) acc[et][r] = 0.f;
}

__device__ __forceinline__ void relu4(f32x4 (&acc)[4]) {
#pragma unroll
    for (int et = 0; et < 4; ++et)
#pragma unroll
        for (int r = 0; r < 4; ++r) acc[et][r] = fmaxf(acc[et][r], 0.f);
}

__device__ __forceinline__ void store_split_planes(unsigned short* pHi, unsigned short* pLo,
                                                   const f32x4 (&acc)[4], int l15, int f0) {
#pragma unroll
    for (int et = 0; et < 4; ++et) store_row4(pHi, pLo, acc[et], et * 16 + l15, f0);
}

// stage fp32 [64][64] tile -> split hi/lo planes; invalid rows zero
__device__ __forceinline__ void stage_split64(unsigned short* pHi, unsigned short* pLo,
                                              const float* g, long rowBase, int t, int nValid) {
    const int row = t >> 2, q = t & 3;
    const bool valid = row < nValid;
#pragma unroll
    for (int i = 0; i < 4; ++i) {
        const int col = q * 16 + i * 4;
        float4 v = make_float4(0.f, 0.f, 0.f, 0.f);
        if (valid) v = *(const float4*)(g + (size_t)(rowBase + row) * HH + col);
        unsigned hw0, lw0, hw1, lw1;
        split_pair(v.x, v.y, hw0, lw0);
        split_pair(v.z, v.w, hw1, lw1);
        uint2 hv; hv.x = hw0; hv.y = hw1;
        uint2 lv; lv.x = lw0; lv.y = lw1;
        *(uint2*)(pHi + row * LDK + col) = hv;
        *(uint2*)(pLo + row * LDK + col) = lv;
    }
}

// in-LDS segment sum over dst-sorted rows + atomic scatter (64 rows, 4 waves)
__device__ __forceinline__ void segsum_atomic(const unsigned short* pHi, const unsigned short* pLo,
                                              const int* sDst, int t,
                                              float* __restrict__ agg) {
    const int f = t & 63, c0 = (t >> 6) * 16;
    float s = 0.f;
    int d = sDst[c0];
#pragma unroll
    for (int i = 0; i < 16; ++i) {
        const int r = c0 + i;
        s += bf2f(pHi[r * LDK + f]) + bf2f(pLo[r * LDK + f]);
        const int dn = (i == 15) ? -1 : sDst[r + 1];
        if (dn != d) {
            atomicAdd(&agg[(size_t)d * HH + f], s);
            s = 0.f; d = dn;
        }
    }
}

// ---------------- setup: split all weights, transposed [f][k] ----------------

__global__ void k_conv_w(const float* __restrict__ enc_n_w1, const float* __restrict__ enc_n_w2,
                         const float* __restrict__ enc_e_w1, const float* __restrict__ enc_e_w2,
                         const float* __restrict__ pe_w1, const float* __restrict__ pe_w2,
                         const float* __restrict__ pn_w1, const float* __restrict__ pn_w2,
                         const float* __restrict__ dw1, unsigned short* __restrict__ wt)
{
    const int i = blockIdx.x * 256 + threadIdx.x;
    if (i < 17 * 4096) {
        const int m = i >> 12, r = i & 4095;
        const int f = r & 63, k = r >> 6;
        const float* W;
        switch (m) {
            case S_WE2:   W = enc_e_w2; break;
            case S_W1E0:  W = pe_w1; break;
            case S_W2E0:  W = pe_w2; break;
            case S_W1E1:  W = pe_w1 + 192 * 64; break;
            case S_W2E1:  W = pe_w2 + 64 * 64; break;
            case S_WN2:   W = enc_n_w2; break;
            case S_W1S0:  W = pe_w1 + 64 * 64; break;
            case S_W1D0:  W = pe_w1 + 128 * 64; break;
            case S_W1S1:  W = pe_w1 + 192 * 64 + 64 * 64; break;
            case S_W1D1:  W = pe_w1 + 192 * 64 + 128 * 64; break;
            case S_W1NX0: W = pn_w1; break;
            case S_W1NA0: W = pn_w1 + 64 * 64; break;
            case S_W2N0:  W = pn_w2; break;
            case S_W1NX1: W = pn_w1 + 128 * 64; break;
            case S_W1NA1: W = pn_w1 + 128 * 64 + 64 * 64; break;
            case S_W2N1:  W = pn_w2 + 64 * 64; break;
            default:      W = dw1; break;
        }
        unsigned short h, l; split2(W[r], h, l);    // W[k*64+f]
        wt[m * 8192 + f * 64 + k] = h;
        wt[m * 8192 + 4096 + f * 64 + k] = l;
    } else if (i < 17 * 4096 + 2048) {
        const int r = i - 17 * 4096, f = r >> 5, k = r & 31;
        const float v = (k < 4) ? enc_e_w1[k * 64 + f] : 0.f;
        unsigned short h, l; split2(v, h, l);
        wt[OFF_WE1 + f * 32 + k] = h;
        wt[OFF_WE1 + 2048 + f * 32 + k] = l;
    } else if (i < 17 * 4096 + 4096) {
        const int r = i - 17 * 4096 - 2048, f = r >> 5, k = r & 31;
        const float v = (k < 8) ? enc_n_w1[k * 64 + f] : 0.f;
        unsigned short h, l; split2(v, h, l);
        wt[OFF_WN1 + f * 32 + k] = h;
        wt[OFF_WN1 + 2048 + f * 32 + k] = l;
    }
}

// fused weight products (fp32 matmul then split) + fused biases
__global__ void k_fuse_w(const float* __restrict__ enc_n_w2, const float* __restrict__ enc_n_b2,
                         const float* __restrict__ enc_e_w2, const float* __restrict__ enc_e_b2,
                         const float* __restrict__ pe_w1, unsigned short* __restrict__ wt)
{
    const int i = blockIdx.x * 256 + threadIdx.x;
    if (i < 3 * 4096) {
        const int m = i >> 12, r = i & 4095;
        const int g = r & 63, j = r >> 6;
        const float* A = (m == 0) ? enc_e_w2 : enc_n_w2;
        const float* B = pe_w1 + m * 64 * 64;   // m0: e-slice, m1: src, m2: dst
        float s = 0.f;
#pragma unroll 8
        for (int f = 0; f < 64; ++f) s += A[j * 64 + f] * B[f * 64 + g];
        unsigned short h, l; split2(s, h, l);
        wt[(S_WE21 + m) * 8192 + g * 64 + j] = h;
        wt[(S_WE21 + m) * 8192 + 4096 + g * 64 + j] = l;
    } else if (i < 3 * 4096 + 192) {
        const int r = i - 3 * 4096;
        const int m = r >> 6, g = r & 63;
        const float* bb = (m == 0) ? enc_e_b2 : enc_n_b2;
        const float* B = pe_w1 + m * 64 * 64;
        float s = 0.f;
#pragma unroll 8
        for (int f = 0; f < 64; ++f) s += bb[f] * B[f * 64 + g];
        float* fb = (float*)(wt + FB_OFF);
        fb[m * 64 + g] = s;
    }
}

// ---------------- CSR build ----------------

__global__ void k_deg(const int* __restrict__ eidx, unsigned* __restrict__ deg) {
    const int e = blockIdx.x * 256 + threadIdx.x;
    if (e < EE) atomicAdd(&deg[eidx[EE + e]], 1u);
}

__global__ __launch_bounds__(1024) void k_scan(unsigned* deg, unsigned* __restrict__ off) {
    __shared__ unsigned part[1024];
    const int t = threadIdx.x;
    const int CH = (NN + 1023) / 1024;
    const int s = t * CH, e = s + CH < NN ? s + CH : NN;
    unsigned sum = 0;
    for (int i = s; i < e; ++i) sum += deg[i];
    part[t] = sum;
    __syncthreads();
    for (int d = 1; d < 1024; d <<= 1) {
        unsigned v = (t >= d) ? part[t - d] : 0u;
        __syncthreads();
        if (t >= d) part[t] += v;
        __syncthreads();
    }
    unsigned base = (t > 0) ? part[t - 1] : 0u;
    for (int i = s; i < e; ++i) {
        const unsigned d = deg[i];
        off[i] = base;
        deg[i] = base;          // reuse as fill cursor
        base += d;
    }
    if (t == 1023) off[NN] = part[1023];
}

__global__ void k_fill(const int* __restrict__ eidx, unsigned* __restrict__ cur,
                       int* __restrict__ csr, int* __restrict__ srcs_s,
                       int* __restrict__ dsts_s) {
    const int e = blockIdx.x * 256 + threadIdx.x;
    if (e < EE) {
        const int d = eidx[EE + e];
        const unsigned p = atomicAdd(&cur[d], 1u);
        csr[p] = e;
        srcs_s[p] = eidx[e];
        dsts_s[p] = d;
    }
}

// ---------------- K2: edge encoder + layer-0 edge MLP + fused agg ----------------
// R8 geometry, fused phase 2/3: e0 regs-only, t1 via WE21. 4 barriers (was 5).

__global__ __launch_bounds__(256, 4) void k_edge_l0(
    const float* __restrict__ eattr, const int* __restrict__ csr,
    const int* __restrict__ srcs_s, const int* __restrict__ dsts_s,
    const float* __restrict__ Ps, const float* __restrict__ Pd,
    const float* __restrict__ be1, const float* __restrict__ be2,
    const unsigned short* __restrict__ wt, const float* __restrict__ fb,
    const float* __restrict__ pb1, const float* __restrict__ pb2,
    unsigned* __restrict__ epk, float* __restrict__ agg)
{
    __shared__ unsigned short pHhi[EPB * LDK], pHlo[EPB * LDK];
    __shared__ unsigned short pEhi[EPB * LDK], pElo[EPB * LDK];
    __shared__ int sDst[EPB];

    const int t = threadIdx.x;
    const int lane = t & 63, ft = t >> 6;
    const int quad = lane >> 4, l15 = lane & 15;
    const int f0 = ft * 16 + quad * 4;
    const long eBase = (long)blockIdx.x * EPB;

    // stage eattr (gathered via csr): k 0..3 data, 4..31 zero
    {
        const int row = t >> 2, q = t & 3;
        if (q == 0) {
            const int eid = csr[eBase + row];
            const float4 ea = *(const float4*)(eattr + (size_t)eid * 4);
            unsigned hw0, lw0, hw1, lw1;
            split_pair(ea.x, ea.y, hw0, lw0);
            split_pair(ea.z, ea.w, hw1, lw1);
            uint4 H; H.x = hw0; H.y = hw1; H.z = 0u; H.w = 0u;
            uint4 L; L.x = lw0; L.y = lw1; L.z = 0u; L.w = 0u;
            *(uint4*)(pHhi + row * LDK) = H;
            *(uint4*)(pHlo + row * LDK) = L;
        } else {
            const uint4 z = {0u, 0u, 0u, 0u};
            *(uint4*)(pHhi + row * LDK + q * 8) = z;
            *(uint4*)(pHlo + row * LDK + q * 8) = z;
        }
    }
    if (t < EPB) sDst[t] = dsts_s[eBase + t];

    int srcs[4], dsts[4];
#pragma unroll
    for (int et = 0; et < 4; ++et) {
        const long p = eBase + et * 16 + l15;
        srcs[et] = srcs_s[p];
        dsts[et] = dsts_s[p];
    }
    // prefetch Ps/Pd gathers (consumed in fused phase2')
    float4 ps[4], pd[4];
#pragma unroll
    for (int et = 0; et < 4; ++et) {
        ps[et] = *(const float4*)(Ps + (size_t)srcs[et] * HH + f0);
        pd[et] = *(const float4*)(Pd + (size_t)dsts[et] * HH + f0);
    }
    __syncthreads();

    f32x4 acc[4];

    // phase1: h0 = relu(eattr @ We1 + be1) -> pE
    {
        short8 wa0, wa1;
        const int el = (ft * 16 + l15) * 32 + quad * 8;
        wa0 = *(const short8*)(wt + OFF_WE1 + el);
        wa1 = *(const short8*)(wt + OFF_WE1 + 2048 + el);
        set_bias(acc, be1, f0);
#pragma unroll
        for (int et = 0; et < 4; ++et) {
            const int e = et * 16 + l15;
            const short8 bh0 = *(const short8*)(pHhi + e * LDK + quad * 8);
            const short8 bl0 = *(const short8*)(pHlo + e * LDK + quad * 8);
            f32x4 a = acc[et];
            a = MFMA(wa0, bh0, a, 0, 0, 0);
            a = MFMA(wa1, bh0, a, 0, 0, 0);
            a = MFMA(wa0, bl0, a, 0, 0, 0);
            acc[et] = a;
        }
        relu4(acc);
        store_split_planes(pEhi, pElo, acc, l15, f0);
    }
    __syncthreads();

    // phase2' (fused): e0 = h0 @ We2 + be2 (REGS ONLY, residual for phase3');
    //                  t1 = relu(h0 @ WE21 + be2@W1e + pb1 + Ps + Pd) -> pH
    f32x4 e0s[4];
    {
        short8 w[2][2];
        load_wf(wt + S_WE2 * 8192, ft, l15, quad, w);
        set_bias(acc, be2, f0);
        gemm_planes(pEhi, pElo, w, l15, quad, acc);
#pragma unroll
        for (int et = 0; et < 4; ++et) e0s[et] = acc[et];
    }
    {
        short8 w[2][2];
        load_wf(wt + S_WE21 * 8192, ft, l15, quad, w);
        const float4 fa = *(const float4*)(fb + f0);       // be2@W1e
        const float4 fbv = *(const float4*)(pb1 + f0);
        const float4 tb = make_float4(fa.x + fbv.x, fa.y + fbv.y,
                                      fa.z + fbv.z, fa.w + fbv.w);
        set_zero(acc);
        gemm_planes(pEhi, pElo, w, l15, quad, acc);
#pragma unroll
        for (int et = 0; et < 4; ++et) {
            acc[et][0] = fmaxf(acc[et][0] + ps[et].x + pd[et].x + tb.x, 0.f);
            acc[et][1] = fmaxf(acc[et][1] + ps[et].y + pd[et].y + tb.y, 0.f);
            acc[et][2] = fmaxf(acc[et][2] + ps[et].z + pd[et].z + tb.z, 0.f);
            acc[et][3] = fmaxf(acc[et][3] + ps[et].w + pd[et].w + tb.w, 0.f);
        }
        store_split_planes(pHhi, pHlo, acc, l15, f0);
    }
    __syncthreads();

    // phase3': e1 = e0(regs) + t1 @ W2e + pb2 -> pE
    {
        short8 w[2][2];
        load_wf(wt + S_W2E0 * 8192, ft, l15, quad, w);
        set_zero(acc);
        gemm_planes(pHhi, pHlo, w, l15, quad, acc);
        const float4 b4 = *(const float4*)(pb2 + f0);
#pragma unroll
        for (int et = 0; et < 4; ++et) {
            acc[et][0] += e0s[et][0] + b4.x;
            acc[et][1] += e0s[et][1] + b4.y;
            acc[et][2] += e0s[et][2] + b4.z;
            acc[et][3] += e0s[et][3] + b4.w;
        }
        store_split_planes(pEhi, pElo, acc, l15, f0);
    }
    __syncthreads();

    // pack pE -> epk (sorted positions)
    {
        const int row = t >> 2, q = t & 3;
#pragma unroll
        for (int half = 0; half < 2; ++half) {
            const int lo = row * LDK + q * 8 + half * 32;
            const long go = (eBase + row) * HH + q * 8 + half * 32;
            union { unsigned short u[8]; uint4 v; } H, L;
            H.v = *(const uint4*)(pEhi + lo);
            L.v = *(const uint4*)(pElo + lo);
            union { unsigned u[8]; uint4 v[2]; } o;
#pragma unroll
            for (int i = 0; i < 8; ++i) o.u[i] = ((unsigned)H.u[i] << 16) | L.u[i];
            *(uint4*)(epk + go) = o.v[0];
            *(uint4*)(epk + go + 4) = o.v[1];
        }
    }
    // fused aggregation: agg[dst] += e1
    segsum_atomic(pEhi, pElo, sDst, t, agg);
}

// ---------------- K4: layer-1 edge MLP + fused agg (R8 structure) ----------------

__global__ __launch_bounds__(256, 4) void k_edge_l1(
    const int* __restrict__ srcs_s, const int* __restrict__ dsts_s,
    const float* __restrict__ Ps, const float* __restrict__ Pd,
    const unsigned short* __restrict__ wt,
    const float* __restrict__ pb1, const float* __restrict__ pb2,
    const unsigned* __restrict__ epk, float* __restrict__ agg)
{
    __shared__ unsigned short pEhi[EPB * LDK], pElo[EPB * LDK];
    __shared__ unsigned short pHhi[EPB * LDK], pHlo[EPB * LDK];
    __shared__ int sDst[EPB];

    const int t = threadIdx.x;
    const int lane = t & 63, ft = t >> 6;
    const int quad = lane >> 4, l15 = lane & 15;
    const int f0 = ft * 16 + quad * 4;
    const long eBase = (long)blockIdx.x * EPB;

    // load epk -> deinterleave -> pE
    {
        const int row = t >> 2, q = t & 3;
#pragma unroll
        for (int half = 0; half < 2; ++half) {
            const int lo = row * LDK + q * 8 + half * 32;
            const long go = (eBase + row) * HH + q * 8 + half * 32;
            union { unsigned u[8]; uint4 v[2]; } in;
            in.v[0] = *(const uint4*)(epk + go);
            in.v[1] = *(const uint4*)(epk + go + 4);
            union { unsigned short u[8]; uint4 v; } H, L;
#pragma unroll
            for (int i = 0; i < 8; ++i) {
                H.u[i] = (unsigned short)(in.u[i] >> 16);
                L.u[i] = (unsigned short)(in.u[i] & 0xFFFFu);
            }
            *(uint4*)(pEhi + lo) = H.v;
            *(uint4*)(pElo + lo) = L.v;
        }
    }
    if (t < EPB) sDst[t] = dsts_s[eBase + t];

    int srcs[4], dsts[4];
#pragma unroll
    for (int et = 0; et < 4; ++et) {
        const long p = eBase + et * 16 + l15;
        srcs[et] = srcs_s[p];
        dsts[et] = dsts_s[p];
    }
    // prefetch Ps/Pd gathers (consumed in t1 phase)
    float4 ps[4], pd[4];
#pragma unroll
    for (int et = 0; et < 4; ++et) {
        ps[et] = *(const float4*)(Ps + (size_t)srcs[et] * HH + f0);
        pd[et] = *(const float4*)(Pd + (size_t)dsts[et] * HH + f0);
    }
    __syncthreads();

    f32x4 acc[4];

    // t1 = relu(e1 @ W1e + Ps[src] + Pd[dst] + pb1) -> pH
    {
        short8 w[2][2];
        load_wf(wt + S_W1E1 * 8192, ft, l15, quad, w);
        set_zero(acc);
        gemm_planes(pEhi, pElo, w, l15, quad, acc);
        const float4 b4 = *(const float4*)(pb1 + f0);
#pragma unroll
        for (int et = 0; et < 4; ++et) {
            acc[et][0] = fmaxf(acc[et][0] + ps[et].x + pd[et].x + b4.x, 0.f);
            acc[et][1] = fmaxf(acc[et][1] + ps[et].y + pd[et].y + b4.y, 0.f);
            acc[et][2] = fmaxf(acc[et][2] + ps[et].z + pd[et].z + b4.z, 0.f);
            acc[et][3] = fmaxf(acc[et][3] + ps[et].w + pd[et].w + b4.w, 0.f);
        }
        store_split_planes(pHhi, pHlo, acc, l15, f0);
    }
    __syncthreads();

    // e2 = e1(pE residual, own cells) + t1 @ W2e + pb2 -> pE
    {
        short8 w[2][2];
        load_wf(wt + S_W2E1 * 8192, ft, l15, quad, w);
        set_zero(acc);
        gemm_planes(pHhi, pHlo, w, l15, quad, acc);
        const float4 b4 = *(const float4*)(pb2 + f0);
#pragma unroll
        for (int et = 0; et < 4; ++et) {
            const int e = et * 16 + l15;
            const short4v hv = *(const short4v*)(pEhi + e * LDK + f0);
            const short4v lv = *(const short4v*)(pElo + e * LDK + f0);
            acc[et][0] += bf2f((unsigned short)hv[0]) + bf2f((unsigned short)lv[0]) + b4.x;
            acc[et][1] += bf2f((unsigned short)hv[1]) + bf2f((unsigned short)lv[1]) + b4.y;
            acc[et][2] += bf2f((unsigned short)hv[2]) + bf2f((unsigned short)lv[2]) + b4.z;
            acc[et][3] += bf2f((unsigned short)hv[3]) + bf2f((unsigned short)lv[3]) + b4.w;
        }
        store_split_planes(pEhi, pElo, acc, l15, f0);   // own cells, same thread
    }
    __syncthreads();

    // fused aggregation: agg[dst] += e2
    segsum_atomic(pEhi, pElo, sDst, t, agg);
}

// ---------------- K1: node encoder + layer-0 projections (FUSED: 2 barriers) ------

__global__ __launch_bounds__(256, 4) void k_encode_nodes(
    const float* __restrict__ x, const unsigned short* __restrict__ wt,
    const float* __restrict__ fb,
    const float* __restrict__ bn1, const float* __restrict__ bn2,
    float* __restrict__ x_h, float* __restrict__ Ps, float* __restrict__ Pd)
{
    __shared__ unsigned short pXhi[EPB * LDK], pXlo[EPB * LDK];
    __shared__ unsigned short pHhi[EPB * LDK], pHlo[EPB * LDK];

    const int t = threadIdx.x;
    const int lane = t & 63, ft = t >> 6;
    const int quad = lane >> 4, l15 = lane & 15;
    const int f0 = ft * 16 + quad * 4;
    const int nodeBase = blockIdx.x * 64;
    const int nValid = min(64, NN - nodeBase);

    // stage x (8 cols) padded to 32
    {
        const int row = t >> 2, q = t & 3;
        if (q == 0) {
            float4 a0 = make_float4(0.f, 0.f, 0.f, 0.f), a1 = a0;
            if (row < nValid) {
                a0 = *(const float4*)(x + (size_t)(nodeBase + row) * 8);
                a1 = *(const float4*)(x + (size_t)(nodeBase + row) * 8 + 4);
            }
            unsigned hw0, lw0, hw1, lw1, hw2, lw2, hw3, lw3;
            split_pair(a0.x, a0.y, hw0, lw0);
            split_pair(a0.z, a0.w, hw1, lw1);
            split_pair(a1.x, a1.y, hw2, lw2);
            split_pair(a1.z, a1.w, hw3, lw3);
            uint4 H; H.x = hw0; H.y = hw1; H.z = hw2; H.w = hw3;
            uint4 L; L.x = lw0; L.y = lw1; L.z = lw2; L.w = lw3;
            *(uint4*)(pXhi + row * LDK) = H;
            *(uint4*)(pXlo + row * LDK) = L;
        } else {
            const uint4 z = {0u, 0u, 0u, 0u};
            *(uint4*)(pXhi + row * LDK + q * 8) = z;
            *(uint4*)(pXlo + row * LDK + q * 8) = z;
        }
    }
    __syncthreads();

    f32x4 acc[4];

    // phase1: h1 = relu(x @ wn1 + bn1) -> pH
    {
        short8 wa0, wa1;
        const int el = (ft * 16 + l15) * 32 + quad * 8;
        wa0 = *(const short8*)(wt + OFF_WN1 + el);
        wa1 = *(const short8*)(wt + OFF_WN1 + 2048 + el);
        set_bias(acc, bn1, f0);
#pragma unroll
        for (int et = 0; et < 4; ++et) {
            const int e = et * 16 + l15;
            const short8 bh0 = *(const short8*)(pXhi + e * LDK + quad * 8);
            const short8 bl0 = *(const short8*)(pXlo + e * LDK + quad * 8);
            f32x4 a = acc[et];
            a = MFMA(wa0, bh0, a, 0, 0, 0);
            a = MFMA(wa1, bh0, a, 0, 0, 0);
            a = MFMA(wa0, bl0, a, 0, 0, 0);
            acc[et] = a;
        }
        relu4(acc);
        store_split_planes(pHhi, pHlo, acc, l15, f0);
    }
    __syncthreads();

    // phase2' (fused, read-only on pH, no more barriers):
    // x_h = h1 @ wn2 + bn2          -> global
    {
        short8 w[2][2];
        load_wf(wt + S_WN2 * 8192, ft, l15, quad, w);
        set_bias(acc, bn2, f0);
        gemm_planes(pHhi, pHlo, w, l15, quad, acc);
#pragma unroll
        for (int et = 0; et < 4; ++et) {
            const int r = et * 16 + l15;
            if (r < nValid) {
                float4 v = make_float4(acc[et][0], acc[et][1], acc[et][2], acc[et][3]);
                *(float4*)(x_h + (size_t)(nodeBase + r) * HH + f0) = v;
            }
        }
    }
    // Ps = h1 @ (wn2*W1s0) + bn2@W1s0 -> global
    {
        short8 w[2][2];
        load_wf(wt + S_WNS0 * 8192, ft, l15, quad, w);
        set_bias(acc, fb + 64, f0);
        gemm_planes(pHhi, pHlo, w, l15, quad, acc);
#pragma unroll
        for (int et = 0; et < 4; ++et) {
            const int r = et * 16 + l15;
            if (r < nValid) {
                float4 v = make_float4(acc[et][0], acc[et][1], acc[et][2], acc[et][3]);
                *(float4*)(Ps + (size_t)(nodeBase + r) * HH + f0) = v;
            }
        }
    }
    // Pd = h1 @ (wn2*W1d0) + bn2@W1d0 -> global
    {
        short8 w[2][2];
        load_wf(wt + S_WND0 * 8192, ft, l15, quad, w);
        set_bias(acc, fb + 128, f0);
        gemm_planes(pHhi, pHlo, w, l15, quad, acc);
#pragma unroll
        for (int et = 0; et < 4; ++et) {
            const int r = et * 16 + l15;
            if (r < nValid) {
                float4 v = make_float4(acc[et][0], acc[et][1], acc[et][2], acc[et][3]);
                *(float4*)(Pd + (size_t)(nodeBase + r) * HH + f0) = v;
            }
        }
    }
}

// ---------------- K3: node update l0 + layer-1 projections (R8 + cvtpk) --------

__global__ __launch_bounds__(256, 4) void k_node_l0(
    float* x_h, const float* agg, const unsigned short* __restrict__ wt,
    const float* __restrict__ nb1, const float* __restrict__ nb2,
    float* Ps, float* __restrict__ Pd)
{
    __shared__ unsigned short pXhi[EPB * LDK], pXlo[EPB * LDK];
    __shared__ unsigned short pAhi[EPB * LDK], pAlo[EPB * LDK];

    const int t = threadIdx.x;
    const int lane = t & 63, ft = t >> 6;
    const int quad = lane >> 4, l15 = lane & 15;
    const int f0 = ft * 16 + quad * 4;
    const int nodeBase = blockIdx.x * 64;
    const int nValid = min(64, NN - nodeBase);

    stage_split64(pXhi, pXlo, x_h, nodeBase, t, nValid);
    stage_split64(pAhi, pAlo, agg, nodeBase, t, nValid);
    __syncthreads();

    f32x4 acc[4];

    // t1 = relu(x_h @ W1x + agg @ W1a + nb1)
    {
        short8 w[2][2];
        load_wf(wt + S_W1NX0 * 8192, ft, l15, quad, w);
        set_bias(acc, nb1, f0);
        gemm_planes(pXhi, pXlo, w, l15, quad, acc);
        load_wf(wt + S_W1NA0 * 8192, ft, l15, quad, w);
        gemm_planes(pAhi, pAlo, w, l15, quad, acc);
        relu4(acc);
    }
    __syncthreads();                       // pA reads complete
    store_split_planes(pAhi, pAlo, acc, l15, f0);   // t1 -> pA
    __syncthreads();

    // x_h1 = x_h + t1 @ W2n + nb2 -> global + pX
    {
        short8 w[2][2];
        load_wf(wt + S_W2N0 * 8192, ft, l15, quad, w);
        set_bias(acc, nb2, f0);
        gemm_planes(pAhi, pAlo, w, l15, quad, acc);
#pragma unroll
        for (int et = 0; et < 4; ++et) {
            const int r = et * 16 + l15;
            if (r < nValid) {
                const size_t gi = (size_t)(nodeBase + r) * HH + f0;
                const float4 xr = *(const float4*)(x_h + gi);
                acc[et][0] += xr.x; acc[et][1] += xr.y;
                acc[et][2] += xr.z; acc[et][3] += xr.w;
                float4 v = make_float4(acc[et][0], acc[et][1], acc[et][2], acc[et][3]);
                *(float4*)(x_h + gi) = v;
            }
        }
        store_split_planes(pXhi, pXlo, acc, l15, f0);
    }
    __syncthreads();

    // Ps1 = x_h1 @ W1s(l1)
    {
        short8 w[2][2];
        load_wf(wt + S_W1S1 * 8192, ft, l15, quad, w);
        set_zero(acc);
        gemm_planes(pXhi, pXlo, w, l15, quad, acc);
#pragma unroll
        for (int et = 0; et < 4; ++et) {
            const int r = et * 16 + l15;
            if (r < nValid) {
                float4 v = make_float4(acc[et][0], acc[et][1], acc[et][2], acc[et][3]);
                *(float4*)(Ps + (size_t)(nodeBase + r) * HH + f0) = v;
            }
        }
    }
    // Pd1 = x_h1 @ W1d(l1)
    {
        short8 w[2][2];
        load_wf(wt + S_W1D1 * 8192, ft, l15, quad, w);
        set_zero(acc);
        gemm_planes(pXhi, pXlo, w, l15, quad, acc);
#pragma unroll
        for (int et = 0; et < 4; ++et) {
            const int r = et * 16 + l15;
            if (r < nValid) {
                float4 v = make_float4(acc[et][0], acc[et][1], acc[et][2], acc[et][3]);
                *(float4*)(Pd + (size_t)(nodeBase + r) * HH + f0) = v;
            }
        }
    }
}

// ---------------- K5: node update l1 + decoder (R8 + cvtpk) ----------------

__global__ __launch_bounds__(256, 4) void k_node_l1_dec(
    const float* x_h, const float* agg, const unsigned short* __restrict__ wt,
    const float* __restrict__ nb1, const float* __restrict__ nb2,
    const float* __restrict__ db1, const float* __restrict__ dw2,
    const float* __restrict__ db2, float* __restrict__ out)
{
    __shared__ unsigned short pXhi[EPB * LDK], pXlo[EPB * LDK];
    __shared__ unsigned short pAhi[EPB * LDK], pAlo[EPB * LDK];
    __shared__ float sW2[64 * 6];

    const int t = threadIdx.x;
    const int lane = t & 63, ft = t >> 6;
    const int quad = lane >> 4, l15 = lane & 15;
    const int f0 = ft * 16 + quad * 4;
    const int nodeBase = blockIdx.x * 64;
    const int nValid = min(64, NN - nodeBase);

    stage_split64(pXhi, pXlo, x_h, nodeBase, t, nValid);
    stage_split64(pAhi, pAlo, agg, nodeBase, t, nValid);
    if (t < 192) {
        sW2[t] = dw2[t];
        sW2[t + 192] = dw2[t + 192];
    }
    __syncthreads();

    f32x4 acc[4];

    // t1 = relu(x_h @ W1x + agg @ W1a + nb1)
    {
        short8 w[2][2];
        load_wf(wt + S_W1NX1 * 8192, ft, l15, quad, w);
        set_bias(acc, nb1, f0);
        gemm_planes(pXhi, pXlo, w, l15, quad, acc);
        load_wf(wt + S_W1NA1 * 8192, ft, l15, quad, w);
        gemm_planes(pAhi, pAlo, w, l15, quad, acc);
        relu4(acc);
    }
    __syncthreads();
    store_split_planes(pAhi, pAlo, acc, l15, f0);   // t1 -> pA
    __syncthreads();

    // x_h2 = x_h + t1 @ W2n + nb2 -> pX (no global writeback needed)
    {
        short8 w[2][2];
        load_wf(wt + S_W2N1 * 8192, ft, l15, quad, w);
        set_bias(acc, nb2, f0);
        gemm_planes(pAhi, pAlo, w, l15, quad, acc);
#pragma unroll
        for (int et = 0; et < 4; ++et) {
            const int r = et * 16 + l15;
            if (r < nValid) {
                const float4 xr = *(const float4*)(x_h + (size_t)(nodeBase + r) * HH + f0);
                acc[et][0] += xr.x; acc[et][1] += xr.y;
                acc[et][2] += xr.z; acc[et][3] += xr.w;
            }
        }
        store_split_planes(pXhi, pXlo, acc, l15, f0);
    }
    __syncthreads();

    // d1 = relu(x_h2 @ dec_w1 + db1) -> pA
    {
        short8 w[2][2];
        load_wf(wt + S_DW1 * 8192, ft, l15, quad, w);
        set_bias(acc, db1, f0);
        gemm_planes(pXhi, pXlo, w, l15, quad, acc);
        relu4(acc);
        store_split_planes(pAhi, pAlo, acc, l15, f0);
    }
    __syncthreads();

    // out = d1 @ dec_w2 + db2  (64 nodes x 6)
    if (t < 64 && t < nValid) {
        float o[6];
#pragma unroll
        for (int c = 0; c < 6; ++c) o[c] = db2[c];
#pragma unroll 8
        for (int k = 0; k < 64; ++k) {
            const float a = bf2f(pAhi[t * LDK + k]) + bf2f(pAlo[t * LDK + k]);
#pragma unroll
            for (int c = 0; c < 6; ++c) o[c] = fmaf(a, sW2[k * 6 + c], o[c]);
        }
        float* op = out + (size_t)(nodeBase + t) * 6;
#pragma unroll
        for (int c = 0; c < 6; ++c) op[c] = o[c];
    }
}

// ---------------- launcher ----------------

extern "C" void kernel_launch(void* const* d_in, const int* in_sizes, int n_in,
                              void* d_out, int out_size, void* d_ws, size_t ws_size,
                              hipStream_t stream) {
    const float* x        = (const float*)d_in[0];
    const float* eattr    = (const float*)d_in[1];
    const int*   eidx     = (const int*)d_in[2];
    const float* enc_n_w1 = (const float*)d_in[3];
    const float* enc_n_b1 = (const float*)d_in[4];
    const float* enc_n_w2 = (const float*)d_in[5];
    const float* enc_n_b2 = (const float*)d_in[6];
    const float* enc_e_w1 = (const float*)d_in[7];
    const float* enc_e_b1 = (const float*)d_in[8];
    const float* enc_e_w2 = (const float*)d_in[9];
    const float* enc_e_b2 = (const float*)d_in[10];
    const float* pe_w1    = (const float*)d_in[11];  // [2,192,64]
    const float* pe_b1    = (const float*)d_in[12];  // [2,64]
    const float* pe_w2    = (const float*)d_in[13];  // [2,64,64]
    const float* pe_b2    = (const float*)d_in[14];  // [2,64]
    const float* pn_w1    = (const float*)d_in[15];  // [2,128,64]
    const float* pn_b1    = (const float*)d_in[16];
    const float* pn_w2    = (const float*)d_in[17];  // [2,64,64]
    const float* pn_b2    = (const float*)d_in[18];
    const float* dw1      = (const float*)d_in[19];
    const float* db1      = (const float*)d_in[20];
    const float* dw2      = (const float*)d_in[21];
    const float* db2      = (const float*)d_in[22];
    float* out = (float*)d_out;

    // ws: x_h | Ps | Pd | agg | epk | off | deg | csr | srcs_s | dsts_s | wt
    const size_t NNHH = (size_t)NN * HH;
    float* ws  = (float*)d_ws;
    float* x_h = ws;
    float* Ps  = ws + NNHH;
    float* Pd  = ws + 2 * NNHH;
    float* agg = ws + 3 * NNHH;
    unsigned* epk = (unsigned*)(ws + 4 * NNHH);           // EE*HH uints
    unsigned* off = epk + (size_t)EE * HH;                // NN+1
    unsigned* deg = off + (NN + 1);                       // NN, reused as cursor
    int* csr    = (int*)(deg + NN);                       // EE
    int* srcs_s = csr + EE;                               // EE
    int* dsts_s = srcs_s + EE;                            // EE
    unsigned short* wt = (unsigned short*)(dsts_s + EE);  // WT_USHORTS
    const float* fb = (const float*)(wt + FB_OFF);        // fused biases

    const int nodeBlocks = (NN + 63) / 64;   // 782
    const int edgeBlocks = EE / EPB;         // 12500
    const int eScal      = (EE + 255) / 256; // 3125

    hipMemsetAsync(deg, 0, (size_t)NN * sizeof(unsigned), stream);
    hipMemsetAsync(agg, 0, NNHH * sizeof(float), stream);

    k_conv_w<<<288, 256, 0, stream>>>(
        enc_n_w1, enc_n_w2, enc_e_w1, enc_e_w2,
        pe_w1, pe_w2, pn_w1, pn_w2, dw1, wt);

    k_fuse_w<<<49, 256, 0, stream>>>(
        enc_n_w2, enc_n_b2, enc_e_w2, enc_e_b2, pe_w1, wt);

    k_deg<<<eScal, 256, 0, stream>>>(eidx, deg);
    k_scan<<<1, 1024, 0, stream>>>(deg, off);
    k_fill<<<eScal, 256, 0, stream>>>(eidx, deg, csr, srcs_s, dsts_s);

    k_encode_nodes<<<nodeBlocks, 256, 0, stream>>>(
        x, wt, fb, enc_n_b1, enc_n_b2, x_h, Ps, Pd);

    k_edge_l0<<<edgeBlocks, 256, 0, stream>>>(
        eattr, csr, srcs_s, dsts_s, Ps, Pd,
        enc_e_b1, enc_e_b2, wt, fb, pe_b1, pe_b2, epk, agg);

    k_node_l0<<<nodeBlocks, 256, 0, stream>>>(
        x_h, agg, wt, pn_b1, pn_b2, Ps, Pd);

    hipMemsetAsync(agg, 0, NNHH * sizeof(float), stream);

    k_edge_l1<<<edgeBlocks, 256, 0, stream>>>(
        srcs_s, dsts_s, Ps, Pd, wt, pe_b1 + 64, pe_b2 + 64, epk, agg);

    k_node_l1_dec<<<nodeBlocks, 256, 0, stream>>>(
        x_h, agg, wt, pn_b1 + 64, pn_b2 + 64,
        db1, dw2, db2, out);
}

// Round 8
// 561.748 us; speedup vs baseline: 1.8937x; 1.1909x over previous
//
#include <hip/hip_runtime.h>

// GNN: N=50000 nodes, E=800000 edges, H=64, L=2.
// R14: dispatch-count attack + phase2' reg-reuse. Theory: ~200us of the 669
// is outside the big kernels (13 dispatches incl 3 memsets + single-block
// uncoalesced k_scan). Changes vs R13 (which matched R8 at ~668):
//  (1) 13 -> 8 dispatches: fuse_w + deg-zero merged into conv_w; agg memsets
//      replaced by slice-zeroing inside encode / node_l0; k_fill + k_encode
//      merged into one combined-grid kernel.
//  (2) k_scan: CH=52, uint4 loads/stores (4x fewer L2 reqs on the serial
//      single-block critical path).
//  (3) edge_l0 phase2': h0 B-frags read ONCE per tile, feed both WE2 and
//      WE21 chains (-16 ds_read_b128/wave).
// Pipeline: conv_w(+fuse,+deg0) | deg | scan | fill+encode(+agg0) |
//           edge_l0(+agg) | node_l0(+agg0) | edge_l1(+agg) | node_l1+dec.

#define NN 50000
#define EE 800000
#define HH 64
#define LDK 72   // bf16 plane leading dim (144 B row)
#define EPB 64   // rows per block

typedef short short8 __attribute__((ext_vector_type(8)));
typedef short short4v __attribute__((ext_vector_type(4)));
typedef float f32x4 __attribute__((ext_vector_type(4)));

#define MFMA __builtin_amdgcn_mfma_f32_16x16x32_bf16

// wt slots (each 8192 ushorts: 4096 hi + 4096 lo, layout [f][k])
#define S_WE2   0
#define S_W1E0  1
#define S_W2E0  2
#define S_W1E1  3
#define S_W2E1  4
#define S_WN2   5
#define S_W1S0  6
#define S_W1D0  7
#define S_W1S1  8
#define S_W1D1  9
#define S_W1NX0 10
#define S_W1NA0 11
#define S_W2N0  12
#define S_W1NX1 13
#define S_W1NA1 14
#define S_W2N1  15
#define S_DW1   16
#define S_WE21  17  // We2(l0e) @ W1e(l0)
#define S_WNS0  18  // wn2 @ W1s(l0)
#define S_WND0  19  // wn2 @ W1d(l0)
#define OFF_WE1 (20*8192)          // [f][32], K=4 padded
#define OFF_WN1 (20*8192+4096)     // [f][32], K=8 padded
#define FB_OFF  (20*8192+8192)     // ushort offset of float fused biases
// fb floats: [0..63]=be2@W1e, [64..127]=bn2@W1s0, [128..191]=bn2@W1d0
#define WT_USHORTS (20*8192+8192+384)

// ---------------- bf16 helpers ----------------

__device__ __forceinline__ void split2(float x, unsigned short& h, unsigned short& l) {
    union { float f; unsigned u; } a, hf, b;
    a.f = x;
    const unsigned hb = (a.u + 0x7FFFu + ((a.u >> 16) & 1u)) >> 16;  // RNE hi
    hf.u = hb << 16;
    b.f = x - hf.f;                  // exact
    h = (unsigned short)hb;
    l = (unsigned short)(b.u >> 16); // truncated lo: err <= 2^-16 |x|
}

__device__ __forceinline__ float bf2f(unsigned short s) {
    union { unsigned u; float f; } a; a.u = ((unsigned)s) << 16; return a.f;
}

__device__ __forceinline__ float uph(unsigned u) {
    union { unsigned x; float f; } a; a.x = u & 0xFFFF0000u; return a.f;
}
__device__ __forceinline__ float upl(unsigned u) {
    union { unsigned x; float f; } a; a.x = u << 16; return a.f;
}

// packed split (numerics == split2, verified R11-R13 absmax-identical)
__device__ __forceinline__ unsigned cvtpk_bf16(float a, float b) {
    unsigned r;
    asm("v_cvt_pk_bf16_f32 %0, %1, %2" : "=v"(r) : "v"(a), "v"(b));
    return r;
}
__device__ __forceinline__ void split_pair(float x0, float x1, unsigned& hw, unsigned& lw) {
    hw = cvtpk_bf16(x0, x1);
    union { unsigned u; float f; } h0, h1, r0, r1;
    h0.u = hw << 16;
    h1.u = hw & 0xFFFF0000u;
    r0.f = x0 - h0.f;
    r1.f = x1 - h1.f;
    lw = (r0.u >> 16) | (r1.u & 0xFFFF0000u);
}

// A-frags for one 16-feature slice of a 64x64 weight: [chunk][plane]
__device__ __forceinline__ void load_wf(const unsigned short* __restrict__ wm,
                                        int ft, int l15, int quad, short8 (&w)[2][2]) {
#pragma unroll
    for (int c = 0; c < 2; ++c) {
        const int el = (ft * 16 + l15) * 64 + c * 32 + quad * 8;
        w[c][0] = *(const short8*)(wm + el);
        w[c][1] = *(const short8*)(wm + 4096 + el);
    }
}

// D += Ah*Bh + Al*Bh + Ah*Bl over K=64 (2 chunks)
__device__ __forceinline__ f32x4 chain6(const short8 (&w)[2][2],
                                        short8 bh0, short8 bh1,
                                        short8 bl0, short8 bl1, f32x4 a) {
    a = MFMA(w[0][0], bh0, a, 0, 0, 0);
    a = MFMA(w[1][0], bh1, a, 0, 0, 0);
    a = MFMA(w[0][1], bh0, a, 0, 0, 0);
    a = MFMA(w[1][1], bh1, a, 0, 0, 0);
    a = MFMA(w[0][0], bl0, a, 0, 0, 0);
    a = MFMA(w[1][0], bl1, a, 0, 0, 0);
    return a;
}

// one row-tile GEMM step: acc += W @ B(row e)
__device__ __forceinline__ void gemm_tile(const unsigned short* pHi, const unsigned short* pLo,
                                          const short8 (&w)[2][2], int e, int quad, f32x4& a) {
    const short8 bh0 = *(const short8*)(pHi + e * LDK + quad * 8);
    const short8 bh1 = *(const short8*)(pHi + e * LDK + 32 + quad * 8);
    const short8 bl0 = *(const short8*)(pLo + e * LDK + quad * 8);
    const short8 bl1 = *(const short8*)(pLo + e * LDK + 32 + quad * 8);
    a = chain6(w, bh0, bh1, bl0, bl1, a);
}

// store 4 feats of row e via packed cvt split
__device__ __forceinline__ void store_row4(unsigned short* pHi, unsigned short* pLo,
                                           const f32x4& a, int e, int f0) {
    unsigned hw0, lw0, hw1, lw1;
    split_pair(a[0], a[1], hw0, lw0);
    split_pair(a[2], a[3], hw1, lw1);
    uint2 hv; hv.x = hw0; hv.y = hw1;
    uint2 lv; lv.x = lw0; lv.y = lw1;
    *(uint2*)(pHi + e * LDK + f0) = hv;
    *(uint2*)(pLo + e * LDK + f0) = lv;
}

// ======== 4-tile helpers (256 thr) ========

__device__ __forceinline__ void gemm_planes(const unsigned short* pHi, const unsigned short* pLo,
                                            const short8 (&w)[2][2], int l15, int quad,
                                            f32x4 (&acc)[4]) {
#pragma unroll
    for (int et = 0; et < 4; ++et) {
        const int e = et * 16 + l15;
        gemm_tile(pHi, pLo, w, e, quad, acc[et]);
    }
}

__device__ __forceinline__ void set_bias(f32x4 (&acc)[4], const float* __restrict__ b, int f0) {
    const float4 b4 = *(const float4*)(b + f0);
#pragma unroll
    for (int et = 0; et < 4; ++et) {
        acc[et][0] = b4.x; acc[et][1] = b4.y; acc[et][2] = b4.z; acc[et][3] = b4.w;
    }
}

__device__ __forceinline__ void set_zero(f32x4 (&acc)[4]) {
#pragma unroll
    for (int et = 0; et < 4; ++et)
#pragma unroll
        for (int r = 0; r < 4; ++r) acc[et][r] = 0.f;
}

__device__ __forceinline__ void relu4(f32x4 (&acc)[4]) {
#pragma unroll
    for (int et = 0; et < 4; ++et)
#pragma unroll
        for (int r = 0; r < 4; ++r) acc[et][r] = fmaxf(acc[et][r], 0.f);
}

__device__ __forceinline__ void store_split_planes(unsigned short* pHi, unsigned short* pLo,
                                                   const f32x4 (&acc)[4], int l15, int f0) {
#pragma unroll
    for (int et = 0; et < 4; ++et) store_row4(pHi, pLo, acc[et], et * 16 + l15, f0);
}

// stage fp32 [64][64] tile -> split hi/lo planes; invalid rows zero
__device__ __forceinline__ void stage_split64(unsigned short* pHi, unsigned short* pLo,
                                              const float* g, long rowBase, int t, int nValid) {
    const int row = t >> 2, q = t & 3;
    const bool valid = row < nValid;
#pragma unroll
    for (int i = 0; i < 4; ++i) {
        const int col = q * 16 + i * 4;
        float4 v = make_float4(0.f, 0.f, 0.f, 0.f);
        if (valid) v = *(const float4*)(g + (size_t)(rowBase + row) * HH + col);
        unsigned hw0, lw0, hw1, lw1;
        split_pair(v.x, v.y, hw0, lw0);
        split_pair(v.z, v.w, hw1, lw1);
        uint2 hv; hv.x = hw0; hv.y = hw1;
        uint2 lv; lv.x = lw0; lv.y = lw1;
        *(uint2*)(pHi + row * LDK + col) = hv;
        *(uint2*)(pLo + row * LDK + col) = lv;
    }
}

// in-LDS segment sum over dst-sorted rows + atomic scatter (64 rows, 4 waves)
__device__ __forceinline__ void segsum_atomic(const unsigned short* pHi, const unsigned short* pLo,
                                              const int* sDst, int t,
                                              float* __restrict__ agg) {
    const int f = t & 63, c0 = (t >> 6) * 16;
    float s = 0.f;
    int d = sDst[c0];
#pragma unroll
    for (int i = 0; i < 16; ++i) {
        const int r = c0 + i;
        s += bf2f(pHi[r * LDK + f]) + bf2f(pLo[r * LDK + f]);
        const int dn = (i == 15) ? -1 : sDst[r + 1];
        if (dn != d) {
            atomicAdd(&agg[(size_t)d * HH + f], s);
            s = 0.f; d = dn;
        }
    }
}

// ---------------- setup: weights + fused products + deg zero (one kernel) -------

__global__ void k_conv_w(const float* __restrict__ enc_n_w1, const float* __restrict__ enc_n_w2,
                         const float* __restrict__ enc_e_w1, const float* __restrict__ enc_e_w2,
                         const float* __restrict__ pe_w1, const float* __restrict__ pe_w2,
                         const float* __restrict__ pn_w1, const float* __restrict__ pn_w2,
                         const float* __restrict__ dw1,
                         const float* __restrict__ enc_n_b2, const float* __restrict__ enc_e_b2,
                         unsigned short* __restrict__ wt, unsigned* __restrict__ deg)
{
    const int i = blockIdx.x * 256 + threadIdx.x;
    if (i < 17 * 4096) {
        const int m = i >> 12, r = i & 4095;
        const int f = r & 63, k = r >> 6;
        const float* W;
        switch (m) {
            case S_WE2:   W = enc_e_w2; break;
            case S_W1E0:  W = pe_w1; break;
            case S_W2E0:  W = pe_w2; break;
            case S_W1E1:  W = pe_w1 + 192 * 64; break;
            case S_W2E1:  W = pe_w2 + 64 * 64; break;
            case S_WN2:   W = enc_n_w2; break;
            case S_W1S0:  W = pe_w1 + 64 * 64; break;
            case S_W1D0:  W = pe_w1 + 128 * 64; break;
            case S_W1S1:  W = pe_w1 + 192 * 64 + 64 * 64; break;
            case S_W1D1:  W = pe_w1 + 192 * 64 + 128 * 64; break;
            case S_W1NX0: W = pn_w1; break;
            case S_W1NA0: W = pn_w1 + 64 * 64; break;
            case S_W2N0:  W = pn_w2; break;
            case S_W1NX1: W = pn_w1 + 128 * 64; break;
            case S_W1NA1: W = pn_w1 + 128 * 64 + 64 * 64; break;
            case S_W2N1:  W = pn_w2 + 64 * 64; break;
            default:      W = dw1; break;
        }
        unsigned short h, l; split2(W[r], h, l);    // W[k*64+f]
        wt[m * 8192 + f * 64 + k] = h;
        wt[m * 8192 + 4096 + f * 64 + k] = l;
    } else if (i < 17 * 4096 + 2048) {
        const int r = i - 17 * 4096, f = r >> 5, k = r & 31;
        const float v = (k < 4) ? enc_e_w1[k * 64 + f] : 0.f;
        unsigned short h, l; split2(v, h, l);
        wt[OFF_WE1 + f * 32 + k] = h;
        wt[OFF_WE1 + 2048 + f * 32 + k] = l;
    } else if (i < 17 * 4096 + 4096) {
        const int r = i - 17 * 4096 - 2048, f = r >> 5, k = r & 31;
        const float v = (k < 8) ? enc_n_w1[k * 64 + f] : 0.f;
        unsigned short h, l; split2(v, h, l);
        wt[OFF_WN1 + f * 32 + k] = h;
        wt[OFF_WN1 + 2048 + f * 32 + k] = l;
    } else if (i < 73728 + 3 * 4096) {
        // fused weight products (fp32)
        const int r = i - 73728;
        const int m = r >> 12, rr = r & 4095;
        const int g = rr & 63, j = rr >> 6;
        const float* A = (m == 0) ? enc_e_w2 : enc_n_w2;
        const float* B = pe_w1 + m * 64 * 64;   // m0: e-slice, m1: src, m2: dst
        float s = 0.f;
#pragma unroll 8
        for (int f = 0; f < 64; ++f) s += A[j * 64 + f] * B[f * 64 + g];
        unsigned short h, l; split2(s, h, l);
        wt[(S_WE21 + m) * 8192 + g * 64 + j] = h;
        wt[(S_WE21 + m) * 8192 + 4096 + g * 64 + j] = l;
    } else if (i < 73728 + 3 * 4096 + 192) {
        const int r = i - 73728 - 3 * 4096;
        const int m = r >> 6, g = r & 63;
        const float* bb = (m == 0) ? enc_e_b2 : enc_n_b2;
        const float* B = pe_w1 + m * 64 * 64;
        float s = 0.f;
#pragma unroll 8
        for (int f = 0; f < 64; ++f) s += bb[f] * B[f * 64 + g];
        float* fbp = (float*)(wt + FB_OFF);
        fbp[m * 64 + g] = s;
    } else if (i < 73728 + 3 * 4096 + 192 + NN) {
        deg[i - (73728 + 3 * 4096 + 192)] = 0u;   // replaces memset(deg)
    }
}

// ---------------- CSR build ----------------

__global__ void k_deg(const int* __restrict__ eidx, unsigned* __restrict__ deg) {
    const int e = blockIdx.x * 256 + threadIdx.x;
    if (e < EE) atomicAdd(&deg[eidx[EE + e]], 1u);
}

__global__ __launch_bounds__(1024) void k_scan(unsigned* deg, unsigned* __restrict__ off) {
    __shared__ unsigned part[1024];
    const int t = threadIdx.x;
    const int CH = 52;                    // 1024*52 = 53248 >= NN; 52*4B 16B-aligned
    const int s = t * CH;
    unsigned v[52];
    unsigned sum = 0;
#pragma unroll
    for (int j = 0; j < 13; ++j) {
        const int i = s + j * 4;
        uint4 u = {0u, 0u, 0u, 0u};
        if (i + 3 < NN) {
            u = *(const uint4*)(deg + i);
        } else {
            if (i < NN)     u.x = deg[i];
            if (i + 1 < NN) u.y = deg[i + 1];
            if (i + 2 < NN) u.z = deg[i + 2];
            if (i + 3 < NN) u.w = deg[i + 3];
        }
        v[j * 4] = u.x; v[j * 4 + 1] = u.y; v[j * 4 + 2] = u.z; v[j * 4 + 3] = u.w;
        sum += u.x + u.y + u.z + u.w;
    }
    part[t] = sum;
    __syncthreads();
    for (int d = 1; d < 1024; d <<= 1) {
        unsigned p = (t >= d) ? part[t - d] : 0u;
        __syncthreads();
        if (t >= d) part[t] += p;
        __syncthreads();
    }
    unsigned base = (t > 0) ? part[t - 1] : 0u;
#pragma unroll
    for (int j = 0; j < 13; ++j) {
        const int i = s + j * 4;
        uint4 o;
        o.x = base; base += v[j * 4];
        o.y = base; base += v[j * 4 + 1];
        o.z = base; base += v[j * 4 + 2];
        o.w = base; base += v[j * 4 + 3];
        if (i + 3 < NN) {
            *(uint4*)(off + i) = o;
            *(uint4*)(deg + i) = o;       // reuse as fill cursor
        } else {
            if (i < NN)     { off[i] = o.x;     deg[i] = o.x; }
            if (i + 1 < NN) { off[i + 1] = o.y; deg[i + 1] = o.y; }
            if (i + 2 < NN) { off[i + 2] = o.z; deg[i + 2] = o.z; }
            if (i + 3 < NN) { off[i + 3] = o.w; deg[i + 3] = o.w; }
        }
    }
    if (t == 1023) off[NN] = part[1023];
}

// ---------------- K1': CSR fill + node encoder (combined grid) ----------------
// blocks [0, 3125): fill; blocks [3125, 3125+782): encode (+ zero agg slice).

#define FILL_BLOCKS 3125

__global__ __launch_bounds__(256, 4) void k_fill_encode(
    const int* __restrict__ eidx, unsigned* __restrict__ cur,
    int* __restrict__ csr, int* __restrict__ srcs_s, int* __restrict__ dsts_s,
    const float* __restrict__ x, const unsigned short* __restrict__ wt,
    const float* __restrict__ fb,
    const float* __restrict__ bn1, const float* __restrict__ bn2,
    float* __restrict__ x_h, float* __restrict__ Ps, float* __restrict__ Pd,
    float* __restrict__ agg)
{
    __shared__ unsigned short pXhi[EPB * LDK], pXlo[EPB * LDK];
    __shared__ unsigned short pHhi[EPB * LDK], pHlo[EPB * LDK];

    if (blockIdx.x < FILL_BLOCKS) {
        const int e = blockIdx.x * 256 + threadIdx.x;
        if (e < EE) {
            const int d = eidx[EE + e];
            const unsigned p = atomicAdd(&cur[d], 1u);
            csr[p] = e;
            srcs_s[p] = eidx[e];
            dsts_s[p] = d;
        }
        return;
    }

    const int t = threadIdx.x;
    const int lane = t & 63, ft = t >> 6;
    const int quad = lane >> 4, l15 = lane & 15;
    const int f0 = ft * 16 + quad * 4;
    const int nodeBase = (blockIdx.x - FILL_BLOCKS) * 64;
    const int nValid = min(64, NN - nodeBase);

    // zero agg slice (replaces memset#1; consumed by edge_l0 later)
    {
        const uint4 z4 = {0u, 0u, 0u, 0u};
        uint4* ag = (uint4*)(agg + (size_t)nodeBase * HH);
#pragma unroll
        for (int j = 0; j < 4; ++j) {
            const int di = t + j * 256;             // uint4 idx 0..1023
            if (nodeBase + (di >> 4) < NN) ag[di] = z4;
        }
    }

    // stage x (8 cols) padded to 32
    {
        const int row = t >> 2, q = t & 3;
        if (q == 0) {
            float4 a0 = make_float4(0.f, 0.f, 0.f, 0.f), a1 = a0;
            if (row < nValid) {
                a0 = *(const float4*)(x + (size_t)(nodeBase + row) * 8);
                a1 = *(const float4*)(x + (size_t)(nodeBase + row) * 8 + 4);
            }
            unsigned hw0, lw0, hw1, lw1, hw2, lw2, hw3, lw3;
            split_pair(a0.x, a0.y, hw0, lw0);
            split_pair(a0.z, a0.w, hw1, lw1);
            split_pair(a1.x, a1.y, hw2, lw2);
            split_pair(a1.z, a1.w, hw3, lw3);
            uint4 H; H.x = hw0; H.y = hw1; H.z = hw2; H.w = hw3;
            uint4 L; L.x = lw0; L.y = lw1; L.z = lw2; L.w = lw3;
            *(uint4*)(pXhi + row * LDK) = H;
            *(uint4*)(pXlo + row * LDK) = L;
        } else {
            const uint4 z = {0u, 0u, 0u, 0u};
            *(uint4*)(pXhi + row * LDK + q * 8) = z;
            *(uint4*)(pXlo + row * LDK + q * 8) = z;
        }
    }
    __syncthreads();

    f32x4 acc[4];

    // phase1: h1 = relu(x @ wn1 + bn1) -> pH
    {
        short8 wa0, wa1;
        const int el = (ft * 16 + l15) * 32 + quad * 8;
        wa0 = *(const short8*)(wt + OFF_WN1 + el);
        wa1 = *(const short8*)(wt + OFF_WN1 + 2048 + el);
        set_bias(acc, bn1, f0);
#pragma unroll
        for (int et = 0; et < 4; ++et) {
            const int e = et * 16 + l15;
            const short8 bh0 = *(const short8*)(pXhi + e * LDK + quad * 8);
            const short8 bl0 = *(const short8*)(pXlo + e * LDK + quad * 8);
            f32x4 a = acc[et];
            a = MFMA(wa0, bh0, a, 0, 0, 0);
            a = MFMA(wa1, bh0, a, 0, 0, 0);
            a = MFMA(wa0, bl0, a, 0, 0, 0);
            acc[et] = a;
        }
        relu4(acc);
        store_split_planes(pHhi, pHlo, acc, l15, f0);
    }
    __syncthreads();

    // phase2' (fused, read-only on pH):
    // x_h = h1 @ wn2 + bn2
    {
        short8 w[2][2];
        load_wf(wt + S_WN2 * 8192, ft, l15, quad, w);
        set_bias(acc, bn2, f0);
        gemm_planes(pHhi, pHlo, w, l15, quad, acc);
#pragma unroll
        for (int et = 0; et < 4; ++et) {
            const int r = et * 16 + l15;
            if (r < nValid) {
                float4 v = make_float4(acc[et][0], acc[et][1], acc[et][2], acc[et][3]);
                *(float4*)(x_h + (size_t)(nodeBase + r) * HH + f0) = v;
            }
        }
    }
    // Ps = h1 @ (wn2*W1s0) + bn2@W1s0
    {
        short8 w[2][2];
        load_wf(wt + S_WNS0 * 8192, ft, l15, quad, w);
        set_bias(acc, fb + 64, f0);
        gemm_planes(pHhi, pHlo, w, l15, quad, acc);
#pragma unroll
        for (int et = 0; et < 4; ++et) {
            const int r = et * 16 + l15;
            if (r < nValid) {
                float4 v = make_float4(acc[et][0], acc[et][1], acc[et][2], acc[et][3]);
                *(float4*)(Ps + (size_t)(nodeBase + r) * HH + f0) = v;
            }
        }
    }
    // Pd = h1 @ (wn2*W1d0) + bn2@W1d0
    {
        short8 w[2][2];
        load_wf(wt + S_WND0 * 8192, ft, l15, quad, w);
        set_bias(acc, fb + 128, f0);
        gemm_planes(pHhi, pHlo, w, l15, quad, acc);
#pragma unroll
        for (int et = 0; et < 4; ++et) {
            const int r = et * 16 + l15;
            if (r < nValid) {
                float4 v = make_float4(acc[et][0], acc[et][1], acc[et][2], acc[et][3]);
                *(float4*)(Pd + (size_t)(nodeBase + r) * HH + f0) = v;
            }
        }
    }
}

// ---------------- K2: edge encoder + layer-0 edge MLP + fused agg ----------------

__global__ __launch_bounds__(256, 4) void k_edge_l0(
    const float* __restrict__ eattr, const int* __restrict__ csr,
    const int* __restrict__ srcs_s, const int* __restrict__ dsts_s,
    const float* __restrict__ Ps, const float* __restrict__ Pd,
    const float* __restrict__ be1, const float* __restrict__ be2,
    const unsigned short* __restrict__ wt, const float* __restrict__ fb,
    const float* __restrict__ pb1, const float* __restrict__ pb2,
    unsigned* __restrict__ epk, float* __restrict__ agg)
{
    __shared__ unsigned short pHhi[EPB * LDK], pHlo[EPB * LDK];
    __shared__ unsigned short pEhi[EPB * LDK], pElo[EPB * LDK];
    __shared__ int sDst[EPB];

    const int t = threadIdx.x;
    const int lane = t & 63, ft = t >> 6;
    const int quad = lane >> 4, l15 = lane & 15;
    const int f0 = ft * 16 + quad * 4;
    const long eBase = (long)blockIdx.x * EPB;

    // stage eattr (gathered via csr): k 0..3 data, 4..31 zero
    {
        const int row = t >> 2, q = t & 3;
        if (q == 0) {
            const int eid = csr[eBase + row];
            const float4 ea = *(const float4*)(eattr + (size_t)eid * 4);
            unsigned hw0, lw0, hw1, lw1;
            split_pair(ea.x, ea.y, hw0, lw0);
            split_pair(ea.z, ea.w, hw1, lw1);
            uint4 H; H.x = hw0; H.y = hw1; H.z = 0u; H.w = 0u;
            uint4 L; L.x = lw0; L.y = lw1; L.z = 0u; L.w = 0u;
            *(uint4*)(pHhi + row * LDK) = H;
            *(uint4*)(pHlo + row * LDK) = L;
        } else {
            const uint4 z = {0u, 0u, 0u, 0u};
            *(uint4*)(pHhi + row * LDK + q * 8) = z;
            *(uint4*)(pHlo + row * LDK + q * 8) = z;
        }
    }
    if (t < EPB) sDst[t] = dsts_s[eBase + t];

    int srcs[4], dsts[4];
#pragma unroll
    for (int et = 0; et < 4; ++et) {
        const long p = eBase + et * 16 + l15;
        srcs[et] = srcs_s[p];
        dsts[et] = dsts_s[p];
    }
    // prefetch Ps/Pd gathers (consumed in fused phase2')
    float4 ps[4], pd[4];
#pragma unroll
    for (int et = 0; et < 4; ++et) {
        ps[et] = *(const float4*)(Ps + (size_t)srcs[et] * HH + f0);
        pd[et] = *(const float4*)(Pd + (size_t)dsts[et] * HH + f0);
    }
    __syncthreads();

    f32x4 acc[4];

    // phase1: h0 = relu(eattr @ We1 + be1) -> pE
    {
        short8 wa0, wa1;
        const int el = (ft * 16 + l15) * 32 + quad * 8;
        wa0 = *(const short8*)(wt + OFF_WE1 + el);
        wa1 = *(const short8*)(wt + OFF_WE1 + 2048 + el);
        set_bias(acc, be1, f0);
#pragma unroll
        for (int et = 0; et < 4; ++et) {
            const int e = et * 16 + l15;
            const short8 bh0 = *(const short8*)(pHhi + e * LDK + quad * 8);
            const short8 bl0 = *(const short8*)(pHlo + e * LDK + quad * 8);
            f32x4 a = acc[et];
            a = MFMA(wa0, bh0, a, 0, 0, 0);
            a = MFMA(wa1, bh0, a, 0, 0, 0);
            a = MFMA(wa0, bl0, a, 0, 0, 0);
            acc[et] = a;
        }
        relu4(acc);
        store_split_planes(pEhi, pElo, acc, l15, f0);
    }
    __syncthreads();

    // phase2' (fused, SINGLE LDS read of h0 per tile feeds BOTH chains):
    // e0 = h0 @ We2 + be2 (regs residual); t1 = relu(h0 @ WE21 + fb + pb1 + Ps + Pd) -> pH
    f32x4 e0s[4];
    {
        short8 w2[2][2], w21[2][2];
        load_wf(wt + S_WE2 * 8192, ft, l15, quad, w2);
        load_wf(wt + S_WE21 * 8192, ft, l15, quad, w21);
        const float4 b2 = *(const float4*)(be2 + f0);
        const float4 fa = *(const float4*)(fb + f0);       // be2@W1e
        const float4 p1 = *(const float4*)(pb1 + f0);
        const float4 tb = make_float4(fa.x + p1.x, fa.y + p1.y,
                                      fa.z + p1.z, fa.w + p1.w);
#pragma unroll
        for (int et = 0; et < 4; ++et) {
            const int e = et * 16 + l15;
            const short8 bh0 = *(const short8*)(pEhi + e * LDK + quad * 8);
            const short8 bh1 = *(const short8*)(pEhi + e * LDK + 32 + quad * 8);
            const short8 bl0 = *(const short8*)(pElo + e * LDK + quad * 8);
            const short8 bl1 = *(const short8*)(pElo + e * LDK + 32 + quad * 8);
            f32x4 a; a[0] = b2.x; a[1] = b2.y; a[2] = b2.z; a[3] = b2.w;
            a = chain6(w2, bh0, bh1, bl0, bl1, a);
            e0s[et] = a;
            f32x4 b = {0.f, 0.f, 0.f, 0.f};
            b = chain6(w21, bh0, bh1, bl0, bl1, b);
            b[0] = fmaxf(b[0] + ps[et].x + pd[et].x + tb.x, 0.f);
            b[1] = fmaxf(b[1] + ps[et].y + pd[et].y + tb.y, 0.f);
            b[2] = fmaxf(b[2] + ps[et].z + pd[et].z + tb.z, 0.f);
            b[3] = fmaxf(b[3] + ps[et].w + pd[et].w + tb.w, 0.f);
            store_row4(pHhi, pHlo, b, e, f0);
        }
    }
    __syncthreads();

    // phase3': e1 = e0(regs) + t1 @ W2e + pb2 -> pE
    {
        short8 w[2][2];
        load_wf(wt + S_W2E0 * 8192, ft, l15, quad, w);
        set_zero(acc);
        gemm_planes(pHhi, pHlo, w, l15, quad, acc);
        const float4 b4 = *(const float4*)(pb2 + f0);
#pragma unroll
        for (int et = 0; et < 4; ++et) {
            acc[et][0] += e0s[et][0] + b4.x;
            acc[et][1] += e0s[et][1] + b4.y;
            acc[et][2] += e0s[et][2] + b4.z;
            acc[et][3] += e0s[et][3] + b4.w;
        }
        store_split_planes(pEhi, pElo, acc, l15, f0);
    }
    __syncthreads();

    // pack pE -> epk (sorted positions)
    {
        const int row = t >> 2, q = t & 3;
#pragma unroll
        for (int half = 0; half < 2; ++half) {
            const int lo = row * LDK + q * 8 + half * 32;
            const long go = (eBase + row) * HH + q * 8 + half * 32;
            union { unsigned short u[8]; uint4 v; } H, L;
            H.v = *(const uint4*)(pEhi + lo);
            L.v = *(const uint4*)(pElo + lo);
            union { unsigned u[8]; uint4 v[2]; } o;
#pragma unroll
            for (int i = 0; i < 8; ++i) o.u[i] = ((unsigned)H.u[i] << 16) | L.u[i];
            *(uint4*)(epk + go) = o.v[0];
            *(uint4*)(epk + go + 4) = o.v[1];
        }
    }
    // fused aggregation: agg[dst] += e1
    segsum_atomic(pEhi, pElo, sDst, t, agg);
}

// ---------------- K4: layer-1 edge MLP + fused agg ----------------

__global__ __launch_bounds__(256, 4) void k_edge_l1(
    const int* __restrict__ srcs_s, const int* __restrict__ dsts_s,
    const float* __restrict__ Ps, const float* __restrict__ Pd,
    const unsigned short* __restrict__ wt,
    const float* __restrict__ pb1, const float* __restrict__ pb2,
    const unsigned* __restrict__ epk, float* __restrict__ agg)
{
    __shared__ unsigned short pEhi[EPB * LDK], pElo[EPB * LDK];
    __shared__ unsigned short pHhi[EPB * LDK], pHlo[EPB * LDK];
    __shared__ int sDst[EPB];

    const int t = threadIdx.x;
    const int lane = t & 63, ft = t >> 6;
    const int quad = lane >> 4, l15 = lane & 15;
    const int f0 = ft * 16 + quad * 4;
    const long eBase = (long)blockIdx.x * EPB;

    // load epk -> deinterleave -> pE
    {
        const int row = t >> 2, q = t & 3;
#pragma unroll
        for (int half = 0; half < 2; ++half) {
            const int lo = row * LDK + q * 8 + half * 32;
            const long go = (eBase + row) * HH + q * 8 + half * 32;
            union { unsigned u[8]; uint4 v[2]; } in;
            in.v[0] = *(const uint4*)(epk + go);
            in.v[1] = *(const uint4*)(epk + go + 4);
            union { unsigned short u[8]; uint4 v; } H, L;
#pragma unroll
            for (int i = 0; i < 8; ++i) {
                H.u[i] = (unsigned short)(in.u[i] >> 16);
                L.u[i] = (unsigned short)(in.u[i] & 0xFFFFu);
            }
            *(uint4*)(pEhi + lo) = H.v;
            *(uint4*)(pElo + lo) = L.v;
        }
    }
    if (t < EPB) sDst[t] = dsts_s[eBase + t];

    int srcs[4], dsts[4];
#pragma unroll
    for (int et = 0; et < 4; ++et) {
        const long p = eBase + et * 16 + l15;
        srcs[et] = srcs_s[p];
        dsts[et] = dsts_s[p];
    }
    // prefetch Ps/Pd gathers (consumed in t1 phase)
    float4 ps[4], pd[4];
#pragma unroll
    for (int et = 0; et < 4; ++et) {
        ps[et] = *(const float4*)(Ps + (size_t)srcs[et] * HH + f0);
        pd[et] = *(const float4*)(Pd + (size_t)dsts[et] * HH + f0);
    }
    __syncthreads();

    f32x4 acc[4];

    // t1 = relu(e1 @ W1e + Ps[src] + Pd[dst] + pb1) -> pH
    {
        short8 w[2][2];
        load_wf(wt + S_W1E1 * 8192, ft, l15, quad, w);
        set_zero(acc);
        gemm_planes(pEhi, pElo, w, l15, quad, acc);
        const float4 b4 = *(const float4*)(pb1 + f0);
#pragma unroll
        for (int et = 0; et < 4; ++et) {
            acc[et][0] = fmaxf(acc[et][0] + ps[et].x + pd[et].x + b4.x, 0.f);
            acc[et][1] = fmaxf(acc[et][1] + ps[et].y + pd[et].y + b4.y, 0.f);
            acc[et][2] = fmaxf(acc[et][2] + ps[et].z + pd[et].z + b4.z, 0.f);
            acc[et][3] = fmaxf(acc[et][3] + ps[et].w + pd[et].w + b4.w, 0.f);
        }
        store_split_planes(pHhi, pHlo, acc, l15, f0);
    }
    __syncthreads();

    // e2 = e1(pE residual, own cells) + t1 @ W2e + pb2 -> pE
    {
        short8 w[2][2];
        load_wf(wt + S_W2E1 * 8192, ft, l15, quad, w);
        set_zero(acc);
        gemm_planes(pHhi, pHlo, w, l15, quad, acc);
        const float4 b4 = *(const float4*)(pb2 + f0);
#pragma unroll
        for (int et = 0; et < 4; ++et) {
            const int e = et * 16 + l15;
            const short4v hv = *(const short4v*)(pEhi + e * LDK + f0);
            const short4v lv = *(const short4v*)(pElo + e * LDK + f0);
            acc[et][0] += bf2f((unsigned short)hv[0]) + bf2f((unsigned short)lv[0]) + b4.x;
            acc[et][1] += bf2f((unsigned short)hv[1]) + bf2f((unsigned short)lv[1]) + b4.y;
            acc[et][2] += bf2f((unsigned short)hv[2]) + bf2f((unsigned short)lv[2]) + b4.z;
            acc[et][3] += bf2f((unsigned short)hv[3]) + bf2f((unsigned short)lv[3]) + b4.w;
        }
        store_split_planes(pEhi, pElo, acc, l15, f0);   // own cells, same thread
    }
    __syncthreads();

    // fused aggregation: agg[dst] += e2
    segsum_atomic(pEhi, pElo, sDst, t, agg);
}

// ---------------- K3: node update l0 + layer-1 projections (+ agg self-zero) -----

__global__ __launch_bounds__(256, 4) void k_node_l0(
    float* x_h, float* agg, const unsigned short* __restrict__ wt,
    const float* __restrict__ nb1, const float* __restrict__ nb2,
    float* Ps, float* __restrict__ Pd)
{
    __shared__ unsigned short pXhi[EPB * LDK], pXlo[EPB * LDK];
    __shared__ unsigned short pAhi[EPB * LDK], pAlo[EPB * LDK];

    const int t = threadIdx.x;
    const int lane = t & 63, ft = t >> 6;
    const int quad = lane >> 4, l15 = lane & 15;
    const int f0 = ft * 16 + quad * 4;
    const int nodeBase = blockIdx.x * 64;
    const int nValid = min(64, NN - nodeBase);

    stage_split64(pXhi, pXlo, x_h, nodeBase, t, nValid);
    stage_split64(pAhi, pAlo, agg, nodeBase, t, nValid);
    __syncthreads();

    // zero own agg slice for layer-1 (replaces memset#2; reads done above)
    {
        const uint4 z4 = {0u, 0u, 0u, 0u};
        uint4* ag = (uint4*)(agg + (size_t)nodeBase * HH);
#pragma unroll
        for (int j = 0; j < 4; ++j) {
            const int di = t + j * 256;
            if (nodeBase + (di >> 4) < NN) ag[di] = z4;
        }
    }

    f32x4 acc[4];

    // t1 = relu(x_h @ W1x + agg @ W1a + nb1)
    {
        short8 w[2][2];
        load_wf(wt + S_W1NX0 * 8192, ft, l15, quad, w);
        set_bias(acc, nb1, f0);
        gemm_planes(pXhi, pXlo, w, l15, quad, acc);
        load_wf(wt + S_W1NA0 * 8192, ft, l15, quad, w);
        gemm_planes(pAhi, pAlo, w, l15, quad, acc);
        relu4(acc);
    }
    __syncthreads();                       // pA reads complete
    store_split_planes(pAhi, pAlo, acc, l15, f0);   // t1 -> pA
    __syncthreads();

    // x_h1 = x_h + t1 @ W2n + nb2 -> global + pX
    {
        short8 w[2][2];
        load_wf(wt + S_W2N0 * 8192, ft, l15, quad, w);
        set_bias(acc, nb2, f0);
        gemm_planes(pAhi, pAlo, w, l15, quad, acc);
#pragma unroll
        for (int et = 0; et < 4; ++et) {
            const int r = et * 16 + l15;
            if (r < nValid) {
                const size_t gi = (size_t)(nodeBase + r) * HH + f0;
                const float4 xr = *(const float4*)(x_h + gi);
                acc[et][0] += xr.x; acc[et][1] += xr.y;
                acc[et][2] += xr.z; acc[et][3] += xr.w;
                float4 v = make_float4(acc[et][0], acc[et][1], acc[et][2], acc[et][3]);
                *(float4*)(x_h + gi) = v;
            }
        }
        store_split_planes(pXhi, pXlo, acc, l15, f0);
    }
    __syncthreads();

    // Ps1 = x_h1 @ W1s(l1)
    {
        short8 w[2][2];
        load_wf(wt + S_W1S1 * 8192, ft, l15, quad, w);
        set_zero(acc);
        gemm_planes(pXhi, pXlo, w, l15, quad, acc);
#pragma unroll
        for (int et = 0; et < 4; ++et) {
            const int r = et * 16 + l15;
            if (r < nValid) {
                float4 v = make_float4(acc[et][0], acc[et][1], acc[et][2], acc[et][3]);
                *(float4*)(Ps + (size_t)(nodeBase + r) * HH + f0) = v;
            }
        }
    }
    // Pd1 = x_h1 @ W1d(l1)
    {
        short8 w[2][2];
        load_wf(wt + S_W1D1 * 8192, ft, l15, quad, w);
        set_zero(acc);
        gemm_planes(pXhi, pXlo, w, l15, quad, acc);
#pragma unroll
        for (int et = 0; et < 4; ++et) {
            const int r = et * 16 + l15;
            if (r < nValid) {
                float4 v = make_float4(acc[et][0], acc[et][1], acc[et][2], acc[et][3]);
                *(float4*)(Pd + (size_t)(nodeBase + r) * HH + f0) = v;
            }
        }
    }
}

// ---------------- K5: node update l1 + decoder ----------------

__global__ __launch_bounds__(256, 4) void k_node_l1_dec(
    const float* x_h, const float* agg, const unsigned short* __restrict__ wt,
    const float* __restrict__ nb1, const float* __restrict__ nb2,
    const float* __restrict__ db1, const float* __restrict__ dw2,
    const float* __restrict__ db2, float* __restrict__ out)
{
    __shared__ unsigned short pXhi[EPB * LDK], pXlo[EPB * LDK];
    __shared__ unsigned short pAhi[EPB * LDK], pAlo[EPB * LDK];
    __shared__ float sW2[64 * 6];

    const int t = threadIdx.x;
    const int lane = t & 63, ft = t >> 6;
    const int quad = lane >> 4, l15 = lane & 15;
    const int f0 = ft * 16 + quad * 4;
    const int nodeBase = blockIdx.x * 64;
    const int nValid = min(64, NN - nodeBase);

    stage_split64(pXhi, pXlo, x_h, nodeBase, t, nValid);
    stage_split64(pAhi, pAlo, agg, nodeBase, t, nValid);
    if (t < 192) {
        sW2[t] = dw2[t];
        sW2[t + 192] = dw2[t + 192];
    }
    __syncthreads();

    f32x4 acc[4];

    // t1 = relu(x_h @ W1x + agg @ W1a + nb1)
    {
        short8 w[2][2];
        load_wf(wt + S_W1NX1 * 8192, ft, l15, quad, w);
        set_bias(acc, nb1, f0);
        gemm_planes(pXhi, pXlo, w, l15, quad, acc);
        load_wf(wt + S_W1NA1 * 8192, ft, l15, quad, w);
        gemm_planes(pAhi, pAlo, w, l15, quad, acc);
        relu4(acc);
    }
    __syncthreads();
    store_split_planes(pAhi, pAlo, acc, l15, f0);   // t1 -> pA
    __syncthreads();

    // x_h2 = x_h + t1 @ W2n + nb2 -> pX (no global writeback needed)
    {
        short8 w[2][2];
        load_wf(wt + S_W2N1 * 8192, ft, l15, quad, w);
        set_bias(acc, nb2, f0);
        gemm_planes(pAhi, pAlo, w, l15, quad, acc);
#pragma unroll
        for (int et = 0; et < 4; ++et) {
            const int r = et * 16 + l15;
            if (r < nValid) {
                const float4 xr = *(const float4*)(x_h + (size_t)(nodeBase + r) * HH + f0);
                acc[et][0] += xr.x; acc[et][1] += xr.y;
                acc[et][2] += xr.z; acc[et][3] += xr.w;
            }
        }
        store_split_planes(pXhi, pXlo, acc, l15, f0);
    }
    __syncthreads();

    // d1 = relu(x_h2 @ dec_w1 + db1) -> pA
    {
        short8 w[2][2];
        load_wf(wt + S_DW1 * 8192, ft, l15, quad, w);
        set_bias(acc, db1, f0);
        gemm_planes(pXhi, pXlo, w, l15, quad, acc);
        relu4(acc);
        store_split_planes(pAhi, pAlo, acc, l15, f0);
    }
    __syncthreads();

    // out = d1 @ dec_w2 + db2  (64 nodes x 6)
    if (t < 64 && t < nValid) {
        float o[6];
#pragma unroll
        for (int c = 0; c < 6; ++c) o[c] = db2[c];
#pragma unroll 8
        for (int k = 0; k < 64; ++k) {
            const float a = bf2f(pAhi[t * LDK + k]) + bf2f(pAlo[t * LDK + k]);
#pragma unroll
            for (int c = 0; c < 6; ++c) o[c] = fmaf(a, sW2[k * 6 + c], o[c]);
        }
        float* op = out + (size_t)(nodeBase + t) * 6;
#pragma unroll
        for (int c = 0; c < 6; ++c) op[c] = o[c];
    }
}

// ---------------- launcher ----------------

extern "C" void kernel_launch(void* const* d_in, const int* in_sizes, int n_in,
                              void* d_out, int out_size, void* d_ws, size_t ws_size,
                              hipStream_t stream) {
    const float* x        = (const float*)d_in[0];
    const float* eattr    = (const float*)d_in[1];
    const int*   eidx     = (const int*)d_in[2];
    const float* enc_n_w1 = (const float*)d_in[3];
    const float* enc_n_b1 = (const float*)d_in[4];
    const float* enc_n_w2 = (const float*)d_in[5];
    const float* enc_n_b2 = (const float*)d_in[6];
    const float* enc_e_w1 = (const float*)d_in[7];
    const float* enc_e_b1 = (const float*)d_in[8];
    const float* enc_e_w2 = (const float*)d_in[9];
    const float* enc_e_b2 = (const float*)d_in[10];
    const float* pe_w1    = (const float*)d_in[11];  // [2,192,64]
    const float* pe_b1    = (const float*)d_in[12];  // [2,64]
    const float* pe_w2    = (const float*)d_in[13];  // [2,64,64]
    const float* pe_b2    = (const float*)d_in[14];  // [2,64]
    const float* pn_w1    = (const float*)d_in[15];  // [2,128,64]
    const float* pn_b1    = (const float*)d_in[16];
    const float* pn_w2    = (const float*)d_in[17];  // [2,64,64]
    const float* pn_b2    = (const float*)d_in[18];
    const float* dw1      = (const float*)d_in[19];
    const float* db1      = (const float*)d_in[20];
    const float* dw2      = (const float*)d_in[21];
    const float* db2      = (const float*)d_in[22];
    float* out = (float*)d_out;

    // ws: x_h | Ps | Pd | agg | epk | off | deg | csr | srcs_s | dsts_s | wt
    const size_t NNHH = (size_t)NN * HH;
    float* ws  = (float*)d_ws;
    float* x_h = ws;
    float* Ps  = ws + NNHH;
    float* Pd  = ws + 2 * NNHH;
    float* agg = ws + 3 * NNHH;
    unsigned* epk = (unsigned*)(ws + 4 * NNHH);           // EE*HH uints
    unsigned* off = epk + (size_t)EE * HH;                // NN+1
    unsigned* deg = off + (NN + 1);                       // NN, reused as cursor
    int* csr    = (int*)(deg + NN);                       // EE
    int* srcs_s = csr + EE;                               // EE
    int* dsts_s = srcs_s + EE;                            // EE
    unsigned short* wt = (unsigned short*)(dsts_s + EE);  // WT_USHORTS
    const float* fb = (const float*)(wt + FB_OFF);        // fused biases

    const int nodeBlocks = (NN + 63) / 64;   // 782
    const int edgeBlocks = EE / EPB;         // 12500
    const int eScal      = (EE + 255) / 256; // 3125 (= FILL_BLOCKS)
    const int convBlocks = (73728 + 3 * 4096 + 192 + NN + 255) / 256;  // 533

    k_conv_w<<<convBlocks, 256, 0, stream>>>(
        enc_n_w1, enc_n_w2, enc_e_w1, enc_e_w2,
        pe_w1, pe_w2, pn_w1, pn_w2, dw1,
        enc_n_b2, enc_e_b2, wt, deg);

    k_deg<<<eScal, 256, 0, stream>>>(eidx, deg);
    k_scan<<<1, 1024, 0, stream>>>(deg, off);

    k_fill_encode<<<FILL_BLOCKS + nodeBlocks, 256, 0, stream>>>(
        eidx, deg, csr, srcs_s, dsts_s,
        x, wt, fb, enc_n_b1, enc_n_b2, x_h, Ps, Pd, agg);

    k_edge_l0<<<edgeBlocks, 256, 0, stream>>>(
        eattr, csr, srcs_s, dsts_s, Ps, Pd,
        enc_e_b1, enc_e_b2, wt, fb, pe_b1, pe_b2, epk, agg);

    k_node_l0<<<nodeBlocks, 256, 0, stream>>>(
        x_h, agg, wt, pn_b1, pn_b2, Ps, Pd);

    k_edge_l1<<<edgeBlocks, 256, 0, stream>>>(
        srcs_s, dsts_s, Ps, Pd, wt, pe_b1 + 64, pe_b2 + 64, epk, agg);

    k_node_l1_dec<<<nodeBlocks, 256, 0, stream>>>(
        x_h, agg, wt, pn_b1 + 64, pn_b2 + 64,
        db1, dw2, db2, out);
}